// Round 14
// baseline (349.105 us; speedup 1.0000x reference)
//
#include <hip/hip_runtime.h>
#include <hip/hip_bf16.h>
#include <math.h>

#define NHEADS 2

typedef unsigned short u16;
typedef __attribute__((ext_vector_type(8))) unsigned short u16x8;
typedef __attribute__((ext_vector_type(4))) unsigned short u16x4;
typedef __attribute__((ext_vector_type(8))) short short8;
typedef __attribute__((ext_vector_type(4))) short short4v;
typedef __attribute__((ext_vector_type(4))) float f32x4;

__device__ __forceinline__ u16 f2bf(float x) {
    __hip_bfloat16 h = __float2bfloat16(x);
    return __builtin_bit_cast(unsigned short, h);
}

// ---------------------------------------------------------------------------
// Per-level argument blocks (passed by value to fused kernels).
// ---------------------------------------------------------------------------
struct QkvLvl {
    const float *f1, *f2, *f3;
    const float *w12, *b12, *w13, *b13;
    u16 *Qa, *Ka, *Va, *Qb, *Kb, *Vb;
    int C, L, dh, gx, perAtt;
    float qscale;
};
struct PrepArgs {
    const float *sqw[3], *owa[3], *owb[3], *oba[3], *obb[3], *sqb[3];
    float *wp[3], *bp[3];
};
struct SqLvl {
    const float* F1; const u16 *X1, *X2;
    const float *W, *bias; float* out;
    int M, C, L, gx, nblk;
};

// ---------------------------------------------------------------------------
// qkv GEMM body (identical math to round 13), shared tiles passed in.
// ---------------------------------------------------------------------------
__device__ __forceinline__ void qkv_dev(const QkvLvl& A, int lbid,
                                        u16 (*Xs)[72], u16 (*Ws)[72])
{
    const int att = lbid / A.perAtt;
    const int r = lbid - att * A.perAtt;
    const int n0 = (r % A.gx) * 64;
    const int m0 = (r / A.gx) * 64;
    const int C = A.C, L = A.L, dh = A.dh;
    const int K = C;
    const int tid = threadIdx.x;
    const int wid = tid >> 6, lane = tid & 63;
    const int lo = lane & 15, hi = lane >> 4;
    const int wm = wid >> 1, wn = wid & 1;

    const float* __restrict__ Xf = (n0 < C) ? A.f1 : (att ? A.f3 : A.f2);
    const float* __restrict__ W = att ? A.w13 : A.w12;
    const float* __restrict__ bias = att ? A.b13 : A.b12;
    const int bb = m0 / L;
    const int l0 = m0 - bb * L;

    f32x4 acc[2][2];
    #pragma unroll
    for (int i = 0; i < 2; ++i)
        #pragma unroll
        for (int j = 0; j < 2; ++j)
            #pragma unroll
            for (int rr = 0; rr < 4; ++rr) acc[i][j][rr] = 0.f;

    f32x4 xregf[4];
    f32x4 wreg[4];
    const int kx = tid >> 4;
    const int lc = tid & 15;

    auto load_x = [&](int k0) {
        #pragma unroll
        for (int i = 0; i < 4; ++i)
            xregf[i] = *(const f32x4*)&Xf[((size_t)(bb * C) + k0 + kx + 16 * i) * L + l0 + lc * 4];
    };
    auto store_x = [&]() {
        #pragma unroll
        for (int i = 0; i < 4; ++i)
            #pragma unroll
            for (int j = 0; j < 4; ++j)
                Xs[lc * 4 + j][kx + 16 * i] = f2bf(xregf[i][j]);
    };
    auto load_w = [&](int k0) {
        #pragma unroll
        for (int p = 0; p < 4; ++p) {
            int c = tid + p * 256;
            int row = c >> 4, kc = c & 15;
            wreg[p] = *(const f32x4*)&W[(size_t)(n0 + row) * K + k0 + kc * 4];
        }
    };

    load_x(0);
    load_w(0);
    const int ns = K / 64;
    for (int s = 0; s < ns; ++s) {
        __syncthreads();
        store_x();
        #pragma unroll
        for (int p = 0; p < 4; ++p) {
            int c = tid + p * 256;
            int row = c >> 4, kc = c & 15;
            u16x4 cv = {f2bf(wreg[p][0]), f2bf(wreg[p][1]),
                        f2bf(wreg[p][2]), f2bf(wreg[p][3])};
            *(u16x4*)&Ws[row][kc * 4] = cv;
        }
        __syncthreads();
        if (s + 1 < ns) { load_x((s + 1) * 64); load_w((s + 1) * 64); }
        #pragma unroll
        for (int kk = 0; kk < 2; ++kk) {
            short8 wf0 = *(const short8*)&Ws[wn * 32 + lo][kk * 32 + hi * 8];
            short8 wf1 = *(const short8*)&Ws[wn * 32 + 16 + lo][kk * 32 + hi * 8];
            short8 xf0 = *(const short8*)&Xs[wm * 32 + lo][kk * 32 + hi * 8];
            short8 xf1 = *(const short8*)&Xs[wm * 32 + 16 + lo][kk * 32 + hi * 8];
            acc[0][0] = __builtin_amdgcn_mfma_f32_16x16x32_bf16(wf0, xf0, acc[0][0], 0, 0, 0);
            acc[0][1] = __builtin_amdgcn_mfma_f32_16x16x32_bf16(wf1, xf0, acc[0][1], 0, 0, 0);
            acc[1][0] = __builtin_amdgcn_mfma_f32_16x16x32_bf16(wf0, xf1, acc[1][0], 0, 0, 0);
            acc[1][1] = __builtin_amdgcn_mfma_f32_16x16x32_bf16(wf1, xf1, acc[1][1], 0, 0, 0);
        }
    }

    #pragma unroll
    for (int nt = 0; nt < 2; ++nt) {
        const int nb = n0 + wn * 32 + nt * 16 + hi * 4;
        const float b0 = bias[nb + 0], b1 = bias[nb + 1];
        const float b2 = bias[nb + 2], b3 = bias[nb + 3];
        const int which = nb / C;
        const int co = nb - which * C;
        const int h = co / dh;
        const int dd = co - h * dh;
        u16* dst = (which == 0) ? (att ? A.Qb : A.Qa)
                 : (which == 1) ? (att ? A.Kb : A.Ka) : (att ? A.Vb : A.Va);
        const float sc = (which == 0) ? A.qscale : 1.0f;
        #pragma unroll
        for (int mt = 0; mt < 2; ++mt) {
            int m = m0 + wm * 32 + mt * 16 + lo;
            int b_ = m / L; int l = m - b_ * L;
            u16x4 pk = {f2bf((acc[mt][nt][0] + b0) * sc),
                        f2bf((acc[mt][nt][1] + b1) * sc),
                        f2bf((acc[mt][nt][2] + b2) * sc),
                        f2bf((acc[mt][nt][3] + b3) * sc)};
            *(u16x4*)&dst[((size_t)(b_ * NHEADS + h) * L + l) * dh + dd] = pk;
        }
    }
}

// ---------------------------------------------------------------------------
// prep_w body (identical to round 13): fold out_proj into squeeze weights.
// ---------------------------------------------------------------------------
__device__ __forceinline__ void prepw_dev(const PrepArgs& P, int bid,
                                          u16 (*As)[72], u16 (*Bs)[72])
{
    int C; int lv;
    if (bid < 12)      { C = 128; lv = 0; }
    else if (bid < 60) { bid -= 12; C = 256; lv = 1; }
    else               { bid -= 60; C = 512; lv = 2; }
    const float* sqw = P.sqw[lv];
    const float* owa = P.owa[lv];
    const float* owb = P.owb[lv];
    float* wp = P.wp[lv];
    const int K3 = 3 * C;
    const int gxw = K3 / 64;
    const int n0 = (bid / gxw) * 64;
    const int kc0 = (bid % gxw) * 64;
    const int tid = threadIdx.x;

    if (kc0 < C) {
        for (int p = tid; p < 64 * 64; p += 256) {
            int i = p >> 6, j = p & 63;
            wp[(size_t)(n0 + i) * K3 + kc0 + j] = sqw[(size_t)(n0 + i) * K3 + kc0 + j];
        }
        return;
    }
    const int which = kc0 / C;
    const int kp0 = kc0 - which * C;
    const float* __restrict__ ow = (which == 1) ? owa : owb;

    const int wid = tid >> 6, lane = tid & 63;
    const int lo = lane & 15, hi = lane >> 4;
    const int wm = wid >> 1, wn = wid & 1;

    f32x4 acc[2][2];
    #pragma unroll
    for (int i = 0; i < 2; ++i)
        #pragma unroll
        for (int j = 0; j < 2; ++j)
            #pragma unroll
            for (int rr = 0; rr < 4; ++rr) acc[i][j][rr] = 0.f;

    for (int ct = 0; ct < C / 64; ++ct) {
        __syncthreads();
        for (int p = tid; p < 64 * 64; p += 256) {
            int i = p >> 6, j = p & 63;
            As[i][j] = f2bf(sqw[(size_t)(n0 + i) * K3 + which * C + ct * 64 + j]);
            Bs[j][i] = f2bf(ow[(size_t)(ct * 64 + i) * C + kp0 + j]);
        }
        __syncthreads();
        #pragma unroll
        for (int kk = 0; kk < 2; ++kk) {
            short8 wf0 = *(const short8*)&As[wn * 32 + lo][kk * 32 + hi * 8];
            short8 wf1 = *(const short8*)&As[wn * 32 + 16 + lo][kk * 32 + hi * 8];
            short8 xf0 = *(const short8*)&Bs[wm * 32 + lo][kk * 32 + hi * 8];
            short8 xf1 = *(const short8*)&Bs[wm * 32 + 16 + lo][kk * 32 + hi * 8];
            acc[0][0] = __builtin_amdgcn_mfma_f32_16x16x32_bf16(wf0, xf0, acc[0][0], 0, 0, 0);
            acc[0][1] = __builtin_amdgcn_mfma_f32_16x16x32_bf16(wf1, xf0, acc[0][1], 0, 0, 0);
            acc[1][0] = __builtin_amdgcn_mfma_f32_16x16x32_bf16(wf0, xf1, acc[1][0], 0, 0, 0);
            acc[1][1] = __builtin_amdgcn_mfma_f32_16x16x32_bf16(wf1, xf1, acc[1][1], 0, 0, 0);
        }
    }
    #pragma unroll
    for (int nt = 0; nt < 2; ++nt) {
        const int nb = n0 + wn * 32 + nt * 16 + hi * 4;
        #pragma unroll
        for (int mt = 0; mt < 2; ++mt) {
            const int col = kc0 + wm * 32 + mt * 16 + lo;
            #pragma unroll
            for (int rr = 0; rr < 4; ++rr)
                wp[(size_t)(nb + rr) * K3 + col] = acc[mt][nt][rr];
        }
    }
}

// ---------------------------------------------------------------------------
// prep_b body: one block per output channel, coalesced reduce.
// ---------------------------------------------------------------------------
__device__ __forceinline__ void prepb_dev(const PrepArgs& P, int bid, float* ws4)
{
    int C, n, lv;
    if (bid < 128)      { C = 128; n = bid;       lv = 0; }
    else if (bid < 384) { C = 256; n = bid - 128; lv = 1; }
    else                { C = 512; n = bid - 384; lv = 2; }
    const float* sqw = P.sqw[lv];
    const float* oba = P.oba[lv];
    const float* obb = P.obb[lv];
    const float* sqb = P.sqb[lv];
    float* bp = P.bp[lv];

    const float* row = sqw + (size_t)n * 3 * C;
    float s = 0.f;
    for (int c = threadIdx.x; c < C; c += 256)
        s += row[C + c] * oba[c] + row[2 * C + c] * obb[c];
    #pragma unroll
    for (int off = 1; off < 64; off <<= 1)
        s += __shfl_xor(s, off);
    const int wv = threadIdx.x >> 6;
    if ((threadIdx.x & 63) == 0) ws4[wv] = s;
    __syncthreads();
    if (threadIdx.x == 0)
        bp[n] = sqb[n] + ws4[0] + ws4[1] + ws4[2] + ws4[3];
}

// ---------------------------------------------------------------------------
// stage1: fused qkv (all 3 levels) + prep_w + prep_b in ONE launch.
// ---------------------------------------------------------------------------
__global__ __launch_bounds__(256) void stage1(
    QkvLvl a0, QkvLvl a1, QkvLvl a2, PrepArgs P,
    int n0q, int n1q, int n2q, int npw)
{
    __shared__ __align__(16) u16 Xs[64][72];
    __shared__ __align__(16) u16 Ws[64][72];
    __shared__ float ws4[4];
    int bid = blockIdx.x;
    if (bid < n0q)                { qkv_dev(a0, bid, Xs, Ws); return; }
    bid -= n0q;
    if (bid < n1q)                { qkv_dev(a1, bid, Xs, Ws); return; }
    bid -= n1q;
    if (bid < n2q)                { qkv_dev(a2, bid, Xs, Ws); return; }
    bid -= n2q;
    if (bid < npw)                { prepw_dev(P, bid, Xs, Ws); return; }
    bid -= npw;
    prepb_dev(P, bid, ws4);
}

// ---------------------------------------------------------------------------
// squeeze body (identical to round 13) + fused all-levels kernel.
// ---------------------------------------------------------------------------
__device__ __forceinline__ void squeeze_dev(const SqLvl& A, int idx,
                                            u16 (*Xs)[72], u16 (*Ws)[72])
{
    const int n0 = (idx % A.gx) * 64;
    const int m0 = (idx / A.gx) * 64;
    const int C = A.C, L = A.L;
    const int K = 3 * C;
    const int tid = threadIdx.x;
    const int wid = tid >> 6, lane = tid & 63;
    const int lo = lane & 15, hi = lane >> 4;
    const int wm = wid >> 1, wn = wid & 1;
    const int bb = m0 / L;
    const int l0 = m0 - bb * L;

    f32x4 acc[2][2];
    #pragma unroll
    for (int i = 0; i < 2; ++i)
        #pragma unroll
        for (int j = 0; j < 2; ++j)
            #pragma unroll
            for (int rr = 0; rr < 4; ++rr) acc[i][j][rr] = 0.f;

    f32x4 xregf[4];
    u16x8 xreg[2];
    f32x4 wreg[4];
    const int kx = tid >> 4;
    const int lc = tid & 15;

    auto load_x = [&](int k0) {
        if (k0 < C) {
            #pragma unroll
            for (int i = 0; i < 4; ++i)
                xregf[i] = *(const f32x4*)&A.F1[((size_t)(bb * C) + k0 + kx + 16 * i) * L + l0 + lc * 4];
        } else {
            const u16* src = (k0 < 2 * C) ? A.X1 : A.X2;
            int kl = k0 - ((k0 < 2 * C) ? C : 2 * C);
            #pragma unroll
            for (int p = 0; p < 2; ++p) {
                int c = tid + p * 256;
                int row = c >> 3, kc = c & 7;
                xreg[p] = *(const u16x8*)&src[(size_t)(m0 + row) * C + kl + kc * 8];
            }
        }
    };
    auto store_x = [&](int k0) {
        if (k0 < C) {
            #pragma unroll
            for (int i = 0; i < 4; ++i)
                #pragma unroll
                for (int j = 0; j < 4; ++j)
                    Xs[lc * 4 + j][kx + 16 * i] = f2bf(xregf[i][j]);
        } else {
            #pragma unroll
            for (int p = 0; p < 2; ++p) {
                int c = tid + p * 256;
                int row = c >> 3, kc = c & 7;
                *(u16x8*)&Xs[row][kc * 8] = xreg[p];
            }
        }
    };
    auto load_w = [&](int k0) {
        #pragma unroll
        for (int p = 0; p < 4; ++p) {
            int c = tid + p * 256;
            int row = c >> 4, kc = c & 15;
            wreg[p] = *(const f32x4*)&A.W[(size_t)(n0 + row) * K + k0 + kc * 4];
        }
    };

    load_x(0);
    load_w(0);
    const int ns = K / 64;
    for (int s = 0; s < ns; ++s) {
        __syncthreads();
        store_x(s * 64);
        #pragma unroll
        for (int p = 0; p < 4; ++p) {
            int c = tid + p * 256;
            int row = c >> 4, kc = c & 15;
            u16x4 cv = {f2bf(wreg[p][0]), f2bf(wreg[p][1]),
                        f2bf(wreg[p][2]), f2bf(wreg[p][3])};
            *(u16x4*)&Ws[row][kc * 4] = cv;
        }
        __syncthreads();
        if (s + 1 < ns) { load_x((s + 1) * 64); load_w((s + 1) * 64); }
        #pragma unroll
        for (int kk = 0; kk < 2; ++kk) {
            short8 wf0 = *(const short8*)&Ws[wn * 32 + lo][kk * 32 + hi * 8];
            short8 wf1 = *(const short8*)&Ws[wn * 32 + 16 + lo][kk * 32 + hi * 8];
            short8 xf0 = *(const short8*)&Xs[wm * 32 + lo][kk * 32 + hi * 8];
            short8 xf1 = *(const short8*)&Xs[wm * 32 + 16 + lo][kk * 32 + hi * 8];
            acc[0][0] = __builtin_amdgcn_mfma_f32_16x16x32_bf16(wf0, xf0, acc[0][0], 0, 0, 0);
            acc[0][1] = __builtin_amdgcn_mfma_f32_16x16x32_bf16(wf1, xf0, acc[0][1], 0, 0, 0);
            acc[1][0] = __builtin_amdgcn_mfma_f32_16x16x32_bf16(wf0, xf1, acc[1][0], 0, 0, 0);
            acc[1][1] = __builtin_amdgcn_mfma_f32_16x16x32_bf16(wf1, xf1, acc[1][1], 0, 0, 0);
        }
    }

    #pragma unroll
    for (int nt = 0; nt < 2; ++nt) {
        const int nb = n0 + wn * 32 + nt * 16 + hi * 4;
        const float b0 = A.bias[nb + 0], b1 = A.bias[nb + 1];
        const float b2 = A.bias[nb + 2], b3 = A.bias[nb + 3];
        #pragma unroll
        for (int mt = 0; mt < 2; ++mt) {
            int m = m0 + wm * 32 + mt * 16 + lo;
            int b_ = m / L; int l = m - b_ * L;
            A.out[((size_t)(b_ * C + nb + 0)) * L + l] = acc[mt][nt][0] + b0;
            A.out[((size_t)(b_ * C + nb + 1)) * L + l] = acc[mt][nt][1] + b1;
            A.out[((size_t)(b_ * C + nb + 2)) * L + l] = acc[mt][nt][2] + b2;
            A.out[((size_t)(b_ * C + nb + 3)) * L + l] = acc[mt][nt][3] + b3;
        }
    }
}

__global__ __launch_bounds__(256) void squeeze_all(SqLvl s0, SqLvl s1, SqLvl s2)
{
    __shared__ __align__(16) u16 Xs[64][72];
    __shared__ __align__(16) u16 Ws[64][72];
    int bid = blockIdx.x;
    if (bid < s0.nblk)      { squeeze_dev(s0, bid, Xs, Ws); return; }
    bid -= s0.nblk;
    if (bid < s1.nblk)      { squeeze_dev(s1, bid, Xs, Ws); return; }
    bid -= s1.nblk;
    squeeze_dev(s2, bid, Xs, Ws);
}

// ---------------------------------------------------------------------------
// Generalized split flash (round-10 proven config, unchanged).
// ---------------------------------------------------------------------------
template <int DH, int NPAR, int NQS>
__global__ __launch_bounds__(128 * NPAR) void flash_split(
    const u16* __restrict__ Q1, const u16* __restrict__ K1,
    const u16* __restrict__ V1, u16* __restrict__ O1,
    const u16* __restrict__ Q2, const u16* __restrict__ K2,
    const u16* __restrict__ V2, u16* __restrict__ O2, int L, int S)
{
    constexpr int KB = 64;
    constexpr int QW = 16 * NQS;
    constexpr int QB = 2 * QW;
    constexpr int NKK = DH / 32;
    constexpr int NNT = DH / 16;
    constexpr int DG = DH / 8;
    constexpr int SLOTS = DG / 8;
    constexpr int SZ_VT = 2 * NPAR * DH * KB * 2;
    constexpr int MST = DH + 4;
    constexpr int P = NPAR - 1;

    __shared__ __align__(16) char smem[SZ_VT];
    u16 (*Vt)[NPAR][DH][KB] = (u16 (*)[NPAR][DH][KB])smem;
    float* MrgAcc = (float*)smem;
    float* MrgML  = (float*)(smem + (size_t)2 * P * QW * MST * 4);

    const int nQT = L / QB;
    const int perAtt = 2 * NHEADS * nQT;
    const int att = blockIdx.x / perAtt;
    const int rem = blockIdx.x - att * perAtt;
    const int qt = rem % nQT;
    const int bh = rem / nQT;
    const u16* __restrict__ Q = att ? Q2 : Q1;
    const u16* __restrict__ K = att ? K2 : K1;
    const u16* __restrict__ V = att ? V2 : V1;
    u16* __restrict__ O = att ? O2 : O1;

    const int tid = threadIdx.x;
    const int w = tid >> 6;
    const int lane = tid & 63;
    const int lo = lane & 15, hi = lane >> 4;
    const int qg = w & 1, par = w >> 1;
    const int q0 = qt * QB + qg * QW;

    short8 qf[NQS][NKK];
    #pragma unroll
    for (int qs = 0; qs < NQS; ++qs)
        #pragma unroll
        for (int kk = 0; kk < NKK; ++kk)
            qf[qs][kk] = *(const short8*)&Q[((size_t)bh * L + q0 + qs * 16 + lo) * DH + kk * 32 + hi * 8];

    f32x4 acc[NQS][NNT];
    #pragma unroll
    for (int qs = 0; qs < NQS; ++qs)
        #pragma unroll
        for (int nt = 0; nt < NNT; ++nt)
            #pragma unroll
            for (int r = 0; r < 4; ++r) acc[qs][nt][r] = 0.f;
    float m_i[NQS], l_i[NQS];
    #pragma unroll
    for (int qs = 0; qs < NQS; ++qs) { m_i[qs] = -1e30f; l_i[qs] = 0.f; }

    const u16* Kbase = K + (size_t)bh * S * DH;
    const u16* Vbase = V + (size_t)bh * S * DH;

    short8 kf[4][NKK];
    auto load_kf = [&](int r) {
        const u16* Kt = Kbase + (size_t)(NPAR * r + par) * KB * DH;
        #pragma unroll
        for (int st = 0; st < 4; ++st)
            #pragma unroll
            for (int kk = 0; kk < NKK; ++kk)
                kf[st][kk] = *(const short8*)&Kt[(size_t)(st * 16 + lo) * DH + kk * 32 + hi * 8];
    };

    const int pt = tid >> 7;
    const int u = tid & 127;
    int dV0[SLOTS], sV0[SLOTS];
    #pragma unroll
    for (int z = 0; z < SLOTS; ++z) {
        int e = u + z * 128;
        dV0[z] = (e % DG) * 8;
        sV0[z] = (e / DG) * 4;
    }

    u16x8 vreg[SLOTS][4];

    auto loadslots = [&](int r) {
        const u16* Vp = Vbase + (size_t)(NPAR * r + pt) * KB * DH;
        #pragma unroll
        for (int z = 0; z < SLOTS; ++z)
            #pragma unroll
            for (int si = 0; si < 4; ++si)
                vreg[z][si] = *(const u16x8*)&Vp[(size_t)(sV0[z] + si) * DH + dV0[z]];
    };
    auto writeslots = [&](int buf) {
        #pragma unroll
        for (int z = 0; z < SLOTS; ++z)
            #pragma unroll
            for (int j = 0; j < 8; ++j) {
                int d = dV0[z] + j;
                int g = ((d >> 3) ^ d) & 7;
                int scol = (sV0[z] & 7) | ((((sV0[z] >> 3) ^ g) & 7) << 3);
                u16x4 wj = {vreg[z][0][j], vreg[z][1][j], vreg[z][2][j], vreg[z][3][j]};
                *(u16x4*)&Vt[buf][pt][d][scol] = wj;
            }
    };

    const int NR = S / (KB * NPAR);

    load_kf(0);
    loadslots(0);
    writeslots(0);
    __syncthreads();
    if (1 < NR) loadslots(1);

    for (int r = 0; r < NR; ++r) {
        const int cur = r & 1;

        f32x4 sacc[4][NQS];
        #pragma unroll
        for (int st = 0; st < 4; ++st)
            #pragma unroll
            for (int qs = 0; qs < NQS; ++qs)
                #pragma unroll
                for (int rr = 0; rr < 4; ++rr) sacc[st][qs][rr] = 0.f;
        #pragma unroll
        for (int st = 0; st < 4; ++st) {
            #pragma unroll
            for (int kk = 0; kk < NKK; ++kk) {
                #pragma unroll
                for (int qs = 0; qs < NQS; ++qs)
                    sacc[st][qs] = __builtin_amdgcn_mfma_f32_16x16x32_bf16(
                        kf[st][kk], qf[qs][kk], sacc[st][qs], 0, 0, 0);
            }
        }

        if (r + 1 < NR) load_kf(r + 1);

        float mn[NQS], ts[NQS];
        #pragma unroll
        for (int qs = 0; qs < NQS; ++qs) {
            float tm = -1e30f;
            #pragma unroll
            for (int st = 0; st < 4; ++st)
                #pragma unroll
                for (int rr = 0; rr < 4; ++rr) tm = fmaxf(tm, sacc[st][qs][rr]);
            tm = fmaxf(tm, __shfl_xor(tm, 16));
            tm = fmaxf(tm, __shfl_xor(tm, 32));
            const bool grow = __any(tm > m_i[qs] + 8.0f);
            mn[qs] = grow ? fmaxf(m_i[qs], tm) : m_i[qs];
            ts[qs] = 0.f;
            if (grow) {
                float alpha = __builtin_amdgcn_exp2f(m_i[qs] - mn[qs]);
                m_i[qs] = mn[qs];
                l_i[qs] *= alpha;
                float ar[4];
                #pragma unroll
                for (int rr = 0; rr < 4; ++rr) ar[rr] = __shfl(alpha, hi * 4 + rr);
                #pragma unroll
                for (int nt = 0; nt < NNT; ++nt)
                    #pragma unroll
                    for (int rr = 0; rr < 4; ++rr) acc[qs][nt][rr] *= ar[rr];
            }
        }

        if (r + 1 < NR) writeslots(cur ^ 1);

        __builtin_amdgcn_s_setprio(1);
        #pragma unroll
        for (int st = 0; st < 4; ++st) {
            short4v pa_[NQS];
            #pragma unroll
            for (int qs = 0; qs < NQS; ++qs) {
                float p0 = __builtin_amdgcn_exp2f(sacc[st][qs][0] - mn[qs]);
                float p1 = __builtin_amdgcn_exp2f(sacc[st][qs][1] - mn[qs]);
                float p2 = __builtin_amdgcn_exp2f(sacc[st][qs][2] - mn[qs]);
                float p3 = __builtin_amdgcn_exp2f(sacc[st][qs][3] - mn[qs]);
                ts[qs] += (p0 + p1) + (p2 + p3);
                short4v pk = {(short)f2bf(p0), (short)f2bf(p1),
                              (short)f2bf(p2), (short)f2bf(p3)};
                pa_[qs] = pk;
            }
            const int s0 = st * 16 + hi * 4;
            #pragma unroll
            for (int nt = 0; nt < NNT; ++nt) {
                int d = nt * 16 + lo;
                int g = ((d >> 3) ^ d) & 7;
                int scol = (s0 & 7) | ((((s0 >> 3) ^ g) & 7) << 3);
                short4v vb = *(const short4v*)&Vt[cur][par][d][scol];
                #pragma unroll
                for (int qs = 0; qs < NQS; ++qs)
                    acc[qs][nt] = __builtin_amdgcn_mfma_f32_16x16x16bf16_1k(
                        pa_[qs], vb, acc[qs][nt], 0, 0, 0);
            }
        }
        __builtin_amdgcn_s_setprio(0);

        #pragma unroll
        for (int qs = 0; qs < NQS; ++qs) {
            float t2 = ts[qs];
            t2 += __shfl_xor(t2, 16);
            t2 += __shfl_xor(t2, 32);
            l_i[qs] += t2;
        }

        __syncthreads();
        if (r + 2 < NR) loadslots(r + 2);
    }

    const int b_ = bh / NHEADS, h_ = bh % NHEADS;
    if (par != 0) {
        const int mi = qg * P + par - 1;
        float* ma = MrgAcc + (size_t)mi * QW * MST;
        #pragma unroll
        for (int qs = 0; qs < NQS; ++qs) {
            #pragma unroll
            for (int nt = 0; nt < NNT; ++nt)
                #pragma unroll
                for (int rr = 0; rr < 4; ++rr)
                    ma[(size_t)(qs * 16 + hi * 4 + rr) * MST + nt * 16 + lo] = acc[qs][nt][rr];
            if (hi == 0) {
                MrgML[(mi * 2 + 0) * QW + qs * 16 + lo] = m_i[qs];
                MrgML[(mi * 2 + 1) * QW + qs * 16 + lo] = l_i[qs];
            }
        }
    }
    __syncthreads();
    if (par == 0) {
        #pragma unroll
        for (int qs = 0; qs < NQS; ++qs) {
            float mp[P > 0 ? P : 1], lp[P > 0 ? P : 1];
            float mt = m_i[qs];
            #pragma unroll
            for (int p = 0; p < P; ++p) {
                mp[p] = MrgML[((qg * P + p) * 2 + 0) * QW + qs * 16 + lo];
                lp[p] = MrgML[((qg * P + p) * 2 + 1) * QW + qs * 16 + lo];
                mt = fmaxf(mt, mp[p]);
            }
            float c0 = __builtin_amdgcn_exp2f(m_i[qs] - mt);
            float lt = c0 * l_i[qs];
            float cp[P > 0 ? P : 1];
            #pragma unroll
            for (int p = 0; p < P; ++p) {
                cp[p] = __builtin_amdgcn_exp2f(mp[p] - mt);
                lt += cp[p] * lp[p];
            }
            float linv = 1.0f / lt;
            c0 *= linv;
            #pragma unroll
            for (int p = 0; p < P; ++p) cp[p] *= linv;
            float c0r[4], cpr[P > 0 ? P : 1][4];
            #pragma unroll
            for (int rr = 0; rr < 4; ++rr) {
                c0r[rr] = __shfl(c0, hi * 4 + rr);
                #pragma unroll
                for (int p = 0; p < P; ++p) cpr[p][rr] = __shfl(cp[p], hi * 4 + rr);
            }
            #pragma unroll
            for (int nt = 0; nt < NNT; ++nt)
                #pragma unroll
                for (int rr = 0; rr < 4; ++rr) {
                    int q = qs * 16 + hi * 4 + rr;
                    float ov = acc[qs][nt][rr] * c0r[rr];
                    #pragma unroll
                    for (int p = 0; p < P; ++p)
                        ov += MrgAcc[((size_t)(qg * P + p) * QW + q) * MST + nt * 16 + lo] * cpr[p][rr];
                    O[(((size_t)b_ * L + q0 + q) * NHEADS + h_) * DH + nt * 16 + lo] = f2bf(ov);
                }
        }
    }
}

// ---------------------------------------------------------------------------
// Level-3 flash (unchanged): 128 threads, 2 waves, in-reg P.
// ---------------------------------------------------------------------------
template <int DH, int NQS, int PRE>
__global__ __launch_bounds__(128) void flash_mfma(
    const u16* __restrict__ Q1, const u16* __restrict__ K1,
    const u16* __restrict__ V1, u16* __restrict__ O1,
    const u16* __restrict__ Q2, const u16* __restrict__ K2,
    const u16* __restrict__ V2, u16* __restrict__ O2, int L, int S)
{
    constexpr int KB = 64;
    constexpr int QW = NQS * 16;
    constexpr int QB = 2 * QW;
    constexpr int DH8 = DH / 8;
    constexpr int KC = (KB * DH8) / 128;
    constexpr int VU = (16 * DH8) / 128;
    constexpr int NKK = DH / 32;
    constexpr int NNT = DH / 16;

    __shared__ __align__(16) u16 Ks[KB][DH + 8];
    __shared__ __align__(16) u16 Vt[DH][KB];

    const int nQT = L / QB;
    const int perAtt = 2 * NHEADS * nQT;
    const int att = blockIdx.x / perAtt;
    const int rem = blockIdx.x - att * perAtt;
    const int qt = rem % nQT;
    const int bh = rem / nQT;
    const u16* __restrict__ Q = att ? Q2 : Q1;
    const u16* __restrict__ K = att ? K2 : K1;
    const u16* __restrict__ V = att ? V2 : V1;
    u16* __restrict__ O = att ? O2 : O1;

    const int tid = threadIdx.x;
    const int wv = tid >> 6;
    const int lane = tid & 63;
    const int lo = lane & 15;
    const int hi = lane >> 4;
    const int q0 = qt * QB + wv * QW;

    short8 qf[NQS][NKK];
    #pragma unroll
    for (int qs = 0; qs < NQS; ++qs)
        #pragma unroll
        for (int kk = 0; kk < NKK; ++kk)
            qf[qs][kk] = *(const short8*)&Q[((size_t)bh * L + q0 + qs * 16 + lo) * DH + kk * 32 + hi * 8];

    f32x4 acc[NQS][NNT];
    #pragma unroll
    for (int qs = 0; qs < NQS; ++qs)
        #pragma unroll
        for (int nt = 0; nt < NNT; ++nt)
            #pragma unroll
            for (int r = 0; r < 4; ++r) acc[qs][nt][r] = 0.f;
    float m_i[NQS], l_i[NQS];
    #pragma unroll
    for (int qs = 0; qs < NQS; ++qs) { m_i[qs] = -1e30f; l_i[qs] = 0.f; }

    const int NT = S / KB;
    u16x8 kreg[PRE ? KC : 1];
    u16x8 vreg[PRE ? VU : 1][4];

    const u16* Kbase = K + (size_t)bh * S * DH;
    const u16* Vbase = V + (size_t)bh * S * DH;

    auto vwrite = [&](int d, int s0, u16x4 wj) {
        int g = ((d >> 3) ^ d) & 7;
        int scol = (s0 & 7) | ((((s0 >> 3) ^ g) & 7) << 3);
        *(u16x4*)&Vt[d][scol] = wj;
    };

    if (PRE) {
        #pragma unroll
        for (int i = 0; i < KC; ++i) {
            int idx = tid + i * 128;
            kreg[i] = *(const u16x8*)&Kbase[(size_t)(idx / DH8) * DH + (idx % DH8) * 8];
        }
        #pragma unroll
        for (int u = 0; u < VU; ++u) {
            int uu = tid + u * 128;
            int d0 = (uu % DH8) * 8, s0 = (uu / DH8) * 4;
            #pragma unroll
            for (int si = 0; si < 4; ++si)
                vreg[u][si] = *(const u16x8*)&Vbase[(size_t)(s0 + si) * DH + d0];
        }
    }

    for (int t = 0; t < NT; ++t) {
        __syncthreads();
        if (PRE) {
            #pragma unroll
            for (int i = 0; i < KC; ++i) {
                int idx = tid + i * 128;
                *(u16x8*)&Ks[idx / DH8][(idx % DH8) * 8] = kreg[i];
            }
            #pragma unroll
            for (int u = 0; u < VU; ++u) {
                int uu = tid + u * 128;
                int d0 = (uu % DH8) * 8, s0 = (uu / DH8) * 4;
                #pragma unroll
                for (int j = 0; j < 8; ++j) {
                    u16x4 wj = {vreg[u][0][j], vreg[u][1][j], vreg[u][2][j], vreg[u][3][j]};
                    vwrite(d0 + j, s0, wj);
                }
            }
        } else {
            const u16* Kp = Kbase + (size_t)t * KB * DH;
            const u16* Vp = Vbase + (size_t)t * KB * DH;
            #pragma unroll
            for (int i = 0; i < KC; ++i) {
                int idx = tid + i * 128;
                *(u16x8*)&Ks[idx / DH8][(idx % DH8) * 8] =
                    *(const u16x8*)&Kp[(size_t)(idx / DH8) * DH + (idx % DH8) * 8];
            }
            #pragma unroll
            for (int u = 0; u < VU; ++u) {
                int uu = tid + u * 128;
                int d0 = (uu % DH8) * 8, s0 = (uu / DH8) * 4;
                u16x8 v0 = *(const u16x8*)&Vp[(size_t)(s0 + 0) * DH + d0];
                u16x8 v1 = *(const u16x8*)&Vp[(size_t)(s0 + 1) * DH + d0];
                u16x8 v2 = *(const u16x8*)&Vp[(size_t)(s0 + 2) * DH + d0];
                u16x8 v3 = *(const u16x8*)&Vp[(size_t)(s0 + 3) * DH + d0];
                #pragma unroll
                for (int j = 0; j < 8; ++j) {
                    u16x4 wj = {v0[j], v1[j], v2[j], v3[j]};
                    vwrite(d0 + j, s0, wj);
                }
            }
        }
        __syncthreads();

        if (PRE && t + 1 < NT) {
            const u16* Kp = Kbase + (size_t)(t + 1) * KB * DH;
            const u16* Vp = Vbase + (size_t)(t + 1) * KB * DH;
            #pragma unroll
            for (int i = 0; i < KC; ++i) {
                int idx = tid + i * 128;
                kreg[i] = *(const u16x8*)&Kp[(size_t)(idx / DH8) * DH + (idx % DH8) * 8];
            }
            #pragma unroll
            for (int u = 0; u < VU; ++u) {
                int uu = tid + u * 128;
                int d0 = (uu % DH8) * 8, s0 = (uu / DH8) * 4;
                #pragma unroll
                for (int si = 0; si < 4; ++si)
                    vreg[u][si] = *(const u16x8*)&Vp[(size_t)(s0 + si) * DH + d0];
            }
        }

        f32x4 sacc[4][NQS];
        #pragma unroll
        for (int st = 0; st < 4; ++st)
            #pragma unroll
            for (int qs = 0; qs < NQS; ++qs)
                #pragma unroll
                for (int r = 0; r < 4; ++r) sacc[st][qs][r] = 0.f;
        #pragma unroll
        for (int st = 0; st < 4; ++st) {
            #pragma unroll
            for (int kk = 0; kk < NKK; ++kk) {
                short8 a = *(const short8*)&Ks[st * 16 + lo][kk * 32 + hi * 8];
                #pragma unroll
                for (int qs = 0; qs < NQS; ++qs)
                    sacc[st][qs] = __builtin_amdgcn_mfma_f32_16x16x32_bf16(
                        a, qf[qs][kk], sacc[st][qs], 0, 0, 0);
            }
        }

        float mn[NQS], ts[NQS];
        #pragma unroll
        for (int qs = 0; qs < NQS; ++qs) {
            float tm = -1e30f;
            #pragma unroll
            for (int st = 0; st < 4; ++st)
                #pragma unroll
                for (int r = 0; r < 4; ++r) tm = fmaxf(tm, sacc[st][qs][r]);
            tm = fmaxf(tm, __shfl_xor(tm, 16));
            tm = fmaxf(tm, __shfl_xor(tm, 32));
            const bool grow = __any(tm > m_i[qs] + 8.0f);
            mn[qs] = grow ? fmaxf(m_i[qs], tm) : m_i[qs];
            ts[qs] = 0.f;
            if (grow) {
                float alpha = __builtin_amdgcn_exp2f(m_i[qs] - mn[qs]);
                m_i[qs] = mn[qs];
                l_i[qs] *= alpha;
                float ar[4];
                #pragma unroll
                for (int r = 0; r < 4; ++r) ar[r] = __shfl(alpha, hi * 4 + r);
                #pragma unroll
                for (int nt = 0; nt < NNT; ++nt)
                    #pragma unroll
                    for (int r = 0; r < 4; ++r) acc[qs][nt][r] *= ar[r];
            }
        }

        #pragma unroll
        for (int st = 0; st < 4; ++st) {
            short4v pa_[NQS];
            #pragma unroll
            for (int qs = 0; qs < NQS; ++qs) {
                float p0 = __builtin_amdgcn_exp2f(sacc[st][qs][0] - mn[qs]);
                float p1 = __builtin_amdgcn_exp2f(sacc[st][qs][1] - mn[qs]);
                float p2 = __builtin_amdgcn_exp2f(sacc[st][qs][2] - mn[qs]);
                float p3 = __builtin_amdgcn_exp2f(sacc[st][qs][3] - mn[qs]);
                ts[qs] += (p0 + p1) + (p2 + p3);
                short4v pk = {(short)f2bf(p0), (short)f2bf(p1),
                              (short)f2bf(p2), (short)f2bf(p3)};
                pa_[qs] = pk;
            }
            const int s0 = st * 16 + hi * 4;
            #pragma unroll
            for (int nt = 0; nt < NNT; ++nt) {
                int d = nt * 16 + lo;
                int g = ((d >> 3) ^ d) & 7;
                int scol = (s0 & 7) | ((((s0 >> 3) ^ g) & 7) << 3);
                short4v vb = *(const short4v*)&Vt[d][scol];
                #pragma unroll
                for (int qs = 0; qs < NQS; ++qs)
                    acc[qs][nt] = __builtin_amdgcn_mfma_f32_16x16x16bf16_1k(
                        pa_[qs], vb, acc[qs][nt], 0, 0, 0);
            }
        }

        #pragma unroll
        for (int qs = 0; qs < NQS; ++qs) {
            float t2 = ts[qs];
            t2 += __shfl_xor(t2, 16);
            t2 += __shfl_xor(t2, 32);
            l_i[qs] += t2;
        }
    }

    const int b_ = bh / NHEADS, h_ = bh % NHEADS;
    #pragma unroll
    for (int qs = 0; qs < NQS; ++qs) {
        float inv = 1.0f / l_i[qs];
        float ir[4];
        #pragma unroll
        for (int r = 0; r < 4; ++r) ir[r] = __shfl(inv, hi * 4 + r);
        #pragma unroll
        for (int nt = 0; nt < NNT; ++nt)
            #pragma unroll
            for (int r = 0; r < 4; ++r) {
                int l = q0 + qs * 16 + hi * 4 + r;
                O[(((size_t)b_ * L + l) * NHEADS + h_) * DH + nt * 16 + lo] =
                    f2bf(acc[qs][nt][r] * ir[r]);
            }
    }
}

// ---------------------------------------------------------------------------

extern "C" void kernel_launch(void* const* d_in, const int* in_sizes, int n_in,
                              void* d_out, int out_size, void* d_ws, size_t ws_size,
                              hipStream_t stream)
{
    static const int CHs[4] = {64, 128, 256, 512};
    static const int HWs[4] = {128, 64, 32, 16};

    const float* f1[4] = {(const float*)d_in[0], (const float*)d_in[1],
                          (const float*)d_in[2], (const float*)d_in[3]};
    const float* f2[4] = {nullptr, (const float*)d_in[4], (const float*)d_in[6],
                          (const float*)d_in[8]};
    const float* f3[4] = {nullptr, (const float*)d_in[5], (const float*)d_in[7],
                          (const float*)d_in[9]};

    // level 0: pass-through
    size_t out0_elems = (size_t)in_sizes[0];
    hipMemcpyAsync(d_out, d_in[0], out0_elems * sizeof(float),
                   hipMemcpyDeviceToDevice, stream);

    // per-level sizes
    const size_t QE[3] = {(size_t)2 * NHEADS * 4096 * 64,
                          (size_t)2 * NHEADS * 1024 * 128,
                          (size_t)2 * NHEADS * 256 * 256};

    // workspace layout: per-level QKV (x6) + An (x2), then fp32 prep region.
    u16* p = (u16*)d_ws;
    u16 *Qa[3], *Ka[3], *Va[3], *Qb[3], *Kb[3], *Vb[3], *Ana[3], *Anb[3];
    for (int l = 0; l < 3; ++l) {
        Qa[l] = p; p += QE[l];  Ka[l] = p; p += QE[l];  Va[l] = p; p += QE[l];
        Qb[l] = p; p += QE[l];  Kb[l] = p; p += QE[l];  Vb[l] = p; p += QE[l];
        Ana[l] = p; p += QE[l]; Anb[l] = p; p += QE[l];
    }
    float* wp1 = (float*)p;
    float* wp2 = wp1 + (size_t)128 * 384;
    float* wp3 = wp2 + (size_t)256 * 768;
    float* bp1 = wp3 + (size_t)512 * 1536;
    float* bp2 = bp1 + 512;
    float* bp3 = bp2 + 512;

    const float LOG2E = 1.44269504088896340736f;

    // ---- build stage1 args
    QkvLvl qa[3];
    PrepArgs P;
    int nq[3];
    for (int l = 0; l < 3; ++l) {
        const int lvl = l + 1;
        const int C = CHs[lvl], Hs = HWs[lvl];
        const int L = Hs * Hs, dh = C / NHEADS, M = 2 * L;
        const int bi = 10 + l * 10;
        qa[l].f1 = f1[lvl]; qa[l].f2 = f2[lvl]; qa[l].f3 = f3[lvl];
        qa[l].w12 = (const float*)d_in[bi + 0];
        qa[l].b12 = (const float*)d_in[bi + 1];
        qa[l].w13 = (const float*)d_in[bi + 4];
        qa[l].b13 = (const float*)d_in[bi + 5];
        qa[l].Qa = Qa[l]; qa[l].Ka = Ka[l]; qa[l].Va = Va[l];
        qa[l].Qb = Qb[l]; qa[l].Kb = Kb[l]; qa[l].Vb = Vb[l];
        qa[l].C = C; qa[l].L = L; qa[l].dh = dh;
        qa[l].gx = 3 * C / 64;
        qa[l].perAtt = qa[l].gx * (M / 64);
        qa[l].qscale = LOG2E / sqrtf((float)dh);
        nq[l] = 2 * qa[l].perAtt;
        P.owa[l] = (const float*)d_in[bi + 2];
        P.oba[l] = (const float*)d_in[bi + 3];
        P.owb[l] = (const float*)d_in[bi + 6];
        P.obb[l] = (const float*)d_in[bi + 7];
        P.sqw[l] = (const float*)d_in[bi + 8];
        P.sqb[l] = (const float*)d_in[bi + 9];
    }
    P.wp[0] = wp1; P.wp[1] = wp2; P.wp[2] = wp3;
    P.bp[0] = bp1; P.bp[1] = bp2; P.bp[2] = bp3;

    const int NPW = 252, NPB = 896;
    const int totalS1 = nq[0] + nq[1] + nq[2] + NPW + NPB;

    // ---- 1) stage1: all qkv + prep (one launch)
    stage1<<<totalS1, 256, 0, stream>>>(qa[0], qa[1], qa[2], P,
                                        nq[0], nq[1], nq[2], NPW);

    // ---- 2) flash per level (round-10 proven configs)
    {
        const int L1 = 4096;
        flash_split<64, 4, 2><<<2 * (2 * NHEADS) * (L1 / 64), 512, 0, stream>>>(
            Qa[0], Ka[0], Va[0], Ana[0], Qb[0], Kb[0], Vb[0], Anb[0], L1, L1);
        const int L2 = 1024;
        flash_split<128, 2, 1><<<2 * (2 * NHEADS) * (L2 / 32), 256, 0, stream>>>(
            Qa[1], Ka[1], Va[1], Ana[1], Qb[1], Kb[1], Vb[1], Anb[1], L2, L2);
        const int L3 = 256;
        flash_mfma<256, 1, 0><<<2 * (2 * NHEADS) * (L3 / 32), 128, 0, stream>>>(
            Qa[2], Ka[2], Va[2], Ana[2], Qb[2], Kb[2], Vb[2], Anb[2], L3, L3);
    }

    // ---- 3) squeeze_all (one launch)
    SqLvl sq[3];
    size_t outOff = out0_elems;
    for (int l = 0; l < 3; ++l) {
        const int lvl = l + 1;
        const int C = CHs[lvl], Hs = HWs[lvl];
        const int L = Hs * Hs, M = 2 * L;
        sq[l].F1 = f1[lvl];
        sq[l].X1 = Ana[l]; sq[l].X2 = Anb[l];
        sq[l].W = (l == 0) ? wp1 : (l == 1) ? wp2 : wp3;
        sq[l].bias = (l == 0) ? bp1 : (l == 1) ? bp2 : bp3;
        sq[l].out = (float*)d_out + outOff;
        sq[l].M = M; sq[l].C = C; sq[l].L = L;
        sq[l].gx = C / 64;
        sq[l].nblk = sq[l].gx * (M / 64);
        outOff += (size_t)2 * C * L;
    }
    squeeze_all<<<sq[0].nblk + sq[1].nblk + sq[2].nblk, 256, 0, stream>>>(
        sq[0], sq[1], sq[2]);
}

// Round 15
// 256.142 us; speedup vs baseline: 1.3629x; 1.3629x over previous
//
#include <hip/hip_runtime.h>
#include <hip/hip_bf16.h>
#include <math.h>

#define NHEADS 2

typedef unsigned short u16;
typedef __attribute__((ext_vector_type(8))) unsigned short u16x8;
typedef __attribute__((ext_vector_type(4))) unsigned short u16x4;
typedef __attribute__((ext_vector_type(8))) short short8;
typedef __attribute__((ext_vector_type(4))) short short4v;
typedef __attribute__((ext_vector_type(4))) float f32x4;

__device__ __forceinline__ u16 f2bf(float x) {
    __hip_bfloat16 h = __float2bfloat16(x);
    return __builtin_bit_cast(unsigned short, h);
}

// ---------------------------------------------------------------------------
// Fused qkv GEMM, both attentions in one launch (round-13 proven).
// X read directly from fp32 [b, c, l] maps with transposing LDS stage.
// ---------------------------------------------------------------------------
__global__ __launch_bounds__(256) void gemm_qkv(
    const float* __restrict__ f1, const float* __restrict__ f2,
    const float* __restrict__ f3,
    const float* __restrict__ w12, const float* __restrict__ b12,
    const float* __restrict__ w13, const float* __restrict__ b13,
    u16* __restrict__ Qa, u16* __restrict__ Ka, u16* __restrict__ Va,
    u16* __restrict__ Qb, u16* __restrict__ Kb, u16* __restrict__ Vb,
    int M, int C, int L, int dh, float qscale, int gx, int perAtt)
{
    const int att = blockIdx.x / perAtt;
    const int r = blockIdx.x - att * perAtt;
    const int n0 = (r % gx) * 64;
    const int m0 = (r / gx) * 64;
    const int K = C;
    __shared__ __align__(16) u16 Xs[64][72];
    __shared__ __align__(16) u16 Ws[64][72];
    const int tid = threadIdx.x;
    const int wid = tid >> 6, lane = tid & 63;
    const int lo = lane & 15, hi = lane >> 4;
    const int wm = wid >> 1, wn = wid & 1;

    const float* __restrict__ Xf = (n0 < C) ? f1 : (att ? f3 : f2);
    const float* __restrict__ W = att ? w13 : w12;
    const float* __restrict__ bias = att ? b13 : b12;
    const int bb = m0 / L;
    const int l0 = m0 - bb * L;

    f32x4 acc[2][2];
    #pragma unroll
    for (int i = 0; i < 2; ++i)
        #pragma unroll
        for (int j = 0; j < 2; ++j)
            #pragma unroll
            for (int rr = 0; rr < 4; ++rr) acc[i][j][rr] = 0.f;

    f32x4 xregf[4];
    f32x4 wreg[4];
    const int kx = tid >> 4;      // k row within 16-row pass
    const int lc = tid & 15;      // float4 chunk along l

    auto load_x = [&](int k0) {
        #pragma unroll
        for (int i = 0; i < 4; ++i)
            xregf[i] = *(const f32x4*)&Xf[((size_t)(bb * C) + k0 + kx + 16 * i) * L + l0 + lc * 4];
    };
    auto store_x = [&]() {
        #pragma unroll
        for (int i = 0; i < 4; ++i)
            #pragma unroll
            for (int j = 0; j < 4; ++j)
                Xs[lc * 4 + j][kx + 16 * i] = f2bf(xregf[i][j]);
    };
    auto load_w = [&](int k0) {
        #pragma unroll
        for (int p = 0; p < 4; ++p) {
            int c = tid + p * 256;
            int row = c >> 4, kc = c & 15;
            wreg[p] = *(const f32x4*)&W[(size_t)(n0 + row) * K + k0 + kc * 4];
        }
    };

    load_x(0);
    load_w(0);
    const int ns = K / 64;
    for (int s = 0; s < ns; ++s) {
        __syncthreads();
        store_x();
        #pragma unroll
        for (int p = 0; p < 4; ++p) {
            int c = tid + p * 256;
            int row = c >> 4, kc = c & 15;
            u16x4 cv = {f2bf(wreg[p][0]), f2bf(wreg[p][1]),
                        f2bf(wreg[p][2]), f2bf(wreg[p][3])};
            *(u16x4*)&Ws[row][kc * 4] = cv;
        }
        __syncthreads();
        if (s + 1 < ns) { load_x((s + 1) * 64); load_w((s + 1) * 64); }
        #pragma unroll
        for (int kk = 0; kk < 2; ++kk) {
            short8 wf0 = *(const short8*)&Ws[wn * 32 + lo][kk * 32 + hi * 8];
            short8 wf1 = *(const short8*)&Ws[wn * 32 + 16 + lo][kk * 32 + hi * 8];
            short8 xf0 = *(const short8*)&Xs[wm * 32 + lo][kk * 32 + hi * 8];
            short8 xf1 = *(const short8*)&Xs[wm * 32 + 16 + lo][kk * 32 + hi * 8];
            acc[0][0] = __builtin_amdgcn_mfma_f32_16x16x32_bf16(wf0, xf0, acc[0][0], 0, 0, 0);
            acc[0][1] = __builtin_amdgcn_mfma_f32_16x16x32_bf16(wf1, xf0, acc[0][1], 0, 0, 0);
            acc[1][0] = __builtin_amdgcn_mfma_f32_16x16x32_bf16(wf0, xf1, acc[1][0], 0, 0, 0);
            acc[1][1] = __builtin_amdgcn_mfma_f32_16x16x32_bf16(wf1, xf1, acc[1][1], 0, 0, 0);
        }
    }

    #pragma unroll
    for (int nt = 0; nt < 2; ++nt) {
        const int nb = n0 + wn * 32 + nt * 16 + hi * 4;
        const float b0 = bias[nb + 0], b1 = bias[nb + 1];
        const float b2 = bias[nb + 2], b3 = bias[nb + 3];
        const int which = nb / C;
        const int co = nb - which * C;
        const int h = co / dh;
        const int dd = co - h * dh;
        u16* dst = (which == 0) ? (att ? Qb : Qa)
                 : (which == 1) ? (att ? Kb : Ka) : (att ? Vb : Va);
        const float sc = (which == 0) ? qscale : 1.0f;
        #pragma unroll
        for (int mt = 0; mt < 2; ++mt) {
            int m = m0 + wm * 32 + mt * 16 + lo;
            int b_ = m / L; int l = m - b_ * L;
            u16x4 pk = {f2bf((acc[mt][nt][0] + b0) * sc),
                        f2bf((acc[mt][nt][1] + b1) * sc),
                        f2bf((acc[mt][nt][2] + b2) * sc),
                        f2bf((acc[mt][nt][3] + b3) * sc)};
            *(u16x4*)&dst[((size_t)(b_ * NHEADS + h) * L + l) * dh + dd] = pk;
        }
    }
}

// ---------------------------------------------------------------------------
// prep_all: prep_w (blocks 0..251) + prep_b (blocks 252..1147), one launch.
// Bodies identical to round 13. Independent work items; combined footprint
// ~8 MB (L2-safe; round-14 lesson: fuse only if working set stays resident).
// ---------------------------------------------------------------------------
__global__ __launch_bounds__(256) void prep_all(
    const float* __restrict__ s1, const float* __restrict__ oa1,
    const float* __restrict__ ob1, const float* __restrict__ oba1,
    const float* __restrict__ obb1, const float* __restrict__ sqb1,
    float* __restrict__ w1, float* __restrict__ b1,
    const float* __restrict__ s2, const float* __restrict__ oa2,
    const float* __restrict__ ob2, const float* __restrict__ oba2,
    const float* __restrict__ obb2, const float* __restrict__ sqb2,
    float* __restrict__ w2, float* __restrict__ b2,
    const float* __restrict__ s3, const float* __restrict__ oa3,
    const float* __restrict__ ob3, const float* __restrict__ oba3,
    const float* __restrict__ obb3, const float* __restrict__ sqb3,
    float* __restrict__ w3, float* __restrict__ b3)
{
    const int tid = threadIdx.x;
    if (blockIdx.x < 252) {
        // ---- prep_w path
        int bid = blockIdx.x;
        int C; const float *sqw, *owa, *owb; float* wp;
        if (bid < 12)      { C = 128; sqw = s1; owa = oa1; owb = ob1; wp = w1; }
        else if (bid < 60) { bid -= 12; C = 256; sqw = s2; owa = oa2; owb = ob2; wp = w2; }
        else               { bid -= 60; C = 512; sqw = s3; owa = oa3; owb = ob3; wp = w3; }
        const int K3 = 3 * C;
        const int gxw = K3 / 64;
        const int n0 = (bid / gxw) * 64;
        const int kc0 = (bid % gxw) * 64;

        if (kc0 < C) {
            for (int p = tid; p < 64 * 64; p += 256) {
                int i = p >> 6, j = p & 63;
                wp[(size_t)(n0 + i) * K3 + kc0 + j] = sqw[(size_t)(n0 + i) * K3 + kc0 + j];
            }
            return;
        }
        const int which = kc0 / C;
        const int kp0 = kc0 - which * C;
        const float* __restrict__ ow = (which == 1) ? owa : owb;

        __shared__ __align__(16) u16 As[64][72];
        __shared__ __align__(16) u16 Bs[64][72];
        const int wid = tid >> 6, lane = tid & 63;
        const int lo = lane & 15, hi = lane >> 4;
        const int wm = wid >> 1, wn = wid & 1;

        f32x4 acc[2][2];
        #pragma unroll
        for (int i = 0; i < 2; ++i)
            #pragma unroll
            for (int j = 0; j < 2; ++j)
                #pragma unroll
                for (int rr = 0; rr < 4; ++rr) acc[i][j][rr] = 0.f;

        for (int ct = 0; ct < C / 64; ++ct) {
            __syncthreads();
            for (int p = tid; p < 64 * 64; p += 256) {
                int i = p >> 6, j = p & 63;
                As[i][j] = f2bf(sqw[(size_t)(n0 + i) * K3 + which * C + ct * 64 + j]);
                Bs[j][i] = f2bf(ow[(size_t)(ct * 64 + i) * C + kp0 + j]);
            }
            __syncthreads();
            #pragma unroll
            for (int kk = 0; kk < 2; ++kk) {
                short8 wf0 = *(const short8*)&As[wn * 32 + lo][kk * 32 + hi * 8];
                short8 wf1 = *(const short8*)&As[wn * 32 + 16 + lo][kk * 32 + hi * 8];
                short8 xf0 = *(const short8*)&Bs[wm * 32 + lo][kk * 32 + hi * 8];
                short8 xf1 = *(const short8*)&Bs[wm * 32 + 16 + lo][kk * 32 + hi * 8];
                acc[0][0] = __builtin_amdgcn_mfma_f32_16x16x32_bf16(wf0, xf0, acc[0][0], 0, 0, 0);
                acc[0][1] = __builtin_amdgcn_mfma_f32_16x16x32_bf16(wf1, xf0, acc[0][1], 0, 0, 0);
                acc[1][0] = __builtin_amdgcn_mfma_f32_16x16x32_bf16(wf0, xf1, acc[1][0], 0, 0, 0);
                acc[1][1] = __builtin_amdgcn_mfma_f32_16x16x32_bf16(wf1, xf1, acc[1][1], 0, 0, 0);
            }
        }
        #pragma unroll
        for (int nt = 0; nt < 2; ++nt) {
            const int nb = n0 + wn * 32 + nt * 16 + hi * 4;
            #pragma unroll
            for (int mt = 0; mt < 2; ++mt) {
                const int col = kc0 + wm * 32 + mt * 16 + lo;
                #pragma unroll
                for (int rr = 0; rr < 4; ++rr)
                    wp[(size_t)(nb + rr) * K3 + col] = acc[mt][nt][rr];
            }
        }
        return;
    }

    // ---- prep_b path
    int bid = blockIdx.x - 252;
    int C, n;
    const float *sqw, *oba, *obb, *sqb; float* bp;
    if (bid < 128)      { C = 128; n = bid;       sqw = s1; oba = oba1; obb = obb1; sqb = sqb1; bp = b1; }
    else if (bid < 384) { C = 256; n = bid - 128; sqw = s2; oba = oba2; obb = obb2; sqb = sqb2; bp = b2; }
    else                { C = 512; n = bid - 384; sqw = s3; oba = oba3; obb = obb3; sqb = sqb3; bp = b3; }

    const float* row = sqw + (size_t)n * 3 * C;
    float s = 0.f;
    for (int c = tid; c < C; c += 256)
        s += row[C + c] * oba[c] + row[2 * C + c] * obb[c];
    #pragma unroll
    for (int off = 1; off < 64; off <<= 1)
        s += __shfl_xor(s, off);
    __shared__ float ws[4];
    const int wv = tid >> 6;
    if ((tid & 63) == 0) ws[wv] = s;
    __syncthreads();
    if (tid == 0)
        bp[n] = sqb[n] + ws[0] + ws[1] + ws[2] + ws[3];
}

// ---------------------------------------------------------------------------
// Squeeze GEMM (round-13 proven): k<C from fp32 f1 (transposing stage),
// k>=C from Ana/Anb (bf16); W = prepped Wp; out fp32 [b][n][l].
// ---------------------------------------------------------------------------
__global__ __launch_bounds__(256) void gemm_squeeze(
    const float* __restrict__ F1, const u16* __restrict__ X1,
    const u16* __restrict__ X2,
    const float* __restrict__ W, const float* __restrict__ bias,
    float* __restrict__ out, int M, int C, int L)
{
    const int n0 = blockIdx.x * 64;
    const int m0 = blockIdx.y * 64;
    const int K = 3 * C;
    __shared__ __align__(16) u16 Xs[64][72];
    __shared__ __align__(16) u16 Ws[64][72];
    const int tid = threadIdx.x;
    const int wid = tid >> 6, lane = tid & 63;
    const int lo = lane & 15, hi = lane >> 4;
    const int wm = wid >> 1, wn = wid & 1;
    const int bb = m0 / L;
    const int l0 = m0 - bb * L;

    f32x4 acc[2][2];
    #pragma unroll
    for (int i = 0; i < 2; ++i)
        #pragma unroll
        for (int j = 0; j < 2; ++j)
            #pragma unroll
            for (int rr = 0; rr < 4; ++rr) acc[i][j][rr] = 0.f;

    f32x4 xregf[4];
    u16x8 xreg[2];
    f32x4 wreg[4];
    const int kx = tid >> 4;
    const int lc = tid & 15;

    auto load_x = [&](int k0) {
        if (k0 < C) {
            #pragma unroll
            for (int i = 0; i < 4; ++i)
                xregf[i] = *(const f32x4*)&F1[((size_t)(bb * C) + k0 + kx + 16 * i) * L + l0 + lc * 4];
        } else {
            const u16* src = (k0 < 2 * C) ? X1 : X2;
            int kl = k0 - ((k0 < 2 * C) ? C : 2 * C);
            #pragma unroll
            for (int p = 0; p < 2; ++p) {
                int c = tid + p * 256;
                int row = c >> 3, kc = c & 7;
                xreg[p] = *(const u16x8*)&src[(size_t)(m0 + row) * C + kl + kc * 8];
            }
        }
    };
    auto store_x = [&](int k0) {
        if (k0 < C) {
            #pragma unroll
            for (int i = 0; i < 4; ++i)
                #pragma unroll
                for (int j = 0; j < 4; ++j)
                    Xs[lc * 4 + j][kx + 16 * i] = f2bf(xregf[i][j]);
        } else {
            #pragma unroll
            for (int p = 0; p < 2; ++p) {
                int c = tid + p * 256;
                int row = c >> 3, kc = c & 7;
                *(u16x8*)&Xs[row][kc * 8] = xreg[p];
            }
        }
    };
    auto load_w = [&](int k0) {
        #pragma unroll
        for (int p = 0; p < 4; ++p) {
            int c = tid + p * 256;
            int row = c >> 4, kc = c & 15;
            wreg[p] = *(const f32x4*)&W[(size_t)(n0 + row) * K + k0 + kc * 4];
        }
    };

    load_x(0);
    load_w(0);
    const int ns = K / 64;
    for (int s = 0; s < ns; ++s) {
        __syncthreads();
        store_x(s * 64);
        #pragma unroll
        for (int p = 0; p < 4; ++p) {
            int c = tid + p * 256;
            int row = c >> 4, kc = c & 15;
            u16x4 cv = {f2bf(wreg[p][0]), f2bf(wreg[p][1]),
                        f2bf(wreg[p][2]), f2bf(wreg[p][3])};
            *(u16x4*)&Ws[row][kc * 4] = cv;
        }
        __syncthreads();
        if (s + 1 < ns) { load_x((s + 1) * 64); load_w((s + 1) * 64); }
        #pragma unroll
        for (int kk = 0; kk < 2; ++kk) {
            short8 wf0 = *(const short8*)&Ws[wn * 32 + lo][kk * 32 + hi * 8];
            short8 wf1 = *(const short8*)&Ws[wn * 32 + 16 + lo][kk * 32 + hi * 8];
            short8 xf0 = *(const short8*)&Xs[wm * 32 + lo][kk * 32 + hi * 8];
            short8 xf1 = *(const short8*)&Xs[wm * 32 + 16 + lo][kk * 32 + hi * 8];
            acc[0][0] = __builtin_amdgcn_mfma_f32_16x16x32_bf16(wf0, xf0, acc[0][0], 0, 0, 0);
            acc[0][1] = __builtin_amdgcn_mfma_f32_16x16x32_bf16(wf1, xf0, acc[0][1], 0, 0, 0);
            acc[1][0] = __builtin_amdgcn_mfma_f32_16x16x32_bf16(wf0, xf1, acc[1][0], 0, 0, 0);
            acc[1][1] = __builtin_amdgcn_mfma_f32_16x16x32_bf16(wf1, xf1, acc[1][1], 0, 0, 0);
        }
    }

    #pragma unroll
    for (int nt = 0; nt < 2; ++nt) {
        const int nb = n0 + wn * 32 + nt * 16 + hi * 4;
        const float b0 = bias[nb + 0], b1 = bias[nb + 1];
        const float b2 = bias[nb + 2], b3 = bias[nb + 3];
        #pragma unroll
        for (int mt = 0; mt < 2; ++mt) {
            int m = m0 + wm * 32 + mt * 16 + lo;
            int b_ = m / L; int l = m - b_ * L;
            out[((size_t)(b_ * C + nb + 0)) * L + l] = acc[mt][nt][0] + b0;
            out[((size_t)(b_ * C + nb + 1)) * L + l] = acc[mt][nt][1] + b1;
            out[((size_t)(b_ * C + nb + 2)) * L + l] = acc[mt][nt][2] + b2;
            out[((size_t)(b_ * C + nb + 3)) * L + l] = acc[mt][nt][3] + b3;
        }
    }
}

// ---------------------------------------------------------------------------
// Generalized split flash (round-10 proven config, unchanged).
// ---------------------------------------------------------------------------
template <int DH, int NPAR, int NQS>
__global__ __launch_bounds__(128 * NPAR) void flash_split(
    const u16* __restrict__ Q1, const u16* __restrict__ K1,
    const u16* __restrict__ V1, u16* __restrict__ O1,
    const u16* __restrict__ Q2, const u16* __restrict__ K2,
    const u16* __restrict__ V2, u16* __restrict__ O2, int L, int S)
{
    constexpr int KB = 64;
    constexpr int QW = 16 * NQS;
    constexpr int QB = 2 * QW;
    constexpr int NKK = DH / 32;
    constexpr int NNT = DH / 16;
    constexpr int DG = DH / 8;
    constexpr int SLOTS = DG / 8;
    constexpr int SZ_VT = 2 * NPAR * DH * KB * 2;
    constexpr int MST = DH + 4;
    constexpr int P = NPAR - 1;

    __shared__ __align__(16) char smem[SZ_VT];
    u16 (*Vt)[NPAR][DH][KB] = (u16 (*)[NPAR][DH][KB])smem;
    float* MrgAcc = (float*)smem;
    float* MrgML  = (float*)(smem + (size_t)2 * P * QW * MST * 4);

    const int nQT = L / QB;
    const int perAtt = 2 * NHEADS * nQT;
    const int att = blockIdx.x / perAtt;
    const int rem = blockIdx.x - att * perAtt;
    const int qt = rem % nQT;
    const int bh = rem / nQT;
    const u16* __restrict__ Q = att ? Q2 : Q1;
    const u16* __restrict__ K = att ? K2 : K1;
    const u16* __restrict__ V = att ? V2 : V1;
    u16* __restrict__ O = att ? O2 : O1;

    const int tid = threadIdx.x;
    const int w = tid >> 6;
    const int lane = tid & 63;
    const int lo = lane & 15, hi = lane >> 4;
    const int qg = w & 1, par = w >> 1;
    const int q0 = qt * QB + qg * QW;

    short8 qf[NQS][NKK];
    #pragma unroll
    for (int qs = 0; qs < NQS; ++qs)
        #pragma unroll
        for (int kk = 0; kk < NKK; ++kk)
            qf[qs][kk] = *(const short8*)&Q[((size_t)bh * L + q0 + qs * 16 + lo) * DH + kk * 32 + hi * 8];

    f32x4 acc[NQS][NNT];
    #pragma unroll
    for (int qs = 0; qs < NQS; ++qs)
        #pragma unroll
        for (int nt = 0; nt < NNT; ++nt)
            #pragma unroll
            for (int r = 0; r < 4; ++r) acc[qs][nt][r] = 0.f;
    float m_i[NQS], l_i[NQS];
    #pragma unroll
    for (int qs = 0; qs < NQS; ++qs) { m_i[qs] = -1e30f; l_i[qs] = 0.f; }

    const u16* Kbase = K + (size_t)bh * S * DH;
    const u16* Vbase = V + (size_t)bh * S * DH;

    short8 kf[4][NKK];
    auto load_kf = [&](int r) {
        const u16* Kt = Kbase + (size_t)(NPAR * r + par) * KB * DH;
        #pragma unroll
        for (int st = 0; st < 4; ++st)
            #pragma unroll
            for (int kk = 0; kk < NKK; ++kk)
                kf[st][kk] = *(const short8*)&Kt[(size_t)(st * 16 + lo) * DH + kk * 32 + hi * 8];
    };

    const int pt = tid >> 7;
    const int u = tid & 127;
    int dV0[SLOTS], sV0[SLOTS];
    #pragma unroll
    for (int z = 0; z < SLOTS; ++z) {
        int e = u + z * 128;
        dV0[z] = (e % DG) * 8;
        sV0[z] = (e / DG) * 4;
    }

    u16x8 vreg[SLOTS][4];

    auto loadslots = [&](int r) {
        const u16* Vp = Vbase + (size_t)(NPAR * r + pt) * KB * DH;
        #pragma unroll
        for (int z = 0; z < SLOTS; ++z)
            #pragma unroll
            for (int si = 0; si < 4; ++si)
                vreg[z][si] = *(const u16x8*)&Vp[(size_t)(sV0[z] + si) * DH + dV0[z]];
    };
    auto writeslots = [&](int buf) {
        #pragma unroll
        for (int z = 0; z < SLOTS; ++z)
            #pragma unroll
            for (int j = 0; j < 8; ++j) {
                int d = dV0[z] + j;
                int g = ((d >> 3) ^ d) & 7;
                int scol = (sV0[z] & 7) | ((((sV0[z] >> 3) ^ g) & 7) << 3);
                u16x4 wj = {vreg[z][0][j], vreg[z][1][j], vreg[z][2][j], vreg[z][3][j]};
                *(u16x4*)&Vt[buf][pt][d][scol] = wj;
            }
    };

    const int NR = S / (KB * NPAR);

    load_kf(0);
    loadslots(0);
    writeslots(0);
    __syncthreads();
    if (1 < NR) loadslots(1);

    for (int r = 0; r < NR; ++r) {
        const int cur = r & 1;

        f32x4 sacc[4][NQS];
        #pragma unroll
        for (int st = 0; st < 4; ++st)
            #pragma unroll
            for (int qs = 0; qs < NQS; ++qs)
                #pragma unroll
                for (int rr = 0; rr < 4; ++rr) sacc[st][qs][rr] = 0.f;
        #pragma unroll
        for (int st = 0; st < 4; ++st) {
            #pragma unroll
            for (int kk = 0; kk < NKK; ++kk) {
                #pragma unroll
                for (int qs = 0; qs < NQS; ++qs)
                    sacc[st][qs] = __builtin_amdgcn_mfma_f32_16x16x32_bf16(
                        kf[st][kk], qf[qs][kk], sacc[st][qs], 0, 0, 0);
            }
        }

        if (r + 1 < NR) load_kf(r + 1);

        float mn[NQS], ts[NQS];
        #pragma unroll
        for (int qs = 0; qs < NQS; ++qs) {
            float tm = -1e30f;
            #pragma unroll
            for (int st = 0; st < 4; ++st)
                #pragma unroll
                for (int rr = 0; rr < 4; ++rr) tm = fmaxf(tm, sacc[st][qs][rr]);
            tm = fmaxf(tm, __shfl_xor(tm, 16));
            tm = fmaxf(tm, __shfl_xor(tm, 32));
            const bool grow = __any(tm > m_i[qs] + 8.0f);
            mn[qs] = grow ? fmaxf(m_i[qs], tm) : m_i[qs];
            ts[qs] = 0.f;
            if (grow) {
                float alpha = __builtin_amdgcn_exp2f(m_i[qs] - mn[qs]);
                m_i[qs] = mn[qs];
                l_i[qs] *= alpha;
                float ar[4];
                #pragma unroll
                for (int rr = 0; rr < 4; ++rr) ar[rr] = __shfl(alpha, hi * 4 + rr);
                #pragma unroll
                for (int nt = 0; nt < NNT; ++nt)
                    #pragma unroll
                    for (int rr = 0; rr < 4; ++rr) acc[qs][nt][rr] *= ar[rr];
            }
        }

        if (r + 1 < NR) writeslots(cur ^ 1);

        __builtin_amdgcn_s_setprio(1);
        #pragma unroll
        for (int st = 0; st < 4; ++st) {
            short4v pa_[NQS];
            #pragma unroll
            for (int qs = 0; qs < NQS; ++qs) {
                float p0 = __builtin_amdgcn_exp2f(sacc[st][qs][0] - mn[qs]);
                float p1 = __builtin_amdgcn_exp2f(sacc[st][qs][1] - mn[qs]);
                float p2 = __builtin_amdgcn_exp2f(sacc[st][qs][2] - mn[qs]);
                float p3 = __builtin_amdgcn_exp2f(sacc[st][qs][3] - mn[qs]);
                ts[qs] += (p0 + p1) + (p2 + p3);
                short4v pk = {(short)f2bf(p0), (short)f2bf(p1),
                              (short)f2bf(p2), (short)f2bf(p3)};
                pa_[qs] = pk;
            }
            const int s0 = st * 16 + hi * 4;
            #pragma unroll
            for (int nt = 0; nt < NNT; ++nt) {
                int d = nt * 16 + lo;
                int g = ((d >> 3) ^ d) & 7;
                int scol = (s0 & 7) | ((((s0 >> 3) ^ g) & 7) << 3);
                short4v vb = *(const short4v*)&Vt[cur][par][d][scol];
                #pragma unroll
                for (int qs = 0; qs < NQS; ++qs)
                    acc[qs][nt] = __builtin_amdgcn_mfma_f32_16x16x16bf16_1k(
                        pa_[qs], vb, acc[qs][nt], 0, 0, 0);
            }
        }
        __builtin_amdgcn_s_setprio(0);

        #pragma unroll
        for (int qs = 0; qs < NQS; ++qs) {
            float t2 = ts[qs];
            t2 += __shfl_xor(t2, 16);
            t2 += __shfl_xor(t2, 32);
            l_i[qs] += t2;
        }

        __syncthreads();
        if (r + 2 < NR) loadslots(r + 2);
    }

    const int b_ = bh / NHEADS, h_ = bh % NHEADS;
    if (par != 0) {
        const int mi = qg * P + par - 1;
        float* ma = MrgAcc + (size_t)mi * QW * MST;
        #pragma unroll
        for (int qs = 0; qs < NQS; ++qs) {
            #pragma unroll
            for (int nt = 0; nt < NNT; ++nt)
                #pragma unroll
                for (int rr = 0; rr < 4; ++rr)
                    ma[(size_t)(qs * 16 + hi * 4 + rr) * MST + nt * 16 + lo] = acc[qs][nt][rr];
            if (hi == 0) {
                MrgML[(mi * 2 + 0) * QW + qs * 16 + lo] = m_i[qs];
                MrgML[(mi * 2 + 1) * QW + qs * 16 + lo] = l_i[qs];
            }
        }
    }
    __syncthreads();
    if (par == 0) {
        #pragma unroll
        for (int qs = 0; qs < NQS; ++qs) {
            float mp[P > 0 ? P : 1], lp[P > 0 ? P : 1];
            float mt = m_i[qs];
            #pragma unroll
            for (int p = 0; p < P; ++p) {
                mp[p] = MrgML[((qg * P + p) * 2 + 0) * QW + qs * 16 + lo];
                lp[p] = MrgML[((qg * P + p) * 2 + 1) * QW + qs * 16 + lo];
                mt = fmaxf(mt, mp[p]);
            }
            float c0 = __builtin_amdgcn_exp2f(m_i[qs] - mt);
            float lt = c0 * l_i[qs];
            float cp[P > 0 ? P : 1];
            #pragma unroll
            for (int p = 0; p < P; ++p) {
                cp[p] = __builtin_amdgcn_exp2f(mp[p] - mt);
                lt += cp[p] * lp[p];
            }
            float linv = 1.0f / lt;
            c0 *= linv;
            #pragma unroll
            for (int p = 0; p < P; ++p) cp[p] *= linv;
            float c0r[4], cpr[P > 0 ? P : 1][4];
            #pragma unroll
            for (int rr = 0; rr < 4; ++rr) {
                c0r[rr] = __shfl(c0, hi * 4 + rr);
                #pragma unroll
                for (int p = 0; p < P; ++p) cpr[p][rr] = __shfl(cp[p], hi * 4 + rr);
            }
            #pragma unroll
            for (int nt = 0; nt < NNT; ++nt)
                #pragma unroll
                for (int rr = 0; rr < 4; ++rr) {
                    int q = qs * 16 + hi * 4 + rr;
                    float ov = acc[qs][nt][rr] * c0r[rr];
                    #pragma unroll
                    for (int p = 0; p < P; ++p)
                        ov += MrgAcc[((size_t)(qg * P + p) * QW + q) * MST + nt * 16 + lo] * cpr[p][rr];
                    O[(((size_t)b_ * L + q0 + q) * NHEADS + h_) * DH + nt * 16 + lo] = f2bf(ov);
                }
        }
    }
}

// ---------------------------------------------------------------------------
// Level-3 flash (unchanged): 128 threads, 2 waves, in-reg P.
// ---------------------------------------------------------------------------
template <int DH, int NQS, int PRE>
__global__ __launch_bounds__(128) void flash_mfma(
    const u16* __restrict__ Q1, const u16* __restrict__ K1,
    const u16* __restrict__ V1, u16* __restrict__ O1,
    const u16* __restrict__ Q2, const u16* __restrict__ K2,
    const u16* __restrict__ V2, u16* __restrict__ O2, int L, int S)
{
    constexpr int KB = 64;
    constexpr int QW = NQS * 16;
    constexpr int QB = 2 * QW;
    constexpr int DH8 = DH / 8;
    constexpr int KC = (KB * DH8) / 128;
    constexpr int VU = (16 * DH8) / 128;
    constexpr int NKK = DH / 32;
    constexpr int NNT = DH / 16;

    __shared__ __align__(16) u16 Ks[KB][DH + 8];
    __shared__ __align__(16) u16 Vt[DH][KB];

    const int nQT = L / QB;
    const int perAtt = 2 * NHEADS * nQT;
    const int att = blockIdx.x / perAtt;
    const int rem = blockIdx.x - att * perAtt;
    const int qt = rem % nQT;
    const int bh = rem / nQT;
    const u16* __restrict__ Q = att ? Q2 : Q1;
    const u16* __restrict__ K = att ? K2 : K1;
    const u16* __restrict__ V = att ? V2 : V1;
    u16* __restrict__ O = att ? O2 : O1;

    const int tid = threadIdx.x;
    const int wv = tid >> 6;
    const int lane = tid & 63;
    const int lo = lane & 15;
    const int hi = lane >> 4;
    const int q0 = qt * QB + wv * QW;

    short8 qf[NQS][NKK];
    #pragma unroll
    for (int qs = 0; qs < NQS; ++qs)
        #pragma unroll
        for (int kk = 0; kk < NKK; ++kk)
            qf[qs][kk] = *(const short8*)&Q[((size_t)bh * L + q0 + qs * 16 + lo) * DH + kk * 32 + hi * 8];

    f32x4 acc[NQS][NNT];
    #pragma unroll
    for (int qs = 0; qs < NQS; ++qs)
        #pragma unroll
        for (int nt = 0; nt < NNT; ++nt)
            #pragma unroll
            for (int r = 0; r < 4; ++r) acc[qs][nt][r] = 0.f;
    float m_i[NQS], l_i[NQS];
    #pragma unroll
    for (int qs = 0; qs < NQS; ++qs) { m_i[qs] = -1e30f; l_i[qs] = 0.f; }

    const int NT = S / KB;
    u16x8 kreg[PRE ? KC : 1];
    u16x8 vreg[PRE ? VU : 1][4];

    const u16* Kbase = K + (size_t)bh * S * DH;
    const u16* Vbase = V + (size_t)bh * S * DH;

    auto vwrite = [&](int d, int s0, u16x4 wj) {
        int g = ((d >> 3) ^ d) & 7;
        int scol = (s0 & 7) | ((((s0 >> 3) ^ g) & 7) << 3);
        *(u16x4*)&Vt[d][scol] = wj;
    };

    if (PRE) {
        #pragma unroll
        for (int i = 0; i < KC; ++i) {
            int idx = tid + i * 128;
            kreg[i] = *(const u16x8*)&Kbase[(size_t)(idx / DH8) * DH + (idx % DH8) * 8];
        }
        #pragma unroll
        for (int u = 0; u < VU; ++u) {
            int uu = tid + u * 128;
            int d0 = (uu % DH8) * 8, s0 = (uu / DH8) * 4;
            #pragma unroll
            for (int si = 0; si < 4; ++si)
                vreg[u][si] = *(const u16x8*)&Vbase[(size_t)(s0 + si) * DH + d0];
        }
    }

    for (int t = 0; t < NT; ++t) {
        __syncthreads();
        if (PRE) {
            #pragma unroll
            for (int i = 0; i < KC; ++i) {
                int idx = tid + i * 128;
                *(u16x8*)&Ks[idx / DH8][(idx % DH8) * 8] = kreg[i];
            }
            #pragma unroll
            for (int u = 0; u < VU; ++u) {
                int uu = tid + u * 128;
                int d0 = (uu % DH8) * 8, s0 = (uu / DH8) * 4;
                #pragma unroll
                for (int j = 0; j < 8; ++j) {
                    u16x4 wj = {vreg[u][0][j], vreg[u][1][j], vreg[u][2][j], vreg[u][3][j]};
                    vwrite(d0 + j, s0, wj);
                }
            }
        } else {
            const u16* Kp = Kbase + (size_t)t * KB * DH;
            const u16* Vp = Vbase + (size_t)t * KB * DH;
            #pragma unroll
            for (int i = 0; i < KC; ++i) {
                int idx = tid + i * 128;
                *(u16x8*)&Ks[idx / DH8][(idx % DH8) * 8] =
                    *(const u16x8*)&Kp[(size_t)(idx / DH8) * DH + (idx % DH8) * 8];
            }
            #pragma unroll
            for (int u = 0; u < VU; ++u) {
                int uu = tid + u * 128;
                int d0 = (uu % DH8) * 8, s0 = (uu / DH8) * 4;
                u16x8 v0 = *(const u16x8*)&Vp[(size_t)(s0 + 0) * DH + d0];
                u16x8 v1 = *(const u16x8*)&Vp[(size_t)(s0 + 1) * DH + d0];
                u16x8 v2 = *(const u16x8*)&Vp[(size_t)(s0 + 2) * DH + d0];
                u16x8 v3 = *(const u16x8*)&Vp[(size_t)(s0 + 3) * DH + d0];
                #pragma unroll
                for (int j = 0; j < 8; ++j) {
                    u16x4 wj = {v0[j], v1[j], v2[j], v3[j]};
                    vwrite(d0 + j, s0, wj);
                }
            }
        }
        __syncthreads();

        if (PRE && t + 1 < NT) {
            const u16* Kp = Kbase + (size_t)(t + 1) * KB * DH;
            const u16* Vp = Vbase + (size_t)(t + 1) * KB * DH;
            #pragma unroll
            for (int i = 0; i < KC; ++i) {
                int idx = tid + i * 128;
                kreg[i] = *(const u16x8*)&Kp[(size_t)(idx / DH8) * DH + (idx % DH8) * 8];
            }
            #pragma unroll
            for (int u = 0; u < VU; ++u) {
                int uu = tid + u * 128;
                int d0 = (uu % DH8) * 8, s0 = (uu / DH8) * 4;
                #pragma unroll
                for (int si = 0; si < 4; ++si)
                    vreg[u][si] = *(const u16x8*)&Vp[(size_t)(s0 + si) * DH + d0];
            }
        }

        f32x4 sacc[4][NQS];
        #pragma unroll
        for (int st = 0; st < 4; ++st)
            #pragma unroll
            for (int qs = 0; qs < NQS; ++qs)
                #pragma unroll
                for (int r = 0; r < 4; ++r) sacc[st][qs][r] = 0.f;
        #pragma unroll
        for (int st = 0; st < 4; ++st) {
            #pragma unroll
            for (int kk = 0; kk < NKK; ++kk) {
                short8 a = *(const short8*)&Ks[st * 16 + lo][kk * 32 + hi * 8];
                #pragma unroll
                for (int qs = 0; qs < NQS; ++qs)
                    sacc[st][qs] = __builtin_amdgcn_mfma_f32_16x16x32_bf16(
                        a, qf[qs][kk], sacc[st][qs], 0, 0, 0);
            }
        }

        float mn[NQS], ts[NQS];
        #pragma unroll
        for (int qs = 0; qs < NQS; ++qs) {
            float tm = -1e30f;
            #pragma unroll
            for (int st = 0; st < 4; ++st)
                #pragma unroll
                for (int r = 0; r < 4; ++r) tm = fmaxf(tm, sacc[st][qs][r]);
            tm = fmaxf(tm, __shfl_xor(tm, 16));
            tm = fmaxf(tm, __shfl_xor(tm, 32));
            const bool grow = __any(tm > m_i[qs] + 8.0f);
            mn[qs] = grow ? fmaxf(m_i[qs], tm) : m_i[qs];
            ts[qs] = 0.f;
            if (grow) {
                float alpha = __builtin_amdgcn_exp2f(m_i[qs] - mn[qs]);
                m_i[qs] = mn[qs];
                l_i[qs] *= alpha;
                float ar[4];
                #pragma unroll
                for (int r = 0; r < 4; ++r) ar[r] = __shfl(alpha, hi * 4 + r);
                #pragma unroll
                for (int nt = 0; nt < NNT; ++nt)
                    #pragma unroll
                    for (int r = 0; r < 4; ++r) acc[qs][nt][r] *= ar[r];
            }
        }

        #pragma unroll
        for (int st = 0; st < 4; ++st) {
            short4v pa_[NQS];
            #pragma unroll
            for (int qs = 0; qs < NQS; ++qs) {
                float p0 = __builtin_amdgcn_exp2f(sacc[st][qs][0] - mn[qs]);
                float p1 = __builtin_amdgcn_exp2f(sacc[st][qs][1] - mn[qs]);
                float p2 = __builtin_amdgcn_exp2f(sacc[st][qs][2] - mn[qs]);
                float p3 = __builtin_amdgcn_exp2f(sacc[st][qs][3] - mn[qs]);
                ts[qs] += (p0 + p1) + (p2 + p3);
                short4v pk = {(short)f2bf(p0), (short)f2bf(p1),
                              (short)f2bf(p2), (short)f2bf(p3)};
                pa_[qs] = pk;
            }
            const int s0 = st * 16 + hi * 4;
            #pragma unroll
            for (int nt = 0; nt < NNT; ++nt) {
                int d = nt * 16 + lo;
                int g = ((d >> 3) ^ d) & 7;
                int scol = (s0 & 7) | ((((s0 >> 3) ^ g) & 7) << 3);
                short4v vb = *(const short4v*)&Vt[d][scol];
                #pragma unroll
                for (int qs = 0; qs < NQS; ++qs)
                    acc[qs][nt] = __builtin_amdgcn_mfma_f32_16x16x16bf16_1k(
                        pa_[qs], vb, acc[qs][nt], 0, 0, 0);
            }
        }

        #pragma unroll
        for (int qs = 0; qs < NQS; ++qs) {
            float t2 = ts[qs];
            t2 += __shfl_xor(t2, 16);
            t2 += __shfl_xor(t2, 32);
            l_i[qs] += t2;
        }
    }

    const int b_ = bh / NHEADS, h_ = bh % NHEADS;
    #pragma unroll
    for (int qs = 0; qs < NQS; ++qs) {
        float inv = 1.0f / l_i[qs];
        float ir[4];
        #pragma unroll
        for (int r = 0; r < 4; ++r) ir[r] = __shfl(inv, hi * 4 + r);
        #pragma unroll
        for (int nt = 0; nt < NNT; ++nt)
            #pragma unroll
            for (int r = 0; r < 4; ++r) {
                int l = q0 + qs * 16 + hi * 4 + r;
                O[(((size_t)b_ * L + l) * NHEADS + h_) * DH + nt * 16 + lo] =
                    f2bf(acc[qs][nt][r] * ir[r]);
            }
    }
}

// ---------------------------------------------------------------------------

extern "C" void kernel_launch(void* const* d_in, const int* in_sizes, int n_in,
                              void* d_out, int out_size, void* d_ws, size_t ws_size,
                              hipStream_t stream)
{
    static const int CHs[4] = {64, 128, 256, 512};
    static const int HWs[4] = {128, 64, 32, 16};

    const float* f1[4] = {(const float*)d_in[0], (const float*)d_in[1],
                          (const float*)d_in[2], (const float*)d_in[3]};
    const float* f2[4] = {nullptr, (const float*)d_in[4], (const float*)d_in[6],
                          (const float*)d_in[8]};
    const float* f3[4] = {nullptr, (const float*)d_in[5], (const float*)d_in[7],
                          (const float*)d_in[9]};

    // level 0: pass-through
    size_t out0_elems = (size_t)in_sizes[0];
    hipMemcpyAsync(d_out, d_in[0], out0_elems * sizeof(float),
                   hipMemcpyDeviceToDevice, stream);

    // workspace: 8 bf16 slots of 2*4096*128 elems (16 MB) + fp32 prep region.
    const size_t SL = (size_t)2 * 4096 * 128;
    u16* wsu = (u16*)d_ws;
    u16* Qa  = wsu + 0 * SL;
    u16* Ka  = wsu + 1 * SL;
    u16* Va  = wsu + 2 * SL;
    u16* Qb  = wsu + 3 * SL;
    u16* Kb  = wsu + 4 * SL;
    u16* Vb  = wsu + 5 * SL;
    u16* Ana = wsu + 6 * SL;
    u16* Anb = wsu + 7 * SL;
    float* wp1 = (float*)(wsu + 8 * SL);
    float* wp2 = wp1 + (size_t)128 * 384;
    float* wp3 = wp2 + (size_t)256 * 768;
    float* bp1 = wp3 + (size_t)512 * 1536;
    float* bp2 = bp1 + 512;
    float* bp3 = bp2 + 512;

    // per-level weight pointers
    const float* SQW[3]; const float* OWA[3]; const float* OWB[3];
    const float* OBA[3]; const float* OBB[3]; const float* SQB[3];
    for (int l = 0; l < 3; ++l) {
        const int bi = 10 + l * 10;
        OWA[l] = (const float*)d_in[bi + 2];
        OBA[l] = (const float*)d_in[bi + 3];
        OWB[l] = (const float*)d_in[bi + 6];
        OBB[l] = (const float*)d_in[bi + 7];
        SQW[l] = (const float*)d_in[bi + 8];
        SQB[l] = (const float*)d_in[bi + 9];
    }

    // prep: fold out_proj into squeeze weights + bias (one launch)
    prep_all<<<252 + 896, 256, 0, stream>>>(
        SQW[0], OWA[0], OWB[0], OBA[0], OBB[0], SQB[0], wp1, bp1,
        SQW[1], OWA[1], OWB[1], OBA[1], OBB[1], SQB[1], wp2, bp2,
        SQW[2], OWA[2], OWB[2], OBA[2], OBB[2], SQB[2], wp3, bp3);

    const float LOG2E = 1.44269504088896340736f;

    size_t outOff = out0_elems;
    for (int lvl = 1; lvl <= 3; ++lvl) {
        const int C = CHs[lvl];
        const int Hs = HWs[lvl];
        const int L = Hs * Hs;
        const int dh = C / NHEADS;
        const int M = 2 * L;  // B*L
        const float qscale = LOG2E / sqrtf((float)dh);
        const int bi = 10 + (lvl - 1) * 10;
        const float* a12w = (const float*)d_in[bi + 0];
        const float* a12b = (const float*)d_in[bi + 1];
        const float* a13w = (const float*)d_in[bi + 4];
        const float* a13b = (const float*)d_in[bi + 5];
        float* wp = (lvl == 1) ? wp1 : (lvl == 2) ? wp2 : wp3;
        float* bp = (lvl == 1) ? bp1 : (lvl == 2) ? bp2 : bp3;

        // 1) fused qkv (both attentions) — transposing X stage
        const int gx = 3 * C / 64;
        const int perAtt = gx * (M / 64);
        gemm_qkv<<<2 * perAtt, 256, 0, stream>>>(
            f1[lvl], f2[lvl], f3[lvl], a12w, a12b, a13w, a13b,
            Qa, Ka, Va, Qb, Kb, Vb, M, C, L, dh, qscale, gx, perAtt);

        // 2) fused flash (both attentions) — round-10 proven configs
        if (dh == 64)
            flash_split<64, 4, 2><<<2 * (2 * NHEADS) * (L / 64), 512, 0, stream>>>(
                Qa, Ka, Va, Ana, Qb, Kb, Vb, Anb, L, L);
        else if (dh == 128)
            flash_split<128, 2, 1><<<2 * (2 * NHEADS) * (L / 32), 256, 0, stream>>>(
                Qa, Ka, Va, Ana, Qb, Kb, Vb, Anb, L, L);
        else
            flash_mfma<256, 1, 0><<<2 * (2 * NHEADS) * (L / 32), 128, 0, stream>>>(
                Qa, Ka, Va, Ana, Qb, Kb, Vb, Anb, L, L);

        // 3) squeeze (out_proj folded into Wp) into d_out (fp32 [b, n, l])
        dim3 gsq(C / 64, M / 64);
        gemm_squeeze<<<gsq, 256, 0, stream>>>(f1[lvl], Ana, Anb, wp, bp,
                                              (float*)d_out + outOff, M, C, L);
        outOff += (size_t)2 * C * L;
    }
}

// Round 16
// 255.365 us; speedup vs baseline: 1.3671x; 1.0030x over previous
//
#include <hip/hip_runtime.h>
#include <hip/hip_bf16.h>
#include <math.h>

#define NHEADS 2

typedef unsigned short u16;
typedef __attribute__((ext_vector_type(8))) unsigned short u16x8;
typedef __attribute__((ext_vector_type(4))) unsigned short u16x4;
typedef __attribute__((ext_vector_type(8))) short short8;
typedef __attribute__((ext_vector_type(4))) short short4v;
typedef __attribute__((ext_vector_type(4))) float f32x4;

__device__ __forceinline__ u16 f2bf(float x) {
    __hip_bfloat16 h = __float2bfloat16(x);
    return __builtin_bit_cast(unsigned short, h);
}

// ---------------------------------------------------------------------------
// Fused qkv GEMM, both attentions in one launch (round-13 proven).
// ---------------------------------------------------------------------------
__global__ __launch_bounds__(256) void gemm_qkv(
    const float* __restrict__ f1, const float* __restrict__ f2,
    const float* __restrict__ f3,
    const float* __restrict__ w12, const float* __restrict__ b12,
    const float* __restrict__ w13, const float* __restrict__ b13,
    u16* __restrict__ Qa, u16* __restrict__ Ka, u16* __restrict__ Va,
    u16* __restrict__ Qb, u16* __restrict__ Kb, u16* __restrict__ Vb,
    int M, int C, int L, int dh, float qscale, int gx, int perAtt)
{
    const int att = blockIdx.x / perAtt;
    const int r = blockIdx.x - att * perAtt;
    const int n0 = (r % gx) * 64;
    const int m0 = (r / gx) * 64;
    const int K = C;
    __shared__ __align__(16) u16 Xs[64][72];
    __shared__ __align__(16) u16 Ws[64][72];
    const int tid = threadIdx.x;
    const int wid = tid >> 6, lane = tid & 63;
    const int lo = lane & 15, hi = lane >> 4;
    const int wm = wid >> 1, wn = wid & 1;

    const float* __restrict__ Xf = (n0 < C) ? f1 : (att ? f3 : f2);
    const float* __restrict__ W = att ? w13 : w12;
    const float* __restrict__ bias = att ? b13 : b12;
    const int bb = m0 / L;
    const int l0 = m0 - bb * L;

    f32x4 acc[2][2];
    #pragma unroll
    for (int i = 0; i < 2; ++i)
        #pragma unroll
        for (int j = 0; j < 2; ++j)
            #pragma unroll
            for (int rr = 0; rr < 4; ++rr) acc[i][j][rr] = 0.f;

    f32x4 xregf[4];
    f32x4 wreg[4];
    const int kx = tid >> 4;
    const int lc = tid & 15;

    auto load_x = [&](int k0) {
        #pragma unroll
        for (int i = 0; i < 4; ++i)
            xregf[i] = *(const f32x4*)&Xf[((size_t)(bb * C) + k0 + kx + 16 * i) * L + l0 + lc * 4];
    };
    auto store_x = [&]() {
        #pragma unroll
        for (int i = 0; i < 4; ++i)
            #pragma unroll
            for (int j = 0; j < 4; ++j)
                Xs[lc * 4 + j][kx + 16 * i] = f2bf(xregf[i][j]);
    };
    auto load_w = [&](int k0) {
        #pragma unroll
        for (int p = 0; p < 4; ++p) {
            int c = tid + p * 256;
            int row = c >> 4, kc = c & 15;
            wreg[p] = *(const f32x4*)&W[(size_t)(n0 + row) * K + k0 + kc * 4];
        }
    };

    load_x(0);
    load_w(0);
    const int ns = K / 64;
    for (int s = 0; s < ns; ++s) {
        __syncthreads();
        store_x();
        #pragma unroll
        for (int p = 0; p < 4; ++p) {
            int c = tid + p * 256;
            int row = c >> 4, kc = c & 15;
            u16x4 cv = {f2bf(wreg[p][0]), f2bf(wreg[p][1]),
                        f2bf(wreg[p][2]), f2bf(wreg[p][3])};
            *(u16x4*)&Ws[row][kc * 4] = cv;
        }
        __syncthreads();
        if (s + 1 < ns) { load_x((s + 1) * 64); load_w((s + 1) * 64); }
        #pragma unroll
        for (int kk = 0; kk < 2; ++kk) {
            short8 wf0 = *(const short8*)&Ws[wn * 32 + lo][kk * 32 + hi * 8];
            short8 wf1 = *(const short8*)&Ws[wn * 32 + 16 + lo][kk * 32 + hi * 8];
            short8 xf0 = *(const short8*)&Xs[wm * 32 + lo][kk * 32 + hi * 8];
            short8 xf1 = *(const short8*)&Xs[wm * 32 + 16 + lo][kk * 32 + hi * 8];
            acc[0][0] = __builtin_amdgcn_mfma_f32_16x16x32_bf16(wf0, xf0, acc[0][0], 0, 0, 0);
            acc[0][1] = __builtin_amdgcn_mfma_f32_16x16x32_bf16(wf1, xf0, acc[0][1], 0, 0, 0);
            acc[1][0] = __builtin_amdgcn_mfma_f32_16x16x32_bf16(wf0, xf1, acc[1][0], 0, 0, 0);
            acc[1][1] = __builtin_amdgcn_mfma_f32_16x16x32_bf16(wf1, xf1, acc[1][1], 0, 0, 0);
        }
    }

    #pragma unroll
    for (int nt = 0; nt < 2; ++nt) {
        const int nb = n0 + wn * 32 + nt * 16 + hi * 4;
        const float b0 = bias[nb + 0], b1 = bias[nb + 1];
        const float b2 = bias[nb + 2], b3 = bias[nb + 3];
        const int which = nb / C;
        const int co = nb - which * C;
        const int h = co / dh;
        const int dd = co - h * dh;
        u16* dst = (which == 0) ? (att ? Qb : Qa)
                 : (which == 1) ? (att ? Kb : Ka) : (att ? Vb : Va);
        const float sc = (which == 0) ? qscale : 1.0f;
        #pragma unroll
        for (int mt = 0; mt < 2; ++mt) {
            int m = m0 + wm * 32 + mt * 16 + lo;
            int b_ = m / L; int l = m - b_ * L;
            u16x4 pk = {f2bf((acc[mt][nt][0] + b0) * sc),
                        f2bf((acc[mt][nt][1] + b1) * sc),
                        f2bf((acc[mt][nt][2] + b2) * sc),
                        f2bf((acc[mt][nt][3] + b3) * sc)};
            *(u16x4*)&dst[((size_t)(b_ * NHEADS + h) * L + l) * dh + dd] = pk;
        }
    }
}

// ---------------------------------------------------------------------------
// prep_all: prep_w (blocks 0..251) + prep_b (blocks 252..1147), one launch.
// ---------------------------------------------------------------------------
__global__ __launch_bounds__(256) void prep_all(
    const float* __restrict__ s1, const float* __restrict__ oa1,
    const float* __restrict__ ob1, const float* __restrict__ oba1,
    const float* __restrict__ obb1, const float* __restrict__ sqb1,
    float* __restrict__ w1, float* __restrict__ b1,
    const float* __restrict__ s2, const float* __restrict__ oa2,
    const float* __restrict__ ob2, const float* __restrict__ oba2,
    const float* __restrict__ obb2, const float* __restrict__ sqb2,
    float* __restrict__ w2, float* __restrict__ b2,
    const float* __restrict__ s3, const float* __restrict__ oa3,
    const float* __restrict__ ob3, const float* __restrict__ oba3,
    const float* __restrict__ obb3, const float* __restrict__ sqb3,
    float* __restrict__ w3, float* __restrict__ b3)
{
    const int tid = threadIdx.x;
    if (blockIdx.x < 252) {
        int bid = blockIdx.x;
        int C; const float *sqw, *owa, *owb; float* wp;
        if (bid < 12)      { C = 128; sqw = s1; owa = oa1; owb = ob1; wp = w1; }
        else if (bid < 60) { bid -= 12; C = 256; sqw = s2; owa = oa2; owb = ob2; wp = w2; }
        else               { bid -= 60; C = 512; sqw = s3; owa = oa3; owb = ob3; wp = w3; }
        const int K3 = 3 * C;
        const int gxw = K3 / 64;
        const int n0 = (bid / gxw) * 64;
        const int kc0 = (bid % gxw) * 64;

        if (kc0 < C) {
            for (int p = tid; p < 64 * 64; p += 256) {
                int i = p >> 6, j = p & 63;
                wp[(size_t)(n0 + i) * K3 + kc0 + j] = sqw[(size_t)(n0 + i) * K3 + kc0 + j];
            }
            return;
        }
        const int which = kc0 / C;
        const int kp0 = kc0 - which * C;
        const float* __restrict__ ow = (which == 1) ? owa : owb;

        __shared__ __align__(16) u16 As[64][72];
        __shared__ __align__(16) u16 Bs[64][72];
        const int wid = tid >> 6, lane = tid & 63;
        const int lo = lane & 15, hi = lane >> 4;
        const int wm = wid >> 1, wn = wid & 1;

        f32x4 acc[2][2];
        #pragma unroll
        for (int i = 0; i < 2; ++i)
            #pragma unroll
            for (int j = 0; j < 2; ++j)
                #pragma unroll
                for (int rr = 0; rr < 4; ++rr) acc[i][j][rr] = 0.f;

        for (int ct = 0; ct < C / 64; ++ct) {
            __syncthreads();
            for (int p = tid; p < 64 * 64; p += 256) {
                int i = p >> 6, j = p & 63;
                As[i][j] = f2bf(sqw[(size_t)(n0 + i) * K3 + which * C + ct * 64 + j]);
                Bs[j][i] = f2bf(ow[(size_t)(ct * 64 + i) * C + kp0 + j]);
            }
            __syncthreads();
            #pragma unroll
            for (int kk = 0; kk < 2; ++kk) {
                short8 wf0 = *(const short8*)&As[wn * 32 + lo][kk * 32 + hi * 8];
                short8 wf1 = *(const short8*)&As[wn * 32 + 16 + lo][kk * 32 + hi * 8];
                short8 xf0 = *(const short8*)&Bs[wm * 32 + lo][kk * 32 + hi * 8];
                short8 xf1 = *(const short8*)&Bs[wm * 32 + 16 + lo][kk * 32 + hi * 8];
                acc[0][0] = __builtin_amdgcn_mfma_f32_16x16x32_bf16(wf0, xf0, acc[0][0], 0, 0, 0);
                acc[0][1] = __builtin_amdgcn_mfma_f32_16x16x32_bf16(wf1, xf0, acc[0][1], 0, 0, 0);
                acc[1][0] = __builtin_amdgcn_mfma_f32_16x16x32_bf16(wf0, xf1, acc[1][0], 0, 0, 0);
                acc[1][1] = __builtin_amdgcn_mfma_f32_16x16x32_bf16(wf1, xf1, acc[1][1], 0, 0, 0);
            }
        }
        #pragma unroll
        for (int nt = 0; nt < 2; ++nt) {
            const int nb = n0 + wn * 32 + nt * 16 + hi * 4;
            #pragma unroll
            for (int mt = 0; mt < 2; ++mt) {
                const int col = kc0 + wm * 32 + mt * 16 + lo;
                #pragma unroll
                for (int rr = 0; rr < 4; ++rr)
                    wp[(size_t)(nb + rr) * K3 + col] = acc[mt][nt][rr];
            }
        }
        return;
    }

    int bid = blockIdx.x - 252;
    int C, n;
    const float *sqw, *oba, *obb, *sqb; float* bp;
    if (bid < 128)      { C = 128; n = bid;       sqw = s1; oba = oba1; obb = obb1; sqb = sqb1; bp = b1; }
    else if (bid < 384) { C = 256; n = bid - 128; sqw = s2; oba = oba2; obb = obb2; sqb = sqb2; bp = b2; }
    else                { C = 512; n = bid - 384; sqw = s3; oba = oba3; obb = obb3; sqb = sqb3; bp = b3; }

    const float* row = sqw + (size_t)n * 3 * C;
    float s = 0.f;
    for (int c = tid; c < C; c += 256)
        s += row[C + c] * oba[c] + row[2 * C + c] * obb[c];
    #pragma unroll
    for (int off = 1; off < 64; off <<= 1)
        s += __shfl_xor(s, off);
    __shared__ float ws[4];
    const int wv = tid >> 6;
    if ((tid & 63) == 0) ws[wv] = s;
    __syncthreads();
    if (tid == 0)
        bp[n] = sqb[n] + ws[0] + ws[1] + ws[2] + ws[3];
}

// ---------------------------------------------------------------------------
// Squeeze GEMM (round-13 proven).
// ---------------------------------------------------------------------------
__global__ __launch_bounds__(256) void gemm_squeeze(
    const float* __restrict__ F1, const u16* __restrict__ X1,
    const u16* __restrict__ X2,
    const float* __restrict__ W, const float* __restrict__ bias,
    float* __restrict__ out, int M, int C, int L)
{
    const int n0 = blockIdx.x * 64;
    const int m0 = blockIdx.y * 64;
    const int K = 3 * C;
    __shared__ __align__(16) u16 Xs[64][72];
    __shared__ __align__(16) u16 Ws[64][72];
    const int tid = threadIdx.x;
    const int wid = tid >> 6, lane = tid & 63;
    const int lo = lane & 15, hi = lane >> 4;
    const int wm = wid >> 1, wn = wid & 1;
    const int bb = m0 / L;
    const int l0 = m0 - bb * L;

    f32x4 acc[2][2];
    #pragma unroll
    for (int i = 0; i < 2; ++i)
        #pragma unroll
        for (int j = 0; j < 2; ++j)
            #pragma unroll
            for (int rr = 0; rr < 4; ++rr) acc[i][j][rr] = 0.f;

    f32x4 xregf[4];
    u16x8 xreg[2];
    f32x4 wreg[4];
    const int kx = tid >> 4;
    const int lc = tid & 15;

    auto load_x = [&](int k0) {
        if (k0 < C) {
            #pragma unroll
            for (int i = 0; i < 4; ++i)
                xregf[i] = *(const f32x4*)&F1[((size_t)(bb * C) + k0 + kx + 16 * i) * L + l0 + lc * 4];
        } else {
            const u16* src = (k0 < 2 * C) ? X1 : X2;
            int kl = k0 - ((k0 < 2 * C) ? C : 2 * C);
            #pragma unroll
            for (int p = 0; p < 2; ++p) {
                int c = tid + p * 256;
                int row = c >> 3, kc = c & 7;
                xreg[p] = *(const u16x8*)&src[(size_t)(m0 + row) * C + kl + kc * 8];
            }
        }
    };
    auto store_x = [&](int k0) {
        if (k0 < C) {
            #pragma unroll
            for (int i = 0; i < 4; ++i)
                #pragma unroll
                for (int j = 0; j < 4; ++j)
                    Xs[lc * 4 + j][kx + 16 * i] = f2bf(xregf[i][j]);
        } else {
            #pragma unroll
            for (int p = 0; p < 2; ++p) {
                int c = tid + p * 256;
                int row = c >> 3, kc = c & 7;
                *(u16x8*)&Xs[row][kc * 8] = xreg[p];
            }
        }
    };
    auto load_w = [&](int k0) {
        #pragma unroll
        for (int p = 0; p < 4; ++p) {
            int c = tid + p * 256;
            int row = c >> 4, kc = c & 15;
            wreg[p] = *(const f32x4*)&W[(size_t)(n0 + row) * K + k0 + kc * 4];
        }
    };

    load_x(0);
    load_w(0);
    const int ns = K / 64;
    for (int s = 0; s < ns; ++s) {
        __syncthreads();
        store_x(s * 64);
        #pragma unroll
        for (int p = 0; p < 4; ++p) {
            int c = tid + p * 256;
            int row = c >> 4, kc = c & 15;
            u16x4 cv = {f2bf(wreg[p][0]), f2bf(wreg[p][1]),
                        f2bf(wreg[p][2]), f2bf(wreg[p][3])};
            *(u16x4*)&Ws[row][kc * 4] = cv;
        }
        __syncthreads();
        if (s + 1 < ns) { load_x((s + 1) * 64); load_w((s + 1) * 64); }
        #pragma unroll
        for (int kk = 0; kk < 2; ++kk) {
            short8 wf0 = *(const short8*)&Ws[wn * 32 + lo][kk * 32 + hi * 8];
            short8 wf1 = *(const short8*)&Ws[wn * 32 + 16 + lo][kk * 32 + hi * 8];
            short8 xf0 = *(const short8*)&Xs[wm * 32 + lo][kk * 32 + hi * 8];
            short8 xf1 = *(const short8*)&Xs[wm * 32 + 16 + lo][kk * 32 + hi * 8];
            acc[0][0] = __builtin_amdgcn_mfma_f32_16x16x32_bf16(wf0, xf0, acc[0][0], 0, 0, 0);
            acc[0][1] = __builtin_amdgcn_mfma_f32_16x16x32_bf16(wf1, xf0, acc[0][1], 0, 0, 0);
            acc[1][0] = __builtin_amdgcn_mfma_f32_16x16x32_bf16(wf0, xf1, acc[1][0], 0, 0, 0);
            acc[1][1] = __builtin_amdgcn_mfma_f32_16x16x32_bf16(wf1, xf1, acc[1][1], 0, 0, 0);
        }
    }

    #pragma unroll
    for (int nt = 0; nt < 2; ++nt) {
        const int nb = n0 + wn * 32 + nt * 16 + hi * 4;
        const float b0 = bias[nb + 0], b1 = bias[nb + 1];
        const float b2 = bias[nb + 2], b3 = bias[nb + 3];
        #pragma unroll
        for (int mt = 0; mt < 2; ++mt) {
            int m = m0 + wm * 32 + mt * 16 + lo;
            int b_ = m / L; int l = m - b_ * L;
            out[((size_t)(b_ * C + nb + 0)) * L + l] = acc[mt][nt][0] + b0;
            out[((size_t)(b_ * C + nb + 1)) * L + l] = acc[mt][nt][1] + b1;
            out[((size_t)(b_ * C + nb + 2)) * L + l] = acc[mt][nt][2] + b2;
            out[((size_t)(b_ * C + nb + 3)) * L + l] = acc[mt][nt][3] + b3;
        }
    }
}

// ---------------------------------------------------------------------------
// Generalized split flash. Round-16 changes vs round 15 (VALU trim):
//  - l_i kept as PER-LANE PARTIAL sums; cross-lane reduce deferred to the
//    epilogue (alpha is row-uniform so rescale commutes).
//  - row-max via shallow pairwise tree (depth 4, max3-fusable) instead of
//    a 16-deep sequential fmax chain.
// ---------------------------------------------------------------------------
template <int DH, int NPAR, int NQS>
__global__ __launch_bounds__(128 * NPAR) void flash_split(
    const u16* __restrict__ Q1, const u16* __restrict__ K1,
    const u16* __restrict__ V1, u16* __restrict__ O1,
    const u16* __restrict__ Q2, const u16* __restrict__ K2,
    const u16* __restrict__ V2, u16* __restrict__ O2, int L, int S)
{
    constexpr int KB = 64;
    constexpr int QW = 16 * NQS;
    constexpr int QB = 2 * QW;
    constexpr int NKK = DH / 32;
    constexpr int NNT = DH / 16;
    constexpr int DG = DH / 8;
    constexpr int SLOTS = DG / 8;
    constexpr int SZ_VT = 2 * NPAR * DH * KB * 2;
    constexpr int MST = DH + 4;
    constexpr int P = NPAR - 1;

    __shared__ __align__(16) char smem[SZ_VT];
    u16 (*Vt)[NPAR][DH][KB] = (u16 (*)[NPAR][DH][KB])smem;
    float* MrgAcc = (float*)smem;
    float* MrgML  = (float*)(smem + (size_t)2 * P * QW * MST * 4);

    const int nQT = L / QB;
    const int perAtt = 2 * NHEADS * nQT;
    const int att = blockIdx.x / perAtt;
    const int rem = blockIdx.x - att * perAtt;
    const int qt = rem % nQT;
    const int bh = rem / nQT;
    const u16* __restrict__ Q = att ? Q2 : Q1;
    const u16* __restrict__ K = att ? K2 : K1;
    const u16* __restrict__ V = att ? V2 : V1;
    u16* __restrict__ O = att ? O2 : O1;

    const int tid = threadIdx.x;
    const int w = tid >> 6;
    const int lane = tid & 63;
    const int lo = lane & 15, hi = lane >> 4;
    const int qg = w & 1, par = w >> 1;
    const int q0 = qt * QB + qg * QW;

    short8 qf[NQS][NKK];
    #pragma unroll
    for (int qs = 0; qs < NQS; ++qs)
        #pragma unroll
        for (int kk = 0; kk < NKK; ++kk)
            qf[qs][kk] = *(const short8*)&Q[((size_t)bh * L + q0 + qs * 16 + lo) * DH + kk * 32 + hi * 8];

    f32x4 acc[NQS][NNT];
    #pragma unroll
    for (int qs = 0; qs < NQS; ++qs)
        #pragma unroll
        for (int nt = 0; nt < NNT; ++nt)
            #pragma unroll
            for (int r = 0; r < 4; ++r) acc[qs][nt][r] = 0.f;
    float m_i[NQS], l_i[NQS];
    #pragma unroll
    for (int qs = 0; qs < NQS; ++qs) { m_i[qs] = -1e30f; l_i[qs] = 0.f; }

    const u16* Kbase = K + (size_t)bh * S * DH;
    const u16* Vbase = V + (size_t)bh * S * DH;

    short8 kf[4][NKK];
    auto load_kf = [&](int r) {
        const u16* Kt = Kbase + (size_t)(NPAR * r + par) * KB * DH;
        #pragma unroll
        for (int st = 0; st < 4; ++st)
            #pragma unroll
            for (int kk = 0; kk < NKK; ++kk)
                kf[st][kk] = *(const short8*)&Kt[(size_t)(st * 16 + lo) * DH + kk * 32 + hi * 8];
    };

    const int pt = tid >> 7;
    const int u = tid & 127;
    int dV0[SLOTS], sV0[SLOTS];
    #pragma unroll
    for (int z = 0; z < SLOTS; ++z) {
        int e = u + z * 128;
        dV0[z] = (e % DG) * 8;
        sV0[z] = (e / DG) * 4;
    }

    u16x8 vreg[SLOTS][4];

    auto loadslots = [&](int r) {
        const u16* Vp = Vbase + (size_t)(NPAR * r + pt) * KB * DH;
        #pragma unroll
        for (int z = 0; z < SLOTS; ++z)
            #pragma unroll
            for (int si = 0; si < 4; ++si)
                vreg[z][si] = *(const u16x8*)&Vp[(size_t)(sV0[z] + si) * DH + dV0[z]];
    };
    auto writeslots = [&](int buf) {
        #pragma unroll
        for (int z = 0; z < SLOTS; ++z)
            #pragma unroll
            for (int j = 0; j < 8; ++j) {
                int d = dV0[z] + j;
                int g = ((d >> 3) ^ d) & 7;
                int scol = (sV0[z] & 7) | ((((sV0[z] >> 3) ^ g) & 7) << 3);
                u16x4 wj = {vreg[z][0][j], vreg[z][1][j], vreg[z][2][j], vreg[z][3][j]};
                *(u16x4*)&Vt[buf][pt][d][scol] = wj;
            }
    };

    const int NR = S / (KB * NPAR);

    load_kf(0);
    loadslots(0);
    writeslots(0);
    __syncthreads();
    if (1 < NR) loadslots(1);

    for (int r = 0; r < NR; ++r) {
        const int cur = r & 1;

        f32x4 sacc[4][NQS];
        #pragma unroll
        for (int st = 0; st < 4; ++st)
            #pragma unroll
            for (int qs = 0; qs < NQS; ++qs)
                #pragma unroll
                for (int rr = 0; rr < 4; ++rr) sacc[st][qs][rr] = 0.f;
        #pragma unroll
        for (int st = 0; st < 4; ++st) {
            #pragma unroll
            for (int kk = 0; kk < NKK; ++kk) {
                #pragma unroll
                for (int qs = 0; qs < NQS; ++qs)
                    sacc[st][qs] = __builtin_amdgcn_mfma_f32_16x16x32_bf16(
                        kf[st][kk], qf[qs][kk], sacc[st][qs], 0, 0, 0);
            }
        }

        if (r + 1 < NR) load_kf(r + 1);

        float mn[NQS], ts[NQS];
        #pragma unroll
        for (int qs = 0; qs < NQS; ++qs) {
            // shallow tree row-max (depth 4, max3-fusable)
            float a0 = fmaxf(fmaxf(sacc[0][qs][0], sacc[0][qs][1]),
                             fmaxf(sacc[0][qs][2], sacc[0][qs][3]));
            float a1 = fmaxf(fmaxf(sacc[1][qs][0], sacc[1][qs][1]),
                             fmaxf(sacc[1][qs][2], sacc[1][qs][3]));
            float a2 = fmaxf(fmaxf(sacc[2][qs][0], sacc[2][qs][1]),
                             fmaxf(sacc[2][qs][2], sacc[2][qs][3]));
            float a3 = fmaxf(fmaxf(sacc[3][qs][0], sacc[3][qs][1]),
                             fmaxf(sacc[3][qs][2], sacc[3][qs][3]));
            float tm = fmaxf(fmaxf(a0, a1), fmaxf(a2, a3));
            tm = fmaxf(tm, __shfl_xor(tm, 16));
            tm = fmaxf(tm, __shfl_xor(tm, 32));
            const bool grow = __any(tm > m_i[qs] + 8.0f);
            mn[qs] = grow ? fmaxf(m_i[qs], tm) : m_i[qs];
            ts[qs] = 0.f;
            if (grow) {
                float alpha = __builtin_amdgcn_exp2f(m_i[qs] - mn[qs]);
                m_i[qs] = mn[qs];
                l_i[qs] *= alpha;   // per-lane partial; alpha row-uniform
                float ar[4];
                #pragma unroll
                for (int rr = 0; rr < 4; ++rr) ar[rr] = __shfl(alpha, hi * 4 + rr);
                #pragma unroll
                for (int nt = 0; nt < NNT; ++nt)
                    #pragma unroll
                    for (int rr = 0; rr < 4; ++rr) acc[qs][nt][rr] *= ar[rr];
            }
        }

        if (r + 1 < NR) writeslots(cur ^ 1);

        __builtin_amdgcn_s_setprio(1);
        #pragma unroll
        for (int st = 0; st < 4; ++st) {
            short4v pa_[NQS];
            #pragma unroll
            for (int qs = 0; qs < NQS; ++qs) {
                float p0 = __builtin_amdgcn_exp2f(sacc[st][qs][0] - mn[qs]);
                float p1 = __builtin_amdgcn_exp2f(sacc[st][qs][1] - mn[qs]);
                float p2 = __builtin_amdgcn_exp2f(sacc[st][qs][2] - mn[qs]);
                float p3 = __builtin_amdgcn_exp2f(sacc[st][qs][3] - mn[qs]);
                ts[qs] += (p0 + p1) + (p2 + p3);
                short4v pk = {(short)f2bf(p0), (short)f2bf(p1),
                              (short)f2bf(p2), (short)f2bf(p3)};
                pa_[qs] = pk;
            }
            const int s0 = st * 16 + hi * 4;
            #pragma unroll
            for (int nt = 0; nt < NNT; ++nt) {
                int d = nt * 16 + lo;
                int g = ((d >> 3) ^ d) & 7;
                int scol = (s0 & 7) | ((((s0 >> 3) ^ g) & 7) << 3);
                short4v vb = *(const short4v*)&Vt[cur][par][d][scol];
                #pragma unroll
                for (int qs = 0; qs < NQS; ++qs)
                    acc[qs][nt] = __builtin_amdgcn_mfma_f32_16x16x16bf16_1k(
                        pa_[qs], vb, acc[qs][nt], 0, 0, 0);
            }
        }
        __builtin_amdgcn_s_setprio(0);

        // deferred: accumulate per-lane partial l only (no cross-lane reduce)
        #pragma unroll
        for (int qs = 0; qs < NQS; ++qs)
            l_i[qs] += ts[qs];

        __syncthreads();
        if (r + 2 < NR) loadslots(r + 2);
    }

    // epilogue: reduce partial l across the 4 row-lanes now
    #pragma unroll
    for (int qs = 0; qs < NQS; ++qs) {
        float lr = l_i[qs];
        lr += __shfl_xor(lr, 16);
        lr += __shfl_xor(lr, 32);
        l_i[qs] = lr;
    }

    const int b_ = bh / NHEADS, h_ = bh % NHEADS;
    if (par != 0) {
        const int mi = qg * P + par - 1;
        float* ma = MrgAcc + (size_t)mi * QW * MST;
        #pragma unroll
        for (int qs = 0; qs < NQS; ++qs) {
            #pragma unroll
            for (int nt = 0; nt < NNT; ++nt)
                #pragma unroll
                for (int rr = 0; rr < 4; ++rr)
                    ma[(size_t)(qs * 16 + hi * 4 + rr) * MST + nt * 16 + lo] = acc[qs][nt][rr];
            if (hi == 0) {
                MrgML[(mi * 2 + 0) * QW + qs * 16 + lo] = m_i[qs];
                MrgML[(mi * 2 + 1) * QW + qs * 16 + lo] = l_i[qs];
            }
        }
    }
    __syncthreads();
    if (par == 0) {
        #pragma unroll
        for (int qs = 0; qs < NQS; ++qs) {
            float mp[P > 0 ? P : 1], lp[P > 0 ? P : 1];
            float mt = m_i[qs];
            #pragma unroll
            for (int p = 0; p < P; ++p) {
                mp[p] = MrgML[((qg * P + p) * 2 + 0) * QW + qs * 16 + lo];
                lp[p] = MrgML[((qg * P + p) * 2 + 1) * QW + qs * 16 + lo];
                mt = fmaxf(mt, mp[p]);
            }
            float c0 = __builtin_amdgcn_exp2f(m_i[qs] - mt);
            float lt = c0 * l_i[qs];
            float cp[P > 0 ? P : 1];
            #pragma unroll
            for (int p = 0; p < P; ++p) {
                cp[p] = __builtin_amdgcn_exp2f(mp[p] - mt);
                lt += cp[p] * lp[p];
            }
            float linv = 1.0f / lt;
            c0 *= linv;
            #pragma unroll
            for (int p = 0; p < P; ++p) cp[p] *= linv;
            float c0r[4], cpr[P > 0 ? P : 1][4];
            #pragma unroll
            for (int rr = 0; rr < 4; ++rr) {
                c0r[rr] = __shfl(c0, hi * 4 + rr);
                #pragma unroll
                for (int p = 0; p < P; ++p) cpr[p][rr] = __shfl(cp[p], hi * 4 + rr);
            }
            #pragma unroll
            for (int nt = 0; nt < NNT; ++nt)
                #pragma unroll
                for (int rr = 0; rr < 4; ++rr) {
                    int q = qs * 16 + hi * 4 + rr;
                    float ov = acc[qs][nt][rr] * c0r[rr];
                    #pragma unroll
                    for (int p = 0; p < P; ++p)
                        ov += MrgAcc[((size_t)(qg * P + p) * QW + q) * MST + nt * 16 + lo] * cpr[p][rr];
                    O[(((size_t)b_ * L + q0 + q) * NHEADS + h_) * DH + nt * 16 + lo] = f2bf(ov);
                }
        }
    }
}

// ---------------------------------------------------------------------------
// Level-3 flash: 128 threads, 2 waves, in-reg P (same VALU trim applied).
// ---------------------------------------------------------------------------
template <int DH, int NQS, int PRE>
__global__ __launch_bounds__(128) void flash_mfma(
    const u16* __restrict__ Q1, const u16* __restrict__ K1,
    const u16* __restrict__ V1, u16* __restrict__ O1,
    const u16* __restrict__ Q2, const u16* __restrict__ K2,
    const u16* __restrict__ V2, u16* __restrict__ O2, int L, int S)
{
    constexpr int KB = 64;
    constexpr int QW = NQS * 16;
    constexpr int QB = 2 * QW;
    constexpr int DH8 = DH / 8;
    constexpr int KC = (KB * DH8) / 128;
    constexpr int VU = (16 * DH8) / 128;
    constexpr int NKK = DH / 32;
    constexpr int NNT = DH / 16;

    __shared__ __align__(16) u16 Ks[KB][DH + 8];
    __shared__ __align__(16) u16 Vt[DH][KB];

    const int nQT = L / QB;
    const int perAtt = 2 * NHEADS * nQT;
    const int att = blockIdx.x / perAtt;
    const int rem = blockIdx.x - att * perAtt;
    const int qt = rem % nQT;
    const int bh = rem / nQT;
    const u16* __restrict__ Q = att ? Q2 : Q1;
    const u16* __restrict__ K = att ? K2 : K1;
    const u16* __restrict__ V = att ? V2 : V1;
    u16* __restrict__ O = att ? O2 : O1;

    const int tid = threadIdx.x;
    const int wv = tid >> 6;
    const int lane = tid & 63;
    const int lo = lane & 15;
    const int hi = lane >> 4;
    const int q0 = qt * QB + wv * QW;

    short8 qf[NQS][NKK];
    #pragma unroll
    for (int qs = 0; qs < NQS; ++qs)
        #pragma unroll
        for (int kk = 0; kk < NKK; ++kk)
            qf[qs][kk] = *(const short8*)&Q[((size_t)bh * L + q0 + qs * 16 + lo) * DH + kk * 32 + hi * 8];

    f32x4 acc[NQS][NNT];
    #pragma unroll
    for (int qs = 0; qs < NQS; ++qs)
        #pragma unroll
        for (int nt = 0; nt < NNT; ++nt)
            #pragma unroll
            for (int r = 0; r < 4; ++r) acc[qs][nt][r] = 0.f;
    float m_i[NQS], l_i[NQS];
    #pragma unroll
    for (int qs = 0; qs < NQS; ++qs) { m_i[qs] = -1e30f; l_i[qs] = 0.f; }

    const int NT = S / KB;
    u16x8 kreg[PRE ? KC : 1];
    u16x8 vreg[PRE ? VU : 1][4];

    const u16* Kbase = K + (size_t)bh * S * DH;
    const u16* Vbase = V + (size_t)bh * S * DH;

    auto vwrite = [&](int d, int s0, u16x4 wj) {
        int g = ((d >> 3) ^ d) & 7;
        int scol = (s0 & 7) | ((((s0 >> 3) ^ g) & 7) << 3);
        *(u16x4*)&Vt[d][scol] = wj;
    };

    if (PRE) {
        #pragma unroll
        for (int i = 0; i < KC; ++i) {
            int idx = tid + i * 128;
            kreg[i] = *(const u16x8*)&Kbase[(size_t)(idx / DH8) * DH + (idx % DH8) * 8];
        }
        #pragma unroll
        for (int u = 0; u < VU; ++u) {
            int uu = tid + u * 128;
            int d0 = (uu % DH8) * 8, s0 = (uu / DH8) * 4;
            #pragma unroll
            for (int si = 0; si < 4; ++si)
                vreg[u][si] = *(const u16x8*)&Vbase[(size_t)(s0 + si) * DH + d0];
        }
    }

    for (int t = 0; t < NT; ++t) {
        __syncthreads();
        if (PRE) {
            #pragma unroll
            for (int i = 0; i < KC; ++i) {
                int idx = tid + i * 128;
                *(u16x8*)&Ks[idx / DH8][(idx % DH8) * 8] = kreg[i];
            }
            #pragma unroll
            for (int u = 0; u < VU; ++u) {
                int uu = tid + u * 128;
                int d0 = (uu % DH8) * 8, s0 = (uu / DH8) * 4;
                #pragma unroll
                for (int j = 0; j < 8; ++j) {
                    u16x4 wj = {vreg[u][0][j], vreg[u][1][j], vreg[u][2][j], vreg[u][3][j]};
                    vwrite(d0 + j, s0, wj);
                }
            }
        } else {
            const u16* Kp = Kbase + (size_t)t * KB * DH;
            const u16* Vp = Vbase + (size_t)t * KB * DH;
            #pragma unroll
            for (int i = 0; i < KC; ++i) {
                int idx = tid + i * 128;
                *(u16x8*)&Ks[idx / DH8][(idx % DH8) * 8] =
                    *(const u16x8*)&Kp[(size_t)(idx / DH8) * DH + (idx % DH8) * 8];
            }
            #pragma unroll
            for (int u = 0; u < VU; ++u) {
                int uu = tid + u * 128;
                int d0 = (uu % DH8) * 8, s0 = (uu / DH8) * 4;
                u16x8 v0 = *(const u16x8*)&Vp[(size_t)(s0 + 0) * DH + d0];
                u16x8 v1 = *(const u16x8*)&Vp[(size_t)(s0 + 1) * DH + d0];
                u16x8 v2 = *(const u16x8*)&Vp[(size_t)(s0 + 2) * DH + d0];
                u16x8 v3 = *(const u16x8*)&Vp[(size_t)(s0 + 3) * DH + d0];
                #pragma unroll
                for (int j = 0; j < 8; ++j) {
                    u16x4 wj = {v0[j], v1[j], v2[j], v3[j]};
                    vwrite(d0 + j, s0, wj);
                }
            }
        }
        __syncthreads();

        if (PRE && t + 1 < NT) {
            const u16* Kp = Kbase + (size_t)(t + 1) * KB * DH;
            const u16* Vp = Vbase + (size_t)(t + 1) * KB * DH;
            #pragma unroll
            for (int i = 0; i < KC; ++i) {
                int idx = tid + i * 128;
                kreg[i] = *(const u16x8*)&Kp[(size_t)(idx / DH8) * DH + (idx % DH8) * 8];
            }
            #pragma unroll
            for (int u = 0; u < VU; ++u) {
                int uu = tid + u * 128;
                int d0 = (uu % DH8) * 8, s0 = (uu / DH8) * 4;
                #pragma unroll
                for (int si = 0; si < 4; ++si)
                    vreg[u][si] = *(const u16x8*)&Vp[(size_t)(s0 + si) * DH + d0];
            }
        }

        f32x4 sacc[4][NQS];
        #pragma unroll
        for (int st = 0; st < 4; ++st)
            #pragma unroll
            for (int qs = 0; qs < NQS; ++qs)
                #pragma unroll
                for (int r = 0; r < 4; ++r) sacc[st][qs][r] = 0.f;
        #pragma unroll
        for (int st = 0; st < 4; ++st) {
            #pragma unroll
            for (int kk = 0; kk < NKK; ++kk) {
                short8 a = *(const short8*)&Ks[st * 16 + lo][kk * 32 + hi * 8];
                #pragma unroll
                for (int qs = 0; qs < NQS; ++qs)
                    sacc[st][qs] = __builtin_amdgcn_mfma_f32_16x16x32_bf16(
                        a, qf[qs][kk], sacc[st][qs], 0, 0, 0);
            }
        }

        float mn[NQS], ts[NQS];
        #pragma unroll
        for (int qs = 0; qs < NQS; ++qs) {
            float a0 = fmaxf(fmaxf(sacc[0][qs][0], sacc[0][qs][1]),
                             fmaxf(sacc[0][qs][2], sacc[0][qs][3]));
            float a1 = fmaxf(fmaxf(sacc[1][qs][0], sacc[1][qs][1]),
                             fmaxf(sacc[1][qs][2], sacc[1][qs][3]));
            float a2 = fmaxf(fmaxf(sacc[2][qs][0], sacc[2][qs][1]),
                             fmaxf(sacc[2][qs][2], sacc[2][qs][3]));
            float a3 = fmaxf(fmaxf(sacc[3][qs][0], sacc[3][qs][1]),
                             fmaxf(sacc[3][qs][2], sacc[3][qs][3]));
            float tm = fmaxf(fmaxf(a0, a1), fmaxf(a2, a3));
            tm = fmaxf(tm, __shfl_xor(tm, 16));
            tm = fmaxf(tm, __shfl_xor(tm, 32));
            const bool grow = __any(tm > m_i[qs] + 8.0f);
            mn[qs] = grow ? fmaxf(m_i[qs], tm) : m_i[qs];
            ts[qs] = 0.f;
            if (grow) {
                float alpha = __builtin_amdgcn_exp2f(m_i[qs] - mn[qs]);
                m_i[qs] = mn[qs];
                l_i[qs] *= alpha;
                float ar[4];
                #pragma unroll
                for (int r = 0; r < 4; ++r) ar[r] = __shfl(alpha, hi * 4 + r);
                #pragma unroll
                for (int nt = 0; nt < NNT; ++nt)
                    #pragma unroll
                    for (int r = 0; r < 4; ++r) acc[qs][nt][r] *= ar[r];
            }
        }

        #pragma unroll
        for (int st = 0; st < 4; ++st) {
            short4v pa_[NQS];
            #pragma unroll
            for (int qs = 0; qs < NQS; ++qs) {
                float p0 = __builtin_amdgcn_exp2f(sacc[st][qs][0] - mn[qs]);
                float p1 = __builtin_amdgcn_exp2f(sacc[st][qs][1] - mn[qs]);
                float p2 = __builtin_amdgcn_exp2f(sacc[st][qs][2] - mn[qs]);
                float p3 = __builtin_amdgcn_exp2f(sacc[st][qs][3] - mn[qs]);
                ts[qs] += (p0 + p1) + (p2 + p3);
                short4v pk = {(short)f2bf(p0), (short)f2bf(p1),
                              (short)f2bf(p2), (short)f2bf(p3)};
                pa_[qs] = pk;
            }
            const int s0 = st * 16 + hi * 4;
            #pragma unroll
            for (int nt = 0; nt < NNT; ++nt) {
                int d = nt * 16 + lo;
                int g = ((d >> 3) ^ d) & 7;
                int scol = (s0 & 7) | ((((s0 >> 3) ^ g) & 7) << 3);
                short4v vb = *(const short4v*)&Vt[d][scol];
                #pragma unroll
                for (int qs = 0; qs < NQS; ++qs)
                    acc[qs][nt] = __builtin_amdgcn_mfma_f32_16x16x16bf16_1k(
                        pa_[qs], vb, acc[qs][nt], 0, 0, 0);
            }
        }

        #pragma unroll
        for (int qs = 0; qs < NQS; ++qs)
            l_i[qs] += ts[qs];
    }

    const int b_ = bh / NHEADS, h_ = bh % NHEADS;
    #pragma unroll
    for (int qs = 0; qs < NQS; ++qs) {
        float lr = l_i[qs];
        lr += __shfl_xor(lr, 16);
        lr += __shfl_xor(lr, 32);
        float inv = 1.0f / lr;
        float ir[4];
        #pragma unroll
        for (int r = 0; r < 4; ++r) ir[r] = __shfl(inv, hi * 4 + r);
        #pragma unroll
        for (int nt = 0; nt < NNT; ++nt)
            #pragma unroll
            for (int r = 0; r < 4; ++r) {
                int l = q0 + qs * 16 + hi * 4 + r;
                O[(((size_t)b_ * L + l) * NHEADS + h_) * DH + nt * 16 + lo] =
                    f2bf(acc[qs][nt][r] * ir[r]);
            }
    }
}

// ---------------------------------------------------------------------------

extern "C" void kernel_launch(void* const* d_in, const int* in_sizes, int n_in,
                              void* d_out, int out_size, void* d_ws, size_t ws_size,
                              hipStream_t stream)
{
    static const int CHs[4] = {64, 128, 256, 512};
    static const int HWs[4] = {128, 64, 32, 16};

    const float* f1[4] = {(const float*)d_in[0], (const float*)d_in[1],
                          (const float*)d_in[2], (const float*)d_in[3]};
    const float* f2[4] = {nullptr, (const float*)d_in[4], (const float*)d_in[6],
                          (const float*)d_in[8]};
    const float* f3[4] = {nullptr, (const float*)d_in[5], (const float*)d_in[7],
                          (const float*)d_in[9]};

    // level 0: pass-through
    size_t out0_elems = (size_t)in_sizes[0];
    hipMemcpyAsync(d_out, d_in[0], out0_elems * sizeof(float),
                   hipMemcpyDeviceToDevice, stream);

    // workspace: 8 bf16 slots of 2*4096*128 elems (16 MB) + fp32 prep region.
    const size_t SL = (size_t)2 * 4096 * 128;
    u16* wsu = (u16*)d_ws;
    u16* Qa  = wsu + 0 * SL;
    u16* Ka  = wsu + 1 * SL;
    u16* Va  = wsu + 2 * SL;
    u16* Qb  = wsu + 3 * SL;
    u16* Kb  = wsu + 4 * SL;
    u16* Vb  = wsu + 5 * SL;
    u16* Ana = wsu + 6 * SL;
    u16* Anb = wsu + 7 * SL;
    float* wp1 = (float*)(wsu + 8 * SL);
    float* wp2 = wp1 + (size_t)128 * 384;
    float* wp3 = wp2 + (size_t)256 * 768;
    float* bp1 = wp3 + (size_t)512 * 1536;
    float* bp2 = bp1 + 512;
    float* bp3 = bp2 + 512;

    // per-level weight pointers
    const float* SQW[3]; const float* OWA[3]; const float* OWB[3];
    const float* OBA[3]; const float* OBB[3]; const float* SQB[3];
    for (int l = 0; l < 3; ++l) {
        const int bi = 10 + l * 10;
        OWA[l] = (const float*)d_in[bi + 2];
        OBA[l] = (const float*)d_in[bi + 3];
        OWB[l] = (const float*)d_in[bi + 6];
        OBB[l] = (const float*)d_in[bi + 7];
        SQW[l] = (const float*)d_in[bi + 8];
        SQB[l] = (const float*)d_in[bi + 9];
    }

    // prep: fold out_proj into squeeze weights + bias (one launch)
    prep_all<<<252 + 896, 256, 0, stream>>>(
        SQW[0], OWA[0], OWB[0], OBA[0], OBB[0], SQB[0], wp1, bp1,
        SQW[1], OWA[1], OWB[1], OBA[1], OBB[1], SQB[1], wp2, bp2,
        SQW[2], OWA[2], OWB[2], OBA[2], OBB[2], SQB[2], wp3, bp3);

    const float LOG2E = 1.44269504088896340736f;

    size_t outOff = out0_elems;
    for (int lvl = 1; lvl <= 3; ++lvl) {
        const int C = CHs[lvl];
        const int Hs = HWs[lvl];
        const int L = Hs * Hs;
        const int dh = C / NHEADS;
        const int M = 2 * L;  // B*L
        const float qscale = LOG2E / sqrtf((float)dh);
        const int bi = 10 + (lvl - 1) * 10;
        const float* a12w = (const float*)d_in[bi + 0];
        const float* a12b = (const float*)d_in[bi + 1];
        const float* a13w = (const float*)d_in[bi + 4];
        const float* a13b = (const float*)d_in[bi + 5];
        float* wp = (lvl == 1) ? wp1 : (lvl == 2) ? wp2 : wp3;
        float* bp = (lvl == 1) ? bp1 : (lvl == 2) ? bp2 : bp3;

        // 1) fused qkv (both attentions) — transposing X stage
        const int gx = 3 * C / 64;
        const int perAtt = gx * (M / 64);
        gemm_qkv<<<2 * perAtt, 256, 0, stream>>>(
            f1[lvl], f2[lvl], f3[lvl], a12w, a12b, a13w, a13b,
            Qa, Ka, Va, Qb, Kb, Vb, M, C, L, dh, qscale, gx, perAtt);

        // 2) fused flash (both attentions) — round-10 proven configs
        if (dh == 64)
            flash_split<64, 4, 2><<<2 * (2 * NHEADS) * (L / 64), 512, 0, stream>>>(
                Qa, Ka, Va, Ana, Qb, Kb, Vb, Anb, L, L);
        else if (dh == 128)
            flash_split<128, 2, 1><<<2 * (2 * NHEADS) * (L / 32), 256, 0, stream>>>(
                Qa, Ka, Va, Ana, Qb, Kb, Vb, Anb, L, L);
        else
            flash_mfma<256, 1, 0><<<2 * (2 * NHEADS) * (L / 32), 128, 0, stream>>>(
                Qa, Ka, Va, Ana, Qb, Kb, Vb, Anb, L, L);

        // 3) squeeze (out_proj folded into Wp) into d_out (fp32 [b, n, l])
        dim3 gsq(C / 64, M / 64);
        gemm_squeeze<<<gsq, 256, 0, stream>>>(f1[lvl], Ana, Anb, wp, bp,
                                              (float*)d_out + outOff, M, C, L);
        outOff += (size_t)2 * C * L;
    }
}

// Round 17
// 253.360 us; speedup vs baseline: 1.3779x; 1.0079x over previous
//
#include <hip/hip_runtime.h>
#include <hip/hip_bf16.h>
#include <math.h>

#define NHEADS 2

typedef unsigned short u16;
typedef __attribute__((ext_vector_type(8))) unsigned short u16x8;
typedef __attribute__((ext_vector_type(4))) unsigned short u16x4;
typedef __attribute__((ext_vector_type(8))) short short8;
typedef __attribute__((ext_vector_type(4))) short short4v;
typedef __attribute__((ext_vector_type(4))) float f32x4;

__device__ __forceinline__ u16 f2bf(float x) {
    __hip_bfloat16 h = __float2bfloat16(x);
    return __builtin_bit_cast(unsigned short, h);
}

// ---------------------------------------------------------------------------
// Fused qkv GEMM, both attentions in one launch (round-13 proven).
// ---------------------------------------------------------------------------
__global__ __launch_bounds__(256) void gemm_qkv(
    const float* __restrict__ f1, const float* __restrict__ f2,
    const float* __restrict__ f3,
    const float* __restrict__ w12, const float* __restrict__ b12,
    const float* __restrict__ w13, const float* __restrict__ b13,
    u16* __restrict__ Qa, u16* __restrict__ Ka, u16* __restrict__ Va,
    u16* __restrict__ Qb, u16* __restrict__ Kb, u16* __restrict__ Vb,
    int M, int C, int L, int dh, float qscale, int gx, int perAtt)
{
    const int att = blockIdx.x / perAtt;
    const int r = blockIdx.x - att * perAtt;
    const int n0 = (r % gx) * 64;
    const int m0 = (r / gx) * 64;
    const int K = C;
    __shared__ __align__(16) u16 Xs[64][72];
    __shared__ __align__(16) u16 Ws[64][72];
    const int tid = threadIdx.x;
    const int wid = tid >> 6, lane = tid & 63;
    const int lo = lane & 15, hi = lane >> 4;
    const int wm = wid >> 1, wn = wid & 1;

    const float* __restrict__ Xf = (n0 < C) ? f1 : (att ? f3 : f2);
    const float* __restrict__ W = att ? w13 : w12;
    const float* __restrict__ bias = att ? b13 : b12;
    const int bb = m0 / L;
    const int l0 = m0 - bb * L;

    f32x4 acc[2][2];
    #pragma unroll
    for (int i = 0; i < 2; ++i)
        #pragma unroll
        for (int j = 0; j < 2; ++j)
            #pragma unroll
            for (int rr = 0; rr < 4; ++rr) acc[i][j][rr] = 0.f;

    f32x4 xregf[4];
    f32x4 wreg[4];
    const int kx = tid >> 4;
    const int lc = tid & 15;

    auto load_x = [&](int k0) {
        #pragma unroll
        for (int i = 0; i < 4; ++i)
            xregf[i] = *(const f32x4*)&Xf[((size_t)(bb * C) + k0 + kx + 16 * i) * L + l0 + lc * 4];
    };
    auto store_x = [&]() {
        #pragma unroll
        for (int i = 0; i < 4; ++i)
            #pragma unroll
            for (int j = 0; j < 4; ++j)
                Xs[lc * 4 + j][kx + 16 * i] = f2bf(xregf[i][j]);
    };
    auto load_w = [&](int k0) {
        #pragma unroll
        for (int p = 0; p < 4; ++p) {
            int c = tid + p * 256;
            int row = c >> 4, kc = c & 15;
            wreg[p] = *(const f32x4*)&W[(size_t)(n0 + row) * K + k0 + kc * 4];
        }
    };

    load_x(0);
    load_w(0);
    const int ns = K / 64;
    for (int s = 0; s < ns; ++s) {
        __syncthreads();
        store_x();
        #pragma unroll
        for (int p = 0; p < 4; ++p) {
            int c = tid + p * 256;
            int row = c >> 4, kc = c & 15;
            u16x4 cv = {f2bf(wreg[p][0]), f2bf(wreg[p][1]),
                        f2bf(wreg[p][2]), f2bf(wreg[p][3])};
            *(u16x4*)&Ws[row][kc * 4] = cv;
        }
        __syncthreads();
        if (s + 1 < ns) { load_x((s + 1) * 64); load_w((s + 1) * 64); }
        #pragma unroll
        for (int kk = 0; kk < 2; ++kk) {
            short8 wf0 = *(const short8*)&Ws[wn * 32 + lo][kk * 32 + hi * 8];
            short8 wf1 = *(const short8*)&Ws[wn * 32 + 16 + lo][kk * 32 + hi * 8];
            short8 xf0 = *(const short8*)&Xs[wm * 32 + lo][kk * 32 + hi * 8];
            short8 xf1 = *(const short8*)&Xs[wm * 32 + 16 + lo][kk * 32 + hi * 8];
            acc[0][0] = __builtin_amdgcn_mfma_f32_16x16x32_bf16(wf0, xf0, acc[0][0], 0, 0, 0);
            acc[0][1] = __builtin_amdgcn_mfma_f32_16x16x32_bf16(wf1, xf0, acc[0][1], 0, 0, 0);
            acc[1][0] = __builtin_amdgcn_mfma_f32_16x16x32_bf16(wf0, xf1, acc[1][0], 0, 0, 0);
            acc[1][1] = __builtin_amdgcn_mfma_f32_16x16x32_bf16(wf1, xf1, acc[1][1], 0, 0, 0);
        }
    }

    #pragma unroll
    for (int nt = 0; nt < 2; ++nt) {
        const int nb = n0 + wn * 32 + nt * 16 + hi * 4;
        const float b0 = bias[nb + 0], b1 = bias[nb + 1];
        const float b2 = bias[nb + 2], b3 = bias[nb + 3];
        const int which = nb / C;
        const int co = nb - which * C;
        const int h = co / dh;
        const int dd = co - h * dh;
        u16* dst = (which == 0) ? (att ? Qb : Qa)
                 : (which == 1) ? (att ? Kb : Ka) : (att ? Vb : Va);
        const float sc = (which == 0) ? qscale : 1.0f;
        #pragma unroll
        for (int mt = 0; mt < 2; ++mt) {
            int m = m0 + wm * 32 + mt * 16 + lo;
            int b_ = m / L; int l = m - b_ * L;
            u16x4 pk = {f2bf((acc[mt][nt][0] + b0) * sc),
                        f2bf((acc[mt][nt][1] + b1) * sc),
                        f2bf((acc[mt][nt][2] + b2) * sc),
                        f2bf((acc[mt][nt][3] + b3) * sc)};
            *(u16x4*)&dst[((size_t)(b_ * NHEADS + h) * L + l) * dh + dd] = pk;
        }
    }
}

// ---------------------------------------------------------------------------
// prep_all: prep_w (blocks 0..251) + prep_b (blocks 252..1147), one launch.
// ---------------------------------------------------------------------------
__global__ __launch_bounds__(256) void prep_all(
    const float* __restrict__ s1, const float* __restrict__ oa1,
    const float* __restrict__ ob1, const float* __restrict__ oba1,
    const float* __restrict__ obb1, const float* __restrict__ sqb1,
    float* __restrict__ w1, float* __restrict__ b1,
    const float* __restrict__ s2, const float* __restrict__ oa2,
    const float* __restrict__ ob2, const float* __restrict__ oba2,
    const float* __restrict__ obb2, const float* __restrict__ sqb2,
    float* __restrict__ w2, float* __restrict__ b2,
    const float* __restrict__ s3, const float* __restrict__ oa3,
    const float* __restrict__ ob3, const float* __restrict__ oba3,
    const float* __restrict__ obb3, const float* __restrict__ sqb3,
    float* __restrict__ w3, float* __restrict__ b3)
{
    const int tid = threadIdx.x;
    if (blockIdx.x < 252) {
        int bid = blockIdx.x;
        int C; const float *sqw, *owa, *owb; float* wp;
        if (bid < 12)      { C = 128; sqw = s1; owa = oa1; owb = ob1; wp = w1; }
        else if (bid < 60) { bid -= 12; C = 256; sqw = s2; owa = oa2; owb = ob2; wp = w2; }
        else               { bid -= 60; C = 512; sqw = s3; owa = oa3; owb = ob3; wp = w3; }
        const int K3 = 3 * C;
        const int gxw = K3 / 64;
        const int n0 = (bid / gxw) * 64;
        const int kc0 = (bid % gxw) * 64;

        if (kc0 < C) {
            for (int p = tid; p < 64 * 64; p += 256) {
                int i = p >> 6, j = p & 63;
                wp[(size_t)(n0 + i) * K3 + kc0 + j] = sqw[(size_t)(n0 + i) * K3 + kc0 + j];
            }
            return;
        }
        const int which = kc0 / C;
        const int kp0 = kc0 - which * C;
        const float* __restrict__ ow = (which == 1) ? owa : owb;

        __shared__ __align__(16) u16 As[64][72];
        __shared__ __align__(16) u16 Bs[64][72];
        const int wid = tid >> 6, lane = tid & 63;
        const int lo = lane & 15, hi = lane >> 4;
        const int wm = wid >> 1, wn = wid & 1;

        f32x4 acc[2][2];
        #pragma unroll
        for (int i = 0; i < 2; ++i)
            #pragma unroll
            for (int j = 0; j < 2; ++j)
                #pragma unroll
                for (int rr = 0; rr < 4; ++rr) acc[i][j][rr] = 0.f;

        for (int ct = 0; ct < C / 64; ++ct) {
            __syncthreads();
            for (int p = tid; p < 64 * 64; p += 256) {
                int i = p >> 6, j = p & 63;
                As[i][j] = f2bf(sqw[(size_t)(n0 + i) * K3 + which * C + ct * 64 + j]);
                Bs[j][i] = f2bf(ow[(size_t)(ct * 64 + i) * C + kp0 + j]);
            }
            __syncthreads();
            #pragma unroll
            for (int kk = 0; kk < 2; ++kk) {
                short8 wf0 = *(const short8*)&As[wn * 32 + lo][kk * 32 + hi * 8];
                short8 wf1 = *(const short8*)&As[wn * 32 + 16 + lo][kk * 32 + hi * 8];
                short8 xf0 = *(const short8*)&Bs[wm * 32 + lo][kk * 32 + hi * 8];
                short8 xf1 = *(const short8*)&Bs[wm * 32 + 16 + lo][kk * 32 + hi * 8];
                acc[0][0] = __builtin_amdgcn_mfma_f32_16x16x32_bf16(wf0, xf0, acc[0][0], 0, 0, 0);
                acc[0][1] = __builtin_amdgcn_mfma_f32_16x16x32_bf16(wf1, xf0, acc[0][1], 0, 0, 0);
                acc[1][0] = __builtin_amdgcn_mfma_f32_16x16x32_bf16(wf0, xf1, acc[1][0], 0, 0, 0);
                acc[1][1] = __builtin_amdgcn_mfma_f32_16x16x32_bf16(wf1, xf1, acc[1][1], 0, 0, 0);
            }
        }
        #pragma unroll
        for (int nt = 0; nt < 2; ++nt) {
            const int nb = n0 + wn * 32 + nt * 16 + hi * 4;
            #pragma unroll
            for (int mt = 0; mt < 2; ++mt) {
                const int col = kc0 + wm * 32 + mt * 16 + lo;
                #pragma unroll
                for (int rr = 0; rr < 4; ++rr)
                    wp[(size_t)(nb + rr) * K3 + col] = acc[mt][nt][rr];
            }
        }
        return;
    }

    int bid = blockIdx.x - 252;
    int C, n;
    const float *sqw, *oba, *obb, *sqb; float* bp;
    if (bid < 128)      { C = 128; n = bid;       sqw = s1; oba = oba1; obb = obb1; sqb = sqb1; bp = b1; }
    else if (bid < 384) { C = 256; n = bid - 128; sqw = s2; oba = oba2; obb = obb2; sqb = sqb2; bp = b2; }
    else                { C = 512; n = bid - 384; sqw = s3; oba = oba3; obb = obb3; sqb = sqb3; bp = b3; }

    const float* row = sqw + (size_t)n * 3 * C;
    float s = 0.f;
    for (int c = tid; c < C; c += 256)
        s += row[C + c] * oba[c] + row[2 * C + c] * obb[c];
    #pragma unroll
    for (int off = 1; off < 64; off <<= 1)
        s += __shfl_xor(s, off);
    __shared__ float ws[4];
    const int wv = tid >> 6;
    if ((tid & 63) == 0) ws[wv] = s;
    __syncthreads();
    if (tid == 0)
        bp[n] = sqb[n] + ws[0] + ws[1] + ws[2] + ws[3];
}

// ---------------------------------------------------------------------------
// Squeeze GEMM (round-13 proven).
// ---------------------------------------------------------------------------
__global__ __launch_bounds__(256) void gemm_squeeze(
    const float* __restrict__ F1, const u16* __restrict__ X1,
    const u16* __restrict__ X2,
    const float* __restrict__ W, const float* __restrict__ bias,
    float* __restrict__ out, int M, int C, int L)
{
    const int n0 = blockIdx.x * 64;
    const int m0 = blockIdx.y * 64;
    const int K = 3 * C;
    __shared__ __align__(16) u16 Xs[64][72];
    __shared__ __align__(16) u16 Ws[64][72];
    const int tid = threadIdx.x;
    const int wid = tid >> 6, lane = tid & 63;
    const int lo = lane & 15, hi = lane >> 4;
    const int wm = wid >> 1, wn = wid & 1;
    const int bb = m0 / L;
    const int l0 = m0 - bb * L;

    f32x4 acc[2][2];
    #pragma unroll
    for (int i = 0; i < 2; ++i)
        #pragma unroll
        for (int j = 0; j < 2; ++j)
            #pragma unroll
            for (int rr = 0; rr < 4; ++rr) acc[i][j][rr] = 0.f;

    f32x4 xregf[4];
    u16x8 xreg[2];
    f32x4 wreg[4];
    const int kx = tid >> 4;
    const int lc = tid & 15;

    auto load_x = [&](int k0) {
        if (k0 < C) {
            #pragma unroll
            for (int i = 0; i < 4; ++i)
                xregf[i] = *(const f32x4*)&F1[((size_t)(bb * C) + k0 + kx + 16 * i) * L + l0 + lc * 4];
        } else {
            const u16* src = (k0 < 2 * C) ? X1 : X2;
            int kl = k0 - ((k0 < 2 * C) ? C : 2 * C);
            #pragma unroll
            for (int p = 0; p < 2; ++p) {
                int c = tid + p * 256;
                int row = c >> 3, kc = c & 7;
                xreg[p] = *(const u16x8*)&src[(size_t)(m0 + row) * C + kl + kc * 8];
            }
        }
    };
    auto store_x = [&](int k0) {
        if (k0 < C) {
            #pragma unroll
            for (int i = 0; i < 4; ++i)
                #pragma unroll
                for (int j = 0; j < 4; ++j)
                    Xs[lc * 4 + j][kx + 16 * i] = f2bf(xregf[i][j]);
        } else {
            #pragma unroll
            for (int p = 0; p < 2; ++p) {
                int c = tid + p * 256;
                int row = c >> 3, kc = c & 7;
                *(u16x8*)&Xs[row][kc * 8] = xreg[p];
            }
        }
    };
    auto load_w = [&](int k0) {
        #pragma unroll
        for (int p = 0; p < 4; ++p) {
            int c = tid + p * 256;
            int row = c >> 4, kc = c & 15;
            wreg[p] = *(const f32x4*)&W[(size_t)(n0 + row) * K + k0 + kc * 4];
        }
    };

    load_x(0);
    load_w(0);
    const int ns = K / 64;
    for (int s = 0; s < ns; ++s) {
        __syncthreads();
        store_x(s * 64);
        #pragma unroll
        for (int p = 0; p < 4; ++p) {
            int c = tid + p * 256;
            int row = c >> 4, kc = c & 15;
            u16x4 cv = {f2bf(wreg[p][0]), f2bf(wreg[p][1]),
                        f2bf(wreg[p][2]), f2bf(wreg[p][3])};
            *(u16x4*)&Ws[row][kc * 4] = cv;
        }
        __syncthreads();
        if (s + 1 < ns) { load_x((s + 1) * 64); load_w((s + 1) * 64); }
        #pragma unroll
        for (int kk = 0; kk < 2; ++kk) {
            short8 wf0 = *(const short8*)&Ws[wn * 32 + lo][kk * 32 + hi * 8];
            short8 wf1 = *(const short8*)&Ws[wn * 32 + 16 + lo][kk * 32 + hi * 8];
            short8 xf0 = *(const short8*)&Xs[wm * 32 + lo][kk * 32 + hi * 8];
            short8 xf1 = *(const short8*)&Xs[wm * 32 + 16 + lo][kk * 32 + hi * 8];
            acc[0][0] = __builtin_amdgcn_mfma_f32_16x16x32_bf16(wf0, xf0, acc[0][0], 0, 0, 0);
            acc[0][1] = __builtin_amdgcn_mfma_f32_16x16x32_bf16(wf1, xf0, acc[0][1], 0, 0, 0);
            acc[1][0] = __builtin_amdgcn_mfma_f32_16x16x32_bf16(wf0, xf1, acc[1][0], 0, 0, 0);
            acc[1][1] = __builtin_amdgcn_mfma_f32_16x16x32_bf16(wf1, xf1, acc[1][1], 0, 0, 0);
        }
    }

    #pragma unroll
    for (int nt = 0; nt < 2; ++nt) {
        const int nb = n0 + wn * 32 + nt * 16 + hi * 4;
        const float b0 = bias[nb + 0], b1 = bias[nb + 1];
        const float b2 = bias[nb + 2], b3 = bias[nb + 3];
        #pragma unroll
        for (int mt = 0; mt < 2; ++mt) {
            int m = m0 + wm * 32 + mt * 16 + lo;
            int b_ = m / L; int l = m - b_ * L;
            out[((size_t)(b_ * C + nb + 0)) * L + l] = acc[mt][nt][0] + b0;
            out[((size_t)(b_ * C + nb + 1)) * L + l] = acc[mt][nt][1] + b1;
            out[((size_t)(b_ * C + nb + 2)) * L + l] = acc[mt][nt][2] + b2;
            out[((size_t)(b_ * C + nb + 3)) * L + l] = acc[mt][nt][3] + b3;
        }
    }
}

// ---------------------------------------------------------------------------
// Generalized split flash (round-16 body, unchanged).
// ---------------------------------------------------------------------------
template <int DH, int NPAR, int NQS>
__global__ __launch_bounds__(128 * NPAR) void flash_split(
    const u16* __restrict__ Q1, const u16* __restrict__ K1,
    const u16* __restrict__ V1, u16* __restrict__ O1,
    const u16* __restrict__ Q2, const u16* __restrict__ K2,
    const u16* __restrict__ V2, u16* __restrict__ O2, int L, int S)
{
    constexpr int KB = 64;
    constexpr int QW = 16 * NQS;
    constexpr int QB = 2 * QW;
    constexpr int NKK = DH / 32;
    constexpr int NNT = DH / 16;
    constexpr int DG = DH / 8;
    constexpr int SLOTS = DG / 8;
    constexpr int SZ_VT = 2 * NPAR * DH * KB * 2;
    constexpr int MST = DH + 4;
    constexpr int P = NPAR - 1;

    __shared__ __align__(16) char smem[SZ_VT];
    u16 (*Vt)[NPAR][DH][KB] = (u16 (*)[NPAR][DH][KB])smem;
    float* MrgAcc = (float*)smem;
    float* MrgML  = (float*)(smem + (size_t)2 * P * QW * MST * 4);

    const int nQT = L / QB;
    const int perAtt = 2 * NHEADS * nQT;
    const int att = blockIdx.x / perAtt;
    const int rem = blockIdx.x - att * perAtt;
    const int qt = rem % nQT;
    const int bh = rem / nQT;
    const u16* __restrict__ Q = att ? Q2 : Q1;
    const u16* __restrict__ K = att ? K2 : K1;
    const u16* __restrict__ V = att ? V2 : V1;
    u16* __restrict__ O = att ? O2 : O1;

    const int tid = threadIdx.x;
    const int w = tid >> 6;
    const int lane = tid & 63;
    const int lo = lane & 15, hi = lane >> 4;
    const int qg = w & 1, par = w >> 1;
    const int q0 = qt * QB + qg * QW;

    short8 qf[NQS][NKK];
    #pragma unroll
    for (int qs = 0; qs < NQS; ++qs)
        #pragma unroll
        for (int kk = 0; kk < NKK; ++kk)
            qf[qs][kk] = *(const short8*)&Q[((size_t)bh * L + q0 + qs * 16 + lo) * DH + kk * 32 + hi * 8];

    f32x4 acc[NQS][NNT];
    #pragma unroll
    for (int qs = 0; qs < NQS; ++qs)
        #pragma unroll
        for (int nt = 0; nt < NNT; ++nt)
            #pragma unroll
            for (int r = 0; r < 4; ++r) acc[qs][nt][r] = 0.f;
    float m_i[NQS], l_i[NQS];
    #pragma unroll
    for (int qs = 0; qs < NQS; ++qs) { m_i[qs] = -1e30f; l_i[qs] = 0.f; }

    const u16* Kbase = K + (size_t)bh * S * DH;
    const u16* Vbase = V + (size_t)bh * S * DH;

    short8 kf[4][NKK];
    auto load_kf = [&](int r) {
        const u16* Kt = Kbase + (size_t)(NPAR * r + par) * KB * DH;
        #pragma unroll
        for (int st = 0; st < 4; ++st)
            #pragma unroll
            for (int kk = 0; kk < NKK; ++kk)
                kf[st][kk] = *(const short8*)&Kt[(size_t)(st * 16 + lo) * DH + kk * 32 + hi * 8];
    };

    const int pt = (NPAR == 4) ? (tid >> 7) : ((tid >> 7) & (NPAR - 1));
    const int u = tid & 127;
    int dV0[SLOTS], sV0[SLOTS];
    #pragma unroll
    for (int z = 0; z < SLOTS; ++z) {
        int e = u + z * 128;
        dV0[z] = (e % DG) * 8;
        sV0[z] = (e / DG) * 4;
    }

    u16x8 vreg[SLOTS][4];

    auto loadslots = [&](int r) {
        const u16* Vp = Vbase + (size_t)(NPAR * r + pt) * KB * DH;
        #pragma unroll
        for (int z = 0; z < SLOTS; ++z)
            #pragma unroll
            for (int si = 0; si < 4; ++si)
                vreg[z][si] = *(const u16x8*)&Vp[(size_t)(sV0[z] + si) * DH + dV0[z]];
    };
    auto writeslots = [&](int buf) {
        #pragma unroll
        for (int z = 0; z < SLOTS; ++z)
            #pragma unroll
            for (int j = 0; j < 8; ++j) {
                int d = dV0[z] + j;
                int g = ((d >> 3) ^ d) & 7;
                int scol = (sV0[z] & 7) | ((((sV0[z] >> 3) ^ g) & 7) << 3);
                u16x4 wj = {vreg[z][0][j], vreg[z][1][j], vreg[z][2][j], vreg[z][3][j]};
                *(u16x4*)&Vt[buf][pt][d][scol] = wj;
            }
    };

    const int NR = S / (KB * NPAR);

    load_kf(0);
    loadslots(0);
    writeslots(0);
    __syncthreads();
    if (1 < NR) loadslots(1);

    for (int r = 0; r < NR; ++r) {
        const int cur = r & 1;

        f32x4 sacc[4][NQS];
        #pragma unroll
        for (int st = 0; st < 4; ++st)
            #pragma unroll
            for (int qs = 0; qs < NQS; ++qs)
                #pragma unroll
                for (int rr = 0; rr < 4; ++rr) sacc[st][qs][rr] = 0.f;
        #pragma unroll
        for (int st = 0; st < 4; ++st) {
            #pragma unroll
            for (int kk = 0; kk < NKK; ++kk) {
                #pragma unroll
                for (int qs = 0; qs < NQS; ++qs)
                    sacc[st][qs] = __builtin_amdgcn_mfma_f32_16x16x32_bf16(
                        kf[st][kk], qf[qs][kk], sacc[st][qs], 0, 0, 0);
            }
        }

        if (r + 1 < NR) load_kf(r + 1);

        float mn[NQS], ts[NQS];
        #pragma unroll
        for (int qs = 0; qs < NQS; ++qs) {
            float a0 = fmaxf(fmaxf(sacc[0][qs][0], sacc[0][qs][1]),
                             fmaxf(sacc[0][qs][2], sacc[0][qs][3]));
            float a1 = fmaxf(fmaxf(sacc[1][qs][0], sacc[1][qs][1]),
                             fmaxf(sacc[1][qs][2], sacc[1][qs][3]));
            float a2 = fmaxf(fmaxf(sacc[2][qs][0], sacc[2][qs][1]),
                             fmaxf(sacc[2][qs][2], sacc[2][qs][3]));
            float a3 = fmaxf(fmaxf(sacc[3][qs][0], sacc[3][qs][1]),
                             fmaxf(sacc[3][qs][2], sacc[3][qs][3]));
            float tm = fmaxf(fmaxf(a0, a1), fmaxf(a2, a3));
            tm = fmaxf(tm, __shfl_xor(tm, 16));
            tm = fmaxf(tm, __shfl_xor(tm, 32));
            const bool grow = __any(tm > m_i[qs] + 8.0f);
            mn[qs] = grow ? fmaxf(m_i[qs], tm) : m_i[qs];
            ts[qs] = 0.f;
            if (grow) {
                float alpha = __builtin_amdgcn_exp2f(m_i[qs] - mn[qs]);
                m_i[qs] = mn[qs];
                l_i[qs] *= alpha;
                float ar[4];
                #pragma unroll
                for (int rr = 0; rr < 4; ++rr) ar[rr] = __shfl(alpha, hi * 4 + rr);
                #pragma unroll
                for (int nt = 0; nt < NNT; ++nt)
                    #pragma unroll
                    for (int rr = 0; rr < 4; ++rr) acc[qs][nt][rr] *= ar[rr];
            }
        }

        if (r + 1 < NR) writeslots(cur ^ 1);

        __builtin_amdgcn_s_setprio(1);
        #pragma unroll
        for (int st = 0; st < 4; ++st) {
            short4v pa_[NQS];
            #pragma unroll
            for (int qs = 0; qs < NQS; ++qs) {
                float p0 = __builtin_amdgcn_exp2f(sacc[st][qs][0] - mn[qs]);
                float p1 = __builtin_amdgcn_exp2f(sacc[st][qs][1] - mn[qs]);
                float p2 = __builtin_amdgcn_exp2f(sacc[st][qs][2] - mn[qs]);
                float p3 = __builtin_amdgcn_exp2f(sacc[st][qs][3] - mn[qs]);
                ts[qs] += (p0 + p1) + (p2 + p3);
                short4v pk = {(short)f2bf(p0), (short)f2bf(p1),
                              (short)f2bf(p2), (short)f2bf(p3)};
                pa_[qs] = pk;
            }
            const int s0 = st * 16 + hi * 4;
            #pragma unroll
            for (int nt = 0; nt < NNT; ++nt) {
                int d = nt * 16 + lo;
                int g = ((d >> 3) ^ d) & 7;
                int scol = (s0 & 7) | ((((s0 >> 3) ^ g) & 7) << 3);
                short4v vb = *(const short4v*)&Vt[cur][par][d][scol];
                #pragma unroll
                for (int qs = 0; qs < NQS; ++qs)
                    acc[qs][nt] = __builtin_amdgcn_mfma_f32_16x16x16bf16_1k(
                        pa_[qs], vb, acc[qs][nt], 0, 0, 0);
            }
        }
        __builtin_amdgcn_s_setprio(0);

        #pragma unroll
        for (int qs = 0; qs < NQS; ++qs)
            l_i[qs] += ts[qs];

        __syncthreads();
        if (r + 2 < NR) loadslots(r + 2);
    }

    #pragma unroll
    for (int qs = 0; qs < NQS; ++qs) {
        float lr = l_i[qs];
        lr += __shfl_xor(lr, 16);
        lr += __shfl_xor(lr, 32);
        l_i[qs] = lr;
    }

    const int b_ = bh / NHEADS, h_ = bh % NHEADS;
    if (par != 0) {
        const int mi = qg * P + par - 1;
        float* ma = MrgAcc + (size_t)mi * QW * MST;
        #pragma unroll
        for (int qs = 0; qs < NQS; ++qs) {
            #pragma unroll
            for (int nt = 0; nt < NNT; ++nt)
                #pragma unroll
                for (int rr = 0; rr < 4; ++rr)
                    ma[(size_t)(qs * 16 + hi * 4 + rr) * MST + nt * 16 + lo] = acc[qs][nt][rr];
            if (hi == 0) {
                MrgML[(mi * 2 + 0) * QW + qs * 16 + lo] = m_i[qs];
                MrgML[(mi * 2 + 1) * QW + qs * 16 + lo] = l_i[qs];
            }
        }
    }
    __syncthreads();
    if (par == 0) {
        #pragma unroll
        for (int qs = 0; qs < NQS; ++qs) {
            float mp[P > 0 ? P : 1], lp[P > 0 ? P : 1];
            float mt = m_i[qs];
            #pragma unroll
            for (int p = 0; p < P; ++p) {
                mp[p] = MrgML[((qg * P + p) * 2 + 0) * QW + qs * 16 + lo];
                lp[p] = MrgML[((qg * P + p) * 2 + 1) * QW + qs * 16 + lo];
                mt = fmaxf(mt, mp[p]);
            }
            float c0 = __builtin_amdgcn_exp2f(m_i[qs] - mt);
            float lt = c0 * l_i[qs];
            float cp[P > 0 ? P : 1];
            #pragma unroll
            for (int p = 0; p < P; ++p) {
                cp[p] = __builtin_amdgcn_exp2f(mp[p] - mt);
                lt += cp[p] * lp[p];
            }
            float linv = 1.0f / lt;
            c0 *= linv;
            #pragma unroll
            for (int p = 0; p < P; ++p) cp[p] *= linv;
            float c0r[4], cpr[P > 0 ? P : 1][4];
            #pragma unroll
            for (int rr = 0; rr < 4; ++rr) {
                c0r[rr] = __shfl(c0, hi * 4 + rr);
                #pragma unroll
                for (int p = 0; p < P; ++p) cpr[p][rr] = __shfl(cp[p], hi * 4 + rr);
            }
            #pragma unroll
            for (int nt = 0; nt < NNT; ++nt)
                #pragma unroll
                for (int rr = 0; rr < 4; ++rr) {
                    int q = qs * 16 + hi * 4 + rr;
                    float ov = acc[qs][nt][rr] * c0r[rr];
                    #pragma unroll
                    for (int p = 0; p < P; ++p)
                        ov += MrgAcc[((size_t)(qg * P + p) * QW + q) * MST + nt * 16 + lo] * cpr[p][rr];
                    O[(((size_t)b_ * L + q0 + q) * NHEADS + h_) * DH + nt * 16 + lo] = f2bf(ov);
                }
        }
    }
}

// ---------------------------------------------------------------------------
// Level-3 flash: 128 threads, 2 waves, in-reg P.
// ---------------------------------------------------------------------------
template <int DH, int NQS, int PRE>
__global__ __launch_bounds__(128) void flash_mfma(
    const u16* __restrict__ Q1, const u16* __restrict__ K1,
    const u16* __restrict__ V1, u16* __restrict__ O1,
    const u16* __restrict__ Q2, const u16* __restrict__ K2,
    const u16* __restrict__ V2, u16* __restrict__ O2, int L, int S)
{
    constexpr int KB = 64;
    constexpr int QW = NQS * 16;
    constexpr int QB = 2 * QW;
    constexpr int DH8 = DH / 8;
    constexpr int KC = (KB * DH8) / 128;
    constexpr int VU = (16 * DH8) / 128;
    constexpr int NKK = DH / 32;
    constexpr int NNT = DH / 16;

    __shared__ __align__(16) u16 Ks[KB][DH + 8];
    __shared__ __align__(16) u16 Vt[DH][KB];

    const int nQT = L / QB;
    const int perAtt = 2 * NHEADS * nQT;
    const int att = blockIdx.x / perAtt;
    const int rem = blockIdx.x - att * perAtt;
    const int qt = rem % nQT;
    const int bh = rem / nQT;
    const u16* __restrict__ Q = att ? Q2 : Q1;
    const u16* __restrict__ K = att ? K2 : K1;
    const u16* __restrict__ V = att ? V2 : V1;
    u16* __restrict__ O = att ? O2 : O1;

    const int tid = threadIdx.x;
    const int wv = tid >> 6;
    const int lane = tid & 63;
    const int lo = lane & 15;
    const int hi = lane >> 4;
    const int q0 = qt * QB + wv * QW;

    short8 qf[NQS][NKK];
    #pragma unroll
    for (int qs = 0; qs < NQS; ++qs)
        #pragma unroll
        for (int kk = 0; kk < NKK; ++kk)
            qf[qs][kk] = *(const short8*)&Q[((size_t)bh * L + q0 + qs * 16 + lo) * DH + kk * 32 + hi * 8];

    f32x4 acc[NQS][NNT];
    #pragma unroll
    for (int qs = 0; qs < NQS; ++qs)
        #pragma unroll
        for (int nt = 0; nt < NNT; ++nt)
            #pragma unroll
            for (int r = 0; r < 4; ++r) acc[qs][nt][r] = 0.f;
    float m_i[NQS], l_i[NQS];
    #pragma unroll
    for (int qs = 0; qs < NQS; ++qs) { m_i[qs] = -1e30f; l_i[qs] = 0.f; }

    const int NT = S / KB;
    u16x8 kreg[PRE ? KC : 1];
    u16x8 vreg[PRE ? VU : 1][4];

    const u16* Kbase = K + (size_t)bh * S * DH;
    const u16* Vbase = V + (size_t)bh * S * DH;

    auto vwrite = [&](int d, int s0, u16x4 wj) {
        int g = ((d >> 3) ^ d) & 7;
        int scol = (s0 & 7) | ((((s0 >> 3) ^ g) & 7) << 3);
        *(u16x4*)&Vt[d][scol] = wj;
    };

    if (PRE) {
        #pragma unroll
        for (int i = 0; i < KC; ++i) {
            int idx = tid + i * 128;
            kreg[i] = *(const u16x8*)&Kbase[(size_t)(idx / DH8) * DH + (idx % DH8) * 8];
        }
        #pragma unroll
        for (int u = 0; u < VU; ++u) {
            int uu = tid + u * 128;
            int d0 = (uu % DH8) * 8, s0 = (uu / DH8) * 4;
            #pragma unroll
            for (int si = 0; si < 4; ++si)
                vreg[u][si] = *(const u16x8*)&Vbase[(size_t)(s0 + si) * DH + d0];
        }
    }

    for (int t = 0; t < NT; ++t) {
        __syncthreads();
        if (PRE) {
            #pragma unroll
            for (int i = 0; i < KC; ++i) {
                int idx = tid + i * 128;
                *(u16x8*)&Ks[idx / DH8][(idx % DH8) * 8] = kreg[i];
            }
            #pragma unroll
            for (int u = 0; u < VU; ++u) {
                int uu = tid + u * 128;
                int d0 = (uu % DH8) * 8, s0 = (uu / DH8) * 4;
                #pragma unroll
                for (int j = 0; j < 8; ++j) {
                    u16x4 wj = {vreg[u][0][j], vreg[u][1][j], vreg[u][2][j], vreg[u][3][j]};
                    vwrite(d0 + j, s0, wj);
                }
            }
        } else {
            const u16* Kp = Kbase + (size_t)t * KB * DH;
            const u16* Vp = Vbase + (size_t)t * KB * DH;
            #pragma unroll
            for (int i = 0; i < KC; ++i) {
                int idx = tid + i * 128;
                *(u16x8*)&Ks[idx / DH8][(idx % DH8) * 8] =
                    *(const u16x8*)&Kp[(size_t)(idx / DH8) * DH + (idx % DH8) * 8];
            }
            #pragma unroll
            for (int u = 0; u < VU; ++u) {
                int uu = tid + u * 128;
                int d0 = (uu % DH8) * 8, s0 = (uu / DH8) * 4;
                u16x8 v0 = *(const u16x8*)&Vp[(size_t)(s0 + 0) * DH + d0];
                u16x8 v1 = *(const u16x8*)&Vp[(size_t)(s0 + 1) * DH + d0];
                u16x8 v2 = *(const u16x8*)&Vp[(size_t)(s0 + 2) * DH + d0];
                u16x8 v3 = *(const u16x8*)&Vp[(size_t)(s0 + 3) * DH + d0];
                #pragma unroll
                for (int j = 0; j < 8; ++j) {
                    u16x4 wj = {v0[j], v1[j], v2[j], v3[j]};
                    vwrite(d0 + j, s0, wj);
                }
            }
        }
        __syncthreads();

        if (PRE && t + 1 < NT) {
            const u16* Kp = Kbase + (size_t)(t + 1) * KB * DH;
            const u16* Vp = Vbase + (size_t)(t + 1) * KB * DH;
            #pragma unroll
            for (int i = 0; i < KC; ++i) {
                int idx = tid + i * 128;
                kreg[i] = *(const u16x8*)&Kp[(size_t)(idx / DH8) * DH + (idx % DH8) * 8];
            }
            #pragma unroll
            for (int u = 0; u < VU; ++u) {
                int uu = tid + u * 128;
                int d0 = (uu % DH8) * 8, s0 = (uu / DH8) * 4;
                #pragma unroll
                for (int si = 0; si < 4; ++si)
                    vreg[u][si] = *(const u16x8*)&Vp[(size_t)(s0 + si) * DH + d0];
            }
        }

        f32x4 sacc[4][NQS];
        #pragma unroll
        for (int st = 0; st < 4; ++st)
            #pragma unroll
            for (int qs = 0; qs < NQS; ++qs)
                #pragma unroll
                for (int r = 0; r < 4; ++r) sacc[st][qs][r] = 0.f;
        #pragma unroll
        for (int st = 0; st < 4; ++st) {
            #pragma unroll
            for (int kk = 0; kk < NKK; ++kk) {
                short8 a = *(const short8*)&Ks[st * 16 + lo][kk * 32 + hi * 8];
                #pragma unroll
                for (int qs = 0; qs < NQS; ++qs)
                    sacc[st][qs] = __builtin_amdgcn_mfma_f32_16x16x32_bf16(
                        a, qf[qs][kk], sacc[st][qs], 0, 0, 0);
            }
        }

        float mn[NQS], ts[NQS];
        #pragma unroll
        for (int qs = 0; qs < NQS; ++qs) {
            float a0 = fmaxf(fmaxf(sacc[0][qs][0], sacc[0][qs][1]),
                             fmaxf(sacc[0][qs][2], sacc[0][qs][3]));
            float a1 = fmaxf(fmaxf(sacc[1][qs][0], sacc[1][qs][1]),
                             fmaxf(sacc[1][qs][2], sacc[1][qs][3]));
            float a2 = fmaxf(fmaxf(sacc[2][qs][0], sacc[2][qs][1]),
                             fmaxf(sacc[2][qs][2], sacc[2][qs][3]));
            float a3 = fmaxf(fmaxf(sacc[3][qs][0], sacc[3][qs][1]),
                             fmaxf(sacc[3][qs][2], sacc[3][qs][3]));
            float tm = fmaxf(fmaxf(a0, a1), fmaxf(a2, a3));
            tm = fmaxf(tm, __shfl_xor(tm, 16));
            tm = fmaxf(tm, __shfl_xor(tm, 32));
            const bool grow = __any(tm > m_i[qs] + 8.0f);
            mn[qs] = grow ? fmaxf(m_i[qs], tm) : m_i[qs];
            ts[qs] = 0.f;
            if (grow) {
                float alpha = __builtin_amdgcn_exp2f(m_i[qs] - mn[qs]);
                m_i[qs] = mn[qs];
                l_i[qs] *= alpha;
                float ar[4];
                #pragma unroll
                for (int r = 0; r < 4; ++r) ar[r] = __shfl(alpha, hi * 4 + r);
                #pragma unroll
                for (int nt = 0; nt < NNT; ++nt)
                    #pragma unroll
                    for (int r = 0; r < 4; ++r) acc[qs][nt][r] *= ar[r];
            }
        }

        #pragma unroll
        for (int st = 0; st < 4; ++st) {
            short4v pa_[NQS];
            #pragma unroll
            for (int qs = 0; qs < NQS; ++qs) {
                float p0 = __builtin_amdgcn_exp2f(sacc[st][qs][0] - mn[qs]);
                float p1 = __builtin_amdgcn_exp2f(sacc[st][qs][1] - mn[qs]);
                float p2 = __builtin_amdgcn_exp2f(sacc[st][qs][2] - mn[qs]);
                float p3 = __builtin_amdgcn_exp2f(sacc[st][qs][3] - mn[qs]);
                ts[qs] += (p0 + p1) + (p2 + p3);
                short4v pk = {(short)f2bf(p0), (short)f2bf(p1),
                              (short)f2bf(p2), (short)f2bf(p3)};
                pa_[qs] = pk;
            }
            const int s0 = st * 16 + hi * 4;
            #pragma unroll
            for (int nt = 0; nt < NNT; ++nt) {
                int d = nt * 16 + lo;
                int g = ((d >> 3) ^ d) & 7;
                int scol = (s0 & 7) | ((((s0 >> 3) ^ g) & 7) << 3);
                short4v vb = *(const short4v*)&Vt[d][scol];
                #pragma unroll
                for (int qs = 0; qs < NQS; ++qs)
                    acc[qs][nt] = __builtin_amdgcn_mfma_f32_16x16x16bf16_1k(
                        pa_[qs], vb, acc[qs][nt], 0, 0, 0);
            }
        }

        #pragma unroll
        for (int qs = 0; qs < NQS; ++qs)
            l_i[qs] += ts[qs];
    }

    const int b_ = bh / NHEADS, h_ = bh % NHEADS;
    #pragma unroll
    for (int qs = 0; qs < NQS; ++qs) {
        float lr = l_i[qs];
        lr += __shfl_xor(lr, 16);
        lr += __shfl_xor(lr, 32);
        float inv = 1.0f / lr;
        float ir[4];
        #pragma unroll
        for (int r = 0; r < 4; ++r) ir[r] = __shfl(inv, hi * 4 + r);
        #pragma unroll
        for (int nt = 0; nt < NNT; ++nt)
            #pragma unroll
            for (int r = 0; r < 4; ++r) {
                int l = q0 + qs * 16 + hi * 4 + r;
                O[(((size_t)b_ * L + l) * NHEADS + h_) * DH + nt * 16 + lo] =
                    f2bf(acc[qs][nt][r] * ir[r]);
            }
    }
}

// ---------------------------------------------------------------------------

extern "C" void kernel_launch(void* const* d_in, const int* in_sizes, int n_in,
                              void* d_out, int out_size, void* d_ws, size_t ws_size,
                              hipStream_t stream)
{
    static const int CHs[4] = {64, 128, 256, 512};
    static const int HWs[4] = {128, 64, 32, 16};

    const float* f1[4] = {(const float*)d_in[0], (const float*)d_in[1],
                          (const float*)d_in[2], (const float*)d_in[3]};
    const float* f2[4] = {nullptr, (const float*)d_in[4], (const float*)d_in[6],
                          (const float*)d_in[8]};
    const float* f3[4] = {nullptr, (const float*)d_in[5], (const float*)d_in[7],
                          (const float*)d_in[9]};

    // level 0: pass-through
    size_t out0_elems = (size_t)in_sizes[0];
    hipMemcpyAsync(d_out, d_in[0], out0_elems * sizeof(float),
                   hipMemcpyDeviceToDevice, stream);

    // workspace: 8 bf16 slots of 2*4096*128 elems (16 MB) + fp32 prep region.
    const size_t SL = (size_t)2 * 4096 * 128;
    u16* wsu = (u16*)d_ws;
    u16* Qa  = wsu + 0 * SL;
    u16* Ka  = wsu + 1 * SL;
    u16* Va  = wsu + 2 * SL;
    u16* Qb  = wsu + 3 * SL;
    u16* Kb  = wsu + 4 * SL;
    u16* Vb  = wsu + 5 * SL;
    u16* Ana = wsu + 6 * SL;
    u16* Anb = wsu + 7 * SL;
    float* wp1 = (float*)(wsu + 8 * SL);
    float* wp2 = wp1 + (size_t)128 * 384;
    float* wp3 = wp2 + (size_t)256 * 768;
    float* bp1 = wp3 + (size_t)512 * 1536;
    float* bp2 = bp1 + 512;
    float* bp3 = bp2 + 512;

    // per-level weight pointers
    const float* SQW[3]; const float* OWA[3]; const float* OWB[3];
    const float* OBA[3]; const float* OBB[3]; const float* SQB[3];
    for (int l = 0; l < 3; ++l) {
        const int bi = 10 + l * 10;
        OWA[l] = (const float*)d_in[bi + 2];
        OBA[l] = (const float*)d_in[bi + 3];
        OWB[l] = (const float*)d_in[bi + 6];
        OBB[l] = (const float*)d_in[bi + 7];
        SQW[l] = (const float*)d_in[bi + 8];
        SQB[l] = (const float*)d_in[bi + 9];
    }

    // prep: fold out_proj into squeeze weights + bias (one launch)
    prep_all<<<252 + 896, 256, 0, stream>>>(
        SQW[0], OWA[0], OWB[0], OBA[0], OBB[0], SQB[0], wp1, bp1,
        SQW[1], OWA[1], OWB[1], OBA[1], OBB[1], SQB[1], wp2, bp2,
        SQW[2], OWA[2], OWB[2], OBA[2], OBB[2], SQB[2], wp3, bp3);

    const float LOG2E = 1.44269504088896340736f;

    size_t outOff = out0_elems;
    for (int lvl = 1; lvl <= 3; ++lvl) {
        const int C = CHs[lvl];
        const int Hs = HWs[lvl];
        const int L = Hs * Hs;
        const int dh = C / NHEADS;
        const int M = 2 * L;  // B*L
        const float qscale = LOG2E / sqrtf((float)dh);
        const int bi = 10 + (lvl - 1) * 10;
        const float* a12w = (const float*)d_in[bi + 0];
        const float* a12b = (const float*)d_in[bi + 1];
        const float* a13w = (const float*)d_in[bi + 4];
        const float* a13b = (const float*)d_in[bi + 5];
        float* wp = (lvl == 1) ? wp1 : (lvl == 2) ? wp2 : wp3;
        float* bp = (lvl == 1) ? bp1 : (lvl == 2) ? bp2 : bp3;

        // 1) fused qkv (both attentions) — transposing X stage
        const int gx = 3 * C / 64;
        const int perAtt = gx * (M / 64);
        gemm_qkv<<<2 * perAtt, 256, 0, stream>>>(
            f1[lvl], f2[lvl], f3[lvl], a12w, a12b, a13w, a13b,
            Qa, Ka, Va, Qb, Kb, Vb, M, C, L, dh, qscale, gx, perAtt);

        // 2) fused flash (both attentions)
        if (dh == 64)
            flash_split<64, 4, 2><<<2 * (2 * NHEADS) * (L / 64), 512, 0, stream>>>(
                Qa, Ka, Va, Ana, Qb, Kb, Vb, Anb, L, L);
        else if (dh == 128)
            // round-17: NPAR 2->4 (512 thr) — was 1 blk/CU x 4 waves (1/SIMD,
            // latency-exposed); now 8 waves/CU. LDS 128KB static (OK, >64KB
            // proven at round 5's 104KB).
            flash_split<128, 4, 1><<<2 * (2 * NHEADS) * (L / 32), 512, 0, stream>>>(
                Qa, Ka, Va, Ana, Qb, Kb, Vb, Anb, L, L);
        else
            flash_mfma<256, 1, 0><<<2 * (2 * NHEADS) * (L / 32), 128, 0, stream>>>(
                Qa, Ka, Va, Ana, Qb, Kb, Vb, Anb, L, L);

        // 3) squeeze (out_proj folded into Wp) into d_out (fp32 [b, n, l])
        dim3 gsq(C / 64, M / 64);
        gemm_squeeze<<<gsq, 256, 0, stream>>>(f1[lvl], Ana, Anb, wp, bp,
                                              (float*)d_out + outOff, M, C, L);
        outOff += (size_t)2 * C * L;
    }
}

// Round 18
// 252.666 us; speedup vs baseline: 1.3817x; 1.0027x over previous
//
#include <hip/hip_runtime.h>
#include <hip/hip_bf16.h>
#include <math.h>

#define NHEADS 2

typedef unsigned short u16;
typedef unsigned int u32;
typedef __attribute__((ext_vector_type(2))) unsigned int u32x2;
typedef __attribute__((ext_vector_type(8))) unsigned short u16x8;
typedef __attribute__((ext_vector_type(4))) unsigned short u16x4;
typedef __attribute__((ext_vector_type(8))) short short8;
typedef __attribute__((ext_vector_type(4))) short short4v;
typedef __attribute__((ext_vector_type(4))) float f32x4;

__device__ __forceinline__ u16 f2bf(float x) {
    __hip_bfloat16 h = __float2bfloat16(x);
    return __builtin_bit_cast(unsigned short, h);
}

// Truncating bf16 pack for POSITIVE finite values (P = exp2(..) in (0,2^8]).
// (bits>>16 | bits&hi) -> LLVM emits v_perm/v_bfi; ~2-3 ops per PAIR vs ~9
// for two RNE converts. Bias <= 2^-8 relative, numerator-only (l is fp32).
__device__ __forceinline__ short4v pack_bf16_trunc(float p0, float p1,
                                                   float p2, float p3) {
    u32 w0 = (__builtin_bit_cast(u32, p0) >> 16) |
             (__builtin_bit_cast(u32, p1) & 0xFFFF0000u);
    u32 w1 = (__builtin_bit_cast(u32, p2) >> 16) |
             (__builtin_bit_cast(u32, p3) & 0xFFFF0000u);
    u32x2 w = {w0, w1};
    return __builtin_bit_cast(short4v, w);
}

// ---------------------------------------------------------------------------
// Fused qkv GEMM, both attentions in one launch (round-13 proven).
// ---------------------------------------------------------------------------
__global__ __launch_bounds__(256) void gemm_qkv(
    const float* __restrict__ f1, const float* __restrict__ f2,
    const float* __restrict__ f3,
    const float* __restrict__ w12, const float* __restrict__ b12,
    const float* __restrict__ w13, const float* __restrict__ b13,
    u16* __restrict__ Qa, u16* __restrict__ Ka, u16* __restrict__ Va,
    u16* __restrict__ Qb, u16* __restrict__ Kb, u16* __restrict__ Vb,
    int M, int C, int L, int dh, float qscale, int gx, int perAtt)
{
    const int att = blockIdx.x / perAtt;
    const int r = blockIdx.x - att * perAtt;
    const int n0 = (r % gx) * 64;
    const int m0 = (r / gx) * 64;
    const int K = C;
    __shared__ __align__(16) u16 Xs[64][72];
    __shared__ __align__(16) u16 Ws[64][72];
    const int tid = threadIdx.x;
    const int wid = tid >> 6, lane = tid & 63;
    const int lo = lane & 15, hi = lane >> 4;
    const int wm = wid >> 1, wn = wid & 1;

    const float* __restrict__ Xf = (n0 < C) ? f1 : (att ? f3 : f2);
    const float* __restrict__ W = att ? w13 : w12;
    const float* __restrict__ bias = att ? b13 : b12;
    const int bb = m0 / L;
    const int l0 = m0 - bb * L;

    f32x4 acc[2][2];
    #pragma unroll
    for (int i = 0; i < 2; ++i)
        #pragma unroll
        for (int j = 0; j < 2; ++j)
            #pragma unroll
            for (int rr = 0; rr < 4; ++rr) acc[i][j][rr] = 0.f;

    f32x4 xregf[4];
    f32x4 wreg[4];
    const int kx = tid >> 4;
    const int lc = tid & 15;

    auto load_x = [&](int k0) {
        #pragma unroll
        for (int i = 0; i < 4; ++i)
            xregf[i] = *(const f32x4*)&Xf[((size_t)(bb * C) + k0 + kx + 16 * i) * L + l0 + lc * 4];
    };
    auto store_x = [&]() {
        #pragma unroll
        for (int i = 0; i < 4; ++i)
            #pragma unroll
            for (int j = 0; j < 4; ++j)
                Xs[lc * 4 + j][kx + 16 * i] = f2bf(xregf[i][j]);
    };
    auto load_w = [&](int k0) {
        #pragma unroll
        for (int p = 0; p < 4; ++p) {
            int c = tid + p * 256;
            int row = c >> 4, kc = c & 15;
            wreg[p] = *(const f32x4*)&W[(size_t)(n0 + row) * K + k0 + kc * 4];
        }
    };

    load_x(0);
    load_w(0);
    const int ns = K / 64;
    for (int s = 0; s < ns; ++s) {
        __syncthreads();
        store_x();
        #pragma unroll
        for (int p = 0; p < 4; ++p) {
            int c = tid + p * 256;
            int row = c >> 4, kc = c & 15;
            u16x4 cv = {f2bf(wreg[p][0]), f2bf(wreg[p][1]),
                        f2bf(wreg[p][2]), f2bf(wreg[p][3])};
            *(u16x4*)&Ws[row][kc * 4] = cv;
        }
        __syncthreads();
        if (s + 1 < ns) { load_x((s + 1) * 64); load_w((s + 1) * 64); }
        #pragma unroll
        for (int kk = 0; kk < 2; ++kk) {
            short8 wf0 = *(const short8*)&Ws[wn * 32 + lo][kk * 32 + hi * 8];
            short8 wf1 = *(const short8*)&Ws[wn * 32 + 16 + lo][kk * 32 + hi * 8];
            short8 xf0 = *(const short8*)&Xs[wm * 32 + lo][kk * 32 + hi * 8];
            short8 xf1 = *(const short8*)&Xs[wm * 32 + 16 + lo][kk * 32 + hi * 8];
            acc[0][0] = __builtin_amdgcn_mfma_f32_16x16x32_bf16(wf0, xf0, acc[0][0], 0, 0, 0);
            acc[0][1] = __builtin_amdgcn_mfma_f32_16x16x32_bf16(wf1, xf0, acc[0][1], 0, 0, 0);
            acc[1][0] = __builtin_amdgcn_mfma_f32_16x16x32_bf16(wf0, xf1, acc[1][0], 0, 0, 0);
            acc[1][1] = __builtin_amdgcn_mfma_f32_16x16x32_bf16(wf1, xf1, acc[1][1], 0, 0, 0);
        }
    }

    #pragma unroll
    for (int nt = 0; nt < 2; ++nt) {
        const int nb = n0 + wn * 32 + nt * 16 + hi * 4;
        const float b0 = bias[nb + 0], b1 = bias[nb + 1];
        const float b2 = bias[nb + 2], b3 = bias[nb + 3];
        const int which = nb / C;
        const int co = nb - which * C;
        const int h = co / dh;
        const int dd = co - h * dh;
        u16* dst = (which == 0) ? (att ? Qb : Qa)
                 : (which == 1) ? (att ? Kb : Ka) : (att ? Vb : Va);
        const float sc = (which == 0) ? qscale : 1.0f;
        #pragma unroll
        for (int mt = 0; mt < 2; ++mt) {
            int m = m0 + wm * 32 + mt * 16 + lo;
            int b_ = m / L; int l = m - b_ * L;
            u16x4 pk = {f2bf((acc[mt][nt][0] + b0) * sc),
                        f2bf((acc[mt][nt][1] + b1) * sc),
                        f2bf((acc[mt][nt][2] + b2) * sc),
                        f2bf((acc[mt][nt][3] + b3) * sc)};
            *(u16x4*)&dst[((size_t)(b_ * NHEADS + h) * L + l) * dh + dd] = pk;
        }
    }
}

// ---------------------------------------------------------------------------
// prep_all: prep_w (blocks 0..251) + prep_b (blocks 252..1147), one launch.
// ---------------------------------------------------------------------------
__global__ __launch_bounds__(256) void prep_all(
    const float* __restrict__ s1, const float* __restrict__ oa1,
    const float* __restrict__ ob1, const float* __restrict__ oba1,
    const float* __restrict__ obb1, const float* __restrict__ sqb1,
    float* __restrict__ w1, float* __restrict__ b1,
    const float* __restrict__ s2, const float* __restrict__ oa2,
    const float* __restrict__ ob2, const float* __restrict__ oba2,
    const float* __restrict__ obb2, const float* __restrict__ sqb2,
    float* __restrict__ w2, float* __restrict__ b2,
    const float* __restrict__ s3, const float* __restrict__ oa3,
    const float* __restrict__ ob3, const float* __restrict__ oba3,
    const float* __restrict__ obb3, const float* __restrict__ sqb3,
    float* __restrict__ w3, float* __restrict__ b3)
{
    const int tid = threadIdx.x;
    if (blockIdx.x < 252) {
        int bid = blockIdx.x;
        int C; const float *sqw, *owa, *owb; float* wp;
        if (bid < 12)      { C = 128; sqw = s1; owa = oa1; owb = ob1; wp = w1; }
        else if (bid < 60) { bid -= 12; C = 256; sqw = s2; owa = oa2; owb = ob2; wp = w2; }
        else               { bid -= 60; C = 512; sqw = s3; owa = oa3; owb = ob3; wp = w3; }
        const int K3 = 3 * C;
        const int gxw = K3 / 64;
        const int n0 = (bid / gxw) * 64;
        const int kc0 = (bid % gxw) * 64;

        if (kc0 < C) {
            for (int p = tid; p < 64 * 64; p += 256) {
                int i = p >> 6, j = p & 63;
                wp[(size_t)(n0 + i) * K3 + kc0 + j] = sqw[(size_t)(n0 + i) * K3 + kc0 + j];
            }
            return;
        }
        const int which = kc0 / C;
        const int kp0 = kc0 - which * C;
        const float* __restrict__ ow = (which == 1) ? owa : owb;

        __shared__ __align__(16) u16 As[64][72];
        __shared__ __align__(16) u16 Bs[64][72];
        const int wid = tid >> 6, lane = tid & 63;
        const int lo = lane & 15, hi = lane >> 4;
        const int wm = wid >> 1, wn = wid & 1;

        f32x4 acc[2][2];
        #pragma unroll
        for (int i = 0; i < 2; ++i)
            #pragma unroll
            for (int j = 0; j < 2; ++j)
                #pragma unroll
                for (int rr = 0; rr < 4; ++rr) acc[i][j][rr] = 0.f;

        for (int ct = 0; ct < C / 64; ++ct) {
            __syncthreads();
            for (int p = tid; p < 64 * 64; p += 256) {
                int i = p >> 6, j = p & 63;
                As[i][j] = f2bf(sqw[(size_t)(n0 + i) * K3 + which * C + ct * 64 + j]);
                Bs[j][i] = f2bf(ow[(size_t)(ct * 64 + i) * C + kp0 + j]);
            }
            __syncthreads();
            #pragma unroll
            for (int kk = 0; kk < 2; ++kk) {
                short8 wf0 = *(const short8*)&As[wn * 32 + lo][kk * 32 + hi * 8];
                short8 wf1 = *(const short8*)&As[wn * 32 + 16 + lo][kk * 32 + hi * 8];
                short8 xf0 = *(const short8*)&Bs[wm * 32 + lo][kk * 32 + hi * 8];
                short8 xf1 = *(const short8*)&Bs[wm * 32 + 16 + lo][kk * 32 + hi * 8];
                acc[0][0] = __builtin_amdgcn_mfma_f32_16x16x32_bf16(wf0, xf0, acc[0][0], 0, 0, 0);
                acc[0][1] = __builtin_amdgcn_mfma_f32_16x16x32_bf16(wf1, xf0, acc[0][1], 0, 0, 0);
                acc[1][0] = __builtin_amdgcn_mfma_f32_16x16x32_bf16(wf0, xf1, acc[1][0], 0, 0, 0);
                acc[1][1] = __builtin_amdgcn_mfma_f32_16x16x32_bf16(wf1, xf1, acc[1][1], 0, 0, 0);
            }
        }
        #pragma unroll
        for (int nt = 0; nt < 2; ++nt) {
            const int nb = n0 + wn * 32 + nt * 16 + hi * 4;
            #pragma unroll
            for (int mt = 0; mt < 2; ++mt) {
                const int col = kc0 + wm * 32 + mt * 16 + lo;
                #pragma unroll
                for (int rr = 0; rr < 4; ++rr)
                    wp[(size_t)(nb + rr) * K3 + col] = acc[mt][nt][rr];
            }
        }
        return;
    }

    int bid = blockIdx.x - 252;
    int C, n;
    const float *sqw, *oba, *obb, *sqb; float* bp;
    if (bid < 128)      { C = 128; n = bid;       sqw = s1; oba = oba1; obb = obb1; sqb = sqb1; bp = b1; }
    else if (bid < 384) { C = 256; n = bid - 128; sqw = s2; oba = oba2; obb = obb2; sqb = sqb2; bp = b2; }
    else                { C = 512; n = bid - 384; sqw = s3; oba = oba3; obb = obb3; sqb = sqb3; bp = b3; }

    const float* row = sqw + (size_t)n * 3 * C;
    float s = 0.f;
    for (int c = tid; c < C; c += 256)
        s += row[C + c] * oba[c] + row[2 * C + c] * obb[c];
    #pragma unroll
    for (int off = 1; off < 64; off <<= 1)
        s += __shfl_xor(s, off);
    __shared__ float ws[4];
    const int wv = tid >> 6;
    if ((tid & 63) == 0) ws[wv] = s;
    __syncthreads();
    if (tid == 0)
        bp[n] = sqb[n] + ws[0] + ws[1] + ws[2] + ws[3];
}

// ---------------------------------------------------------------------------
// Squeeze GEMM (round-13 proven).
// ---------------------------------------------------------------------------
__global__ __launch_bounds__(256) void gemm_squeeze(
    const float* __restrict__ F1, const u16* __restrict__ X1,
    const u16* __restrict__ X2,
    const float* __restrict__ W, const float* __restrict__ bias,
    float* __restrict__ out, int M, int C, int L)
{
    const int n0 = blockIdx.x * 64;
    const int m0 = blockIdx.y * 64;
    const int K = 3 * C;
    __shared__ __align__(16) u16 Xs[64][72];
    __shared__ __align__(16) u16 Ws[64][72];
    const int tid = threadIdx.x;
    const int wid = tid >> 6, lane = tid & 63;
    const int lo = lane & 15, hi = lane >> 4;
    const int wm = wid >> 1, wn = wid & 1;
    const int bb = m0 / L;
    const int l0 = m0 - bb * L;

    f32x4 acc[2][2];
    #pragma unroll
    for (int i = 0; i < 2; ++i)
        #pragma unroll
        for (int j = 0; j < 2; ++j)
            #pragma unroll
            for (int rr = 0; rr < 4; ++rr) acc[i][j][rr] = 0.f;

    f32x4 xregf[4];
    u16x8 xreg[2];
    f32x4 wreg[4];
    const int kx = tid >> 4;
    const int lc = tid & 15;

    auto load_x = [&](int k0) {
        if (k0 < C) {
            #pragma unroll
            for (int i = 0; i < 4; ++i)
                xregf[i] = *(const f32x4*)&F1[((size_t)(bb * C) + k0 + kx + 16 * i) * L + l0 + lc * 4];
        } else {
            const u16* src = (k0 < 2 * C) ? X1 : X2;
            int kl = k0 - ((k0 < 2 * C) ? C : 2 * C);
            #pragma unroll
            for (int p = 0; p < 2; ++p) {
                int c = tid + p * 256;
                int row = c >> 3, kc = c & 7;
                xreg[p] = *(const u16x8*)&src[(size_t)(m0 + row) * C + kl + kc * 8];
            }
        }
    };
    auto store_x = [&](int k0) {
        if (k0 < C) {
            #pragma unroll
            for (int i = 0; i < 4; ++i)
                #pragma unroll
                for (int j = 0; j < 4; ++j)
                    Xs[lc * 4 + j][kx + 16 * i] = f2bf(xregf[i][j]);
        } else {
            #pragma unroll
            for (int p = 0; p < 2; ++p) {
                int c = tid + p * 256;
                int row = c >> 3, kc = c & 7;
                *(u16x8*)&Xs[row][kc * 8] = xreg[p];
            }
        }
    };
    auto load_w = [&](int k0) {
        #pragma unroll
        for (int p = 0; p < 4; ++p) {
            int c = tid + p * 256;
            int row = c >> 4, kc = c & 15;
            wreg[p] = *(const f32x4*)&W[(size_t)(n0 + row) * K + k0 + kc * 4];
        }
    };

    load_x(0);
    load_w(0);
    const int ns = K / 64;
    for (int s = 0; s < ns; ++s) {
        __syncthreads();
        store_x(s * 64);
        #pragma unroll
        for (int p = 0; p < 4; ++p) {
            int c = tid + p * 256;
            int row = c >> 4, kc = c & 15;
            u16x4 cv = {f2bf(wreg[p][0]), f2bf(wreg[p][1]),
                        f2bf(wreg[p][2]), f2bf(wreg[p][3])};
            *(u16x4*)&Ws[row][kc * 4] = cv;
        }
        __syncthreads();
        if (s + 1 < ns) { load_x((s + 1) * 64); load_w((s + 1) * 64); }
        #pragma unroll
        for (int kk = 0; kk < 2; ++kk) {
            short8 wf0 = *(const short8*)&Ws[wn * 32 + lo][kk * 32 + hi * 8];
            short8 wf1 = *(const short8*)&Ws[wn * 32 + 16 + lo][kk * 32 + hi * 8];
            short8 xf0 = *(const short8*)&Xs[wm * 32 + lo][kk * 32 + hi * 8];
            short8 xf1 = *(const short8*)&Xs[wm * 32 + 16 + lo][kk * 32 + hi * 8];
            acc[0][0] = __builtin_amdgcn_mfma_f32_16x16x32_bf16(wf0, xf0, acc[0][0], 0, 0, 0);
            acc[0][1] = __builtin_amdgcn_mfma_f32_16x16x32_bf16(wf1, xf0, acc[0][1], 0, 0, 0);
            acc[1][0] = __builtin_amdgcn_mfma_f32_16x16x32_bf16(wf0, xf1, acc[1][0], 0, 0, 0);
            acc[1][1] = __builtin_amdgcn_mfma_f32_16x16x32_bf16(wf1, xf1, acc[1][1], 0, 0, 0);
        }
    }

    #pragma unroll
    for (int nt = 0; nt < 2; ++nt) {
        const int nb = n0 + wn * 32 + nt * 16 + hi * 4;
        const float b0 = bias[nb + 0], b1 = bias[nb + 1];
        const float b2 = bias[nb + 2], b3 = bias[nb + 3];
        #pragma unroll
        for (int mt = 0; mt < 2; ++mt) {
            int m = m0 + wm * 32 + mt * 16 + lo;
            int b_ = m / L; int l = m - b_ * L;
            out[((size_t)(b_ * C + nb + 0)) * L + l] = acc[mt][nt][0] + b0;
            out[((size_t)(b_ * C + nb + 1)) * L + l] = acc[mt][nt][1] + b1;
            out[((size_t)(b_ * C + nb + 2)) * L + l] = acc[mt][nt][2] + b2;
            out[((size_t)(b_ * C + nb + 3)) * L + l] = acc[mt][nt][3] + b3;
        }
    }
}

// ---------------------------------------------------------------------------
// Generalized split flash (round-17 structure; round-18: truncating P-pack).
// ---------------------------------------------------------------------------
template <int DH, int NPAR, int NQS>
__global__ __launch_bounds__(128 * NPAR) void flash_split(
    const u16* __restrict__ Q1, const u16* __restrict__ K1,
    const u16* __restrict__ V1, u16* __restrict__ O1,
    const u16* __restrict__ Q2, const u16* __restrict__ K2,
    const u16* __restrict__ V2, u16* __restrict__ O2, int L, int S)
{
    constexpr int KB = 64;
    constexpr int QW = 16 * NQS;
    constexpr int QB = 2 * QW;
    constexpr int NKK = DH / 32;
    constexpr int NNT = DH / 16;
    constexpr int DG = DH / 8;
    constexpr int SLOTS = DG / 8;
    constexpr int SZ_VT = 2 * NPAR * DH * KB * 2;
    constexpr int MST = DH + 4;
    constexpr int P = NPAR - 1;

    __shared__ __align__(16) char smem[SZ_VT];
    u16 (*Vt)[NPAR][DH][KB] = (u16 (*)[NPAR][DH][KB])smem;
    float* MrgAcc = (float*)smem;
    float* MrgML  = (float*)(smem + (size_t)2 * P * QW * MST * 4);

    const int nQT = L / QB;
    const int perAtt = 2 * NHEADS * nQT;
    const int att = blockIdx.x / perAtt;
    const int rem = blockIdx.x - att * perAtt;
    const int qt = rem % nQT;
    const int bh = rem / nQT;
    const u16* __restrict__ Q = att ? Q2 : Q1;
    const u16* __restrict__ K = att ? K2 : K1;
    const u16* __restrict__ V = att ? V2 : V1;
    u16* __restrict__ O = att ? O2 : O1;

    const int tid = threadIdx.x;
    const int w = tid >> 6;
    const int lane = tid & 63;
    const int lo = lane & 15, hi = lane >> 4;
    const int qg = w & 1, par = w >> 1;
    const int q0 = qt * QB + qg * QW;

    short8 qf[NQS][NKK];
    #pragma unroll
    for (int qs = 0; qs < NQS; ++qs)
        #pragma unroll
        for (int kk = 0; kk < NKK; ++kk)
            qf[qs][kk] = *(const short8*)&Q[((size_t)bh * L + q0 + qs * 16 + lo) * DH + kk * 32 + hi * 8];

    f32x4 acc[NQS][NNT];
    #pragma unroll
    for (int qs = 0; qs < NQS; ++qs)
        #pragma unroll
        for (int nt = 0; nt < NNT; ++nt)
            #pragma unroll
            for (int r = 0; r < 4; ++r) acc[qs][nt][r] = 0.f;
    float m_i[NQS], l_i[NQS];
    #pragma unroll
    for (int qs = 0; qs < NQS; ++qs) { m_i[qs] = -1e30f; l_i[qs] = 0.f; }

    const u16* Kbase = K + (size_t)bh * S * DH;
    const u16* Vbase = V + (size_t)bh * S * DH;

    short8 kf[4][NKK];
    auto load_kf = [&](int r) {
        const u16* Kt = Kbase + (size_t)(NPAR * r + par) * KB * DH;
        #pragma unroll
        for (int st = 0; st < 4; ++st)
            #pragma unroll
            for (int kk = 0; kk < NKK; ++kk)
                kf[st][kk] = *(const short8*)&Kt[(size_t)(st * 16 + lo) * DH + kk * 32 + hi * 8];
    };

    const int pt = (NPAR == 4) ? (tid >> 7) : ((tid >> 7) & (NPAR - 1));
    const int u = tid & 127;
    int dV0[SLOTS], sV0[SLOTS];
    #pragma unroll
    for (int z = 0; z < SLOTS; ++z) {
        int e = u + z * 128;
        dV0[z] = (e % DG) * 8;
        sV0[z] = (e / DG) * 4;
    }

    u16x8 vreg[SLOTS][4];

    auto loadslots = [&](int r) {
        const u16* Vp = Vbase + (size_t)(NPAR * r + pt) * KB * DH;
        #pragma unroll
        for (int z = 0; z < SLOTS; ++z)
            #pragma unroll
            for (int si = 0; si < 4; ++si)
                vreg[z][si] = *(const u16x8*)&Vp[(size_t)(sV0[z] + si) * DH + dV0[z]];
    };
    auto writeslots = [&](int buf) {
        #pragma unroll
        for (int z = 0; z < SLOTS; ++z)
            #pragma unroll
            for (int j = 0; j < 8; ++j) {
                int d = dV0[z] + j;
                int g = ((d >> 3) ^ d) & 7;
                int scol = (sV0[z] & 7) | ((((sV0[z] >> 3) ^ g) & 7) << 3);
                u16x4 wj = {vreg[z][0][j], vreg[z][1][j], vreg[z][2][j], vreg[z][3][j]};
                *(u16x4*)&Vt[buf][pt][d][scol] = wj;
            }
    };

    const int NR = S / (KB * NPAR);

    load_kf(0);
    loadslots(0);
    writeslots(0);
    __syncthreads();
    if (1 < NR) loadslots(1);

    for (int r = 0; r < NR; ++r) {
        const int cur = r & 1;

        f32x4 sacc[4][NQS];
        #pragma unroll
        for (int st = 0; st < 4; ++st)
            #pragma unroll
            for (int qs = 0; qs < NQS; ++qs)
                #pragma unroll
                for (int rr = 0; rr < 4; ++rr) sacc[st][qs][rr] = 0.f;
        #pragma unroll
        for (int st = 0; st < 4; ++st) {
            #pragma unroll
            for (int kk = 0; kk < NKK; ++kk) {
                #pragma unroll
                for (int qs = 0; qs < NQS; ++qs)
                    sacc[st][qs] = __builtin_amdgcn_mfma_f32_16x16x32_bf16(
                        kf[st][kk], qf[qs][kk], sacc[st][qs], 0, 0, 0);
            }
        }

        if (r + 1 < NR) load_kf(r + 1);

        float mn[NQS], ts[NQS];
        #pragma unroll
        for (int qs = 0; qs < NQS; ++qs) {
            float a0 = fmaxf(fmaxf(sacc[0][qs][0], sacc[0][qs][1]),
                             fmaxf(sacc[0][qs][2], sacc[0][qs][3]));
            float a1 = fmaxf(fmaxf(sacc[1][qs][0], sacc[1][qs][1]),
                             fmaxf(sacc[1][qs][2], sacc[1][qs][3]));
            float a2 = fmaxf(fmaxf(sacc[2][qs][0], sacc[2][qs][1]),
                             fmaxf(sacc[2][qs][2], sacc[2][qs][3]));
            float a3 = fmaxf(fmaxf(sacc[3][qs][0], sacc[3][qs][1]),
                             fmaxf(sacc[3][qs][2], sacc[3][qs][3]));
            float tm = fmaxf(fmaxf(a0, a1), fmaxf(a2, a3));
            tm = fmaxf(tm, __shfl_xor(tm, 16));
            tm = fmaxf(tm, __shfl_xor(tm, 32));
            const bool grow = __any(tm > m_i[qs] + 8.0f);
            mn[qs] = grow ? fmaxf(m_i[qs], tm) : m_i[qs];
            ts[qs] = 0.f;
            if (grow) {
                float alpha = __builtin_amdgcn_exp2f(m_i[qs] - mn[qs]);
                m_i[qs] = mn[qs];
                l_i[qs] *= alpha;
                float ar[4];
                #pragma unroll
                for (int rr = 0; rr < 4; ++rr) ar[rr] = __shfl(alpha, hi * 4 + rr);
                #pragma unroll
                for (int nt = 0; nt < NNT; ++nt)
                    #pragma unroll
                    for (int rr = 0; rr < 4; ++rr) acc[qs][nt][rr] *= ar[rr];
            }
        }

        if (r + 1 < NR) writeslots(cur ^ 1);

        __builtin_amdgcn_s_setprio(1);
        #pragma unroll
        for (int st = 0; st < 4; ++st) {
            short4v pa_[NQS];
            #pragma unroll
            for (int qs = 0; qs < NQS; ++qs) {
                float p0 = __builtin_amdgcn_exp2f(sacc[st][qs][0] - mn[qs]);
                float p1 = __builtin_amdgcn_exp2f(sacc[st][qs][1] - mn[qs]);
                float p2 = __builtin_amdgcn_exp2f(sacc[st][qs][2] - mn[qs]);
                float p3 = __builtin_amdgcn_exp2f(sacc[st][qs][3] - mn[qs]);
                ts[qs] += (p0 + p1) + (p2 + p3);
                pa_[qs] = pack_bf16_trunc(p0, p1, p2, p3);
            }
            const int s0 = st * 16 + hi * 4;
            #pragma unroll
            for (int nt = 0; nt < NNT; ++nt) {
                int d = nt * 16 + lo;
                int g = ((d >> 3) ^ d) & 7;
                int scol = (s0 & 7) | ((((s0 >> 3) ^ g) & 7) << 3);
                short4v vb = *(const short4v*)&Vt[cur][par][d][scol];
                #pragma unroll
                for (int qs = 0; qs < NQS; ++qs)
                    acc[qs][nt] = __builtin_amdgcn_mfma_f32_16x16x16bf16_1k(
                        pa_[qs], vb, acc[qs][nt], 0, 0, 0);
            }
        }
        __builtin_amdgcn_s_setprio(0);

        #pragma unroll
        for (int qs = 0; qs < NQS; ++qs)
            l_i[qs] += ts[qs];

        __syncthreads();
        if (r + 2 < NR) loadslots(r + 2);
    }

    #pragma unroll
    for (int qs = 0; qs < NQS; ++qs) {
        float lr = l_i[qs];
        lr += __shfl_xor(lr, 16);
        lr += __shfl_xor(lr, 32);
        l_i[qs] = lr;
    }

    const int b_ = bh / NHEADS, h_ = bh % NHEADS;
    if (par != 0) {
        const int mi = qg * P + par - 1;
        float* ma = MrgAcc + (size_t)mi * QW * MST;
        #pragma unroll
        for (int qs = 0; qs < NQS; ++qs) {
            #pragma unroll
            for (int nt = 0; nt < NNT; ++nt)
                #pragma unroll
                for (int rr = 0; rr < 4; ++rr)
                    ma[(size_t)(qs * 16 + hi * 4 + rr) * MST + nt * 16 + lo] = acc[qs][nt][rr];
            if (hi == 0) {
                MrgML[(mi * 2 + 0) * QW + qs * 16 + lo] = m_i[qs];
                MrgML[(mi * 2 + 1) * QW + qs * 16 + lo] = l_i[qs];
            }
        }
    }
    __syncthreads();
    if (par == 0) {
        #pragma unroll
        for (int qs = 0; qs < NQS; ++qs) {
            float mp[P > 0 ? P : 1], lp[P > 0 ? P : 1];
            float mt = m_i[qs];
            #pragma unroll
            for (int p = 0; p < P; ++p) {
                mp[p] = MrgML[((qg * P + p) * 2 + 0) * QW + qs * 16 + lo];
                lp[p] = MrgML[((qg * P + p) * 2 + 1) * QW + qs * 16 + lo];
                mt = fmaxf(mt, mp[p]);
            }
            float c0 = __builtin_amdgcn_exp2f(m_i[qs] - mt);
            float lt = c0 * l_i[qs];
            float cp[P > 0 ? P : 1];
            #pragma unroll
            for (int p = 0; p < P; ++p) {
                cp[p] = __builtin_amdgcn_exp2f(mp[p] - mt);
                lt += cp[p] * lp[p];
            }
            float linv = 1.0f / lt;
            c0 *= linv;
            #pragma unroll
            for (int p = 0; p < P; ++p) cp[p] *= linv;
            float c0r[4], cpr[P > 0 ? P : 1][4];
            #pragma unroll
            for (int rr = 0; rr < 4; ++rr) {
                c0r[rr] = __shfl(c0, hi * 4 + rr);
                #pragma unroll
                for (int p = 0; p < P; ++p) cpr[p][rr] = __shfl(cp[p], hi * 4 + rr);
            }
            #pragma unroll
            for (int nt = 0; nt < NNT; ++nt)
                #pragma unroll
                for (int rr = 0; rr < 4; ++rr) {
                    int q = qs * 16 + hi * 4 + rr;
                    float ov = acc[qs][nt][rr] * c0r[rr];
                    #pragma unroll
                    for (int p = 0; p < P; ++p)
                        ov += MrgAcc[((size_t)(qg * P + p) * QW + q) * MST + nt * 16 + lo] * cpr[p][rr];
                    O[(((size_t)b_ * L + q0 + q) * NHEADS + h_) * DH + nt * 16 + lo] = f2bf(ov);
                }
        }
    }
}

// ---------------------------------------------------------------------------
// Level-3 flash: 128 threads, 2 waves, in-reg P (truncating P-pack applied).
// ---------------------------------------------------------------------------
template <int DH, int NQS, int PRE>
__global__ __launch_bounds__(128) void flash_mfma(
    const u16* __restrict__ Q1, const u16* __restrict__ K1,
    const u16* __restrict__ V1, u16* __restrict__ O1,
    const u16* __restrict__ Q2, const u16* __restrict__ K2,
    const u16* __restrict__ V2, u16* __restrict__ O2, int L, int S)
{
    constexpr int KB = 64;
    constexpr int QW = NQS * 16;
    constexpr int QB = 2 * QW;
    constexpr int DH8 = DH / 8;
    constexpr int KC = (KB * DH8) / 128;
    constexpr int VU = (16 * DH8) / 128;
    constexpr int NKK = DH / 32;
    constexpr int NNT = DH / 16;

    __shared__ __align__(16) u16 Ks[KB][DH + 8];
    __shared__ __align__(16) u16 Vt[DH][KB];

    const int nQT = L / QB;
    const int perAtt = 2 * NHEADS * nQT;
    const int att = blockIdx.x / perAtt;
    const int rem = blockIdx.x - att * perAtt;
    const int qt = rem % nQT;
    const int bh = rem / nQT;
    const u16* __restrict__ Q = att ? Q2 : Q1;
    const u16* __restrict__ K = att ? K2 : K1;
    const u16* __restrict__ V = att ? V2 : V1;
    u16* __restrict__ O = att ? O2 : O1;

    const int tid = threadIdx.x;
    const int wv = tid >> 6;
    const int lane = tid & 63;
    const int lo = lane & 15;
    const int hi = lane >> 4;
    const int q0 = qt * QB + wv * QW;

    short8 qf[NQS][NKK];
    #pragma unroll
    for (int qs = 0; qs < NQS; ++qs)
        #pragma unroll
        for (int kk = 0; kk < NKK; ++kk)
            qf[qs][kk] = *(const short8*)&Q[((size_t)bh * L + q0 + qs * 16 + lo) * DH + kk * 32 + hi * 8];

    f32x4 acc[NQS][NNT];
    #pragma unroll
    for (int qs = 0; qs < NQS; ++qs)
        #pragma unroll
        for (int nt = 0; nt < NNT; ++nt)
            #pragma unroll
            for (int r = 0; r < 4; ++r) acc[qs][nt][r] = 0.f;
    float m_i[NQS], l_i[NQS];
    #pragma unroll
    for (int qs = 0; qs < NQS; ++qs) { m_i[qs] = -1e30f; l_i[qs] = 0.f; }

    const int NT = S / KB;
    u16x8 kreg[PRE ? KC : 1];
    u16x8 vreg[PRE ? VU : 1][4];

    const u16* Kbase = K + (size_t)bh * S * DH;
    const u16* Vbase = V + (size_t)bh * S * DH;

    auto vwrite = [&](int d, int s0, u16x4 wj) {
        int g = ((d >> 3) ^ d) & 7;
        int scol = (s0 & 7) | ((((s0 >> 3) ^ g) & 7) << 3);
        *(u16x4*)&Vt[d][scol] = wj;
    };

    if (PRE) {
        #pragma unroll
        for (int i = 0; i < KC; ++i) {
            int idx = tid + i * 128;
            kreg[i] = *(const u16x8*)&Kbase[(size_t)(idx / DH8) * DH + (idx % DH8) * 8];
        }
        #pragma unroll
        for (int u = 0; u < VU; ++u) {
            int uu = tid + u * 128;
            int d0 = (uu % DH8) * 8, s0 = (uu / DH8) * 4;
            #pragma unroll
            for (int si = 0; si < 4; ++si)
                vreg[u][si] = *(const u16x8*)&Vbase[(size_t)(s0 + si) * DH + d0];
        }
    }

    for (int t = 0; t < NT; ++t) {
        __syncthreads();
        if (PRE) {
            #pragma unroll
            for (int i = 0; i < KC; ++i) {
                int idx = tid + i * 128;
                *(u16x8*)&Ks[idx / DH8][(idx % DH8) * 8] = kreg[i];
            }
            #pragma unroll
            for (int u = 0; u < VU; ++u) {
                int uu = tid + u * 128;
                int d0 = (uu % DH8) * 8, s0 = (uu / DH8) * 4;
                #pragma unroll
                for (int j = 0; j < 8; ++j) {
                    u16x4 wj = {vreg[u][0][j], vreg[u][1][j], vreg[u][2][j], vreg[u][3][j]};
                    vwrite(d0 + j, s0, wj);
                }
            }
        } else {
            const u16* Kp = Kbase + (size_t)t * KB * DH;
            const u16* Vp = Vbase + (size_t)t * KB * DH;
            #pragma unroll
            for (int i = 0; i < KC; ++i) {
                int idx = tid + i * 128;
                *(u16x8*)&Ks[idx / DH8][(idx % DH8) * 8] =
                    *(const u16x8*)&Kp[(size_t)(idx / DH8) * DH + (idx % DH8) * 8];
            }
            #pragma unroll
            for (int u = 0; u < VU; ++u) {
                int uu = tid + u * 128;
                int d0 = (uu % DH8) * 8, s0 = (uu / DH8) * 4;
                u16x8 v0 = *(const u16x8*)&Vp[(size_t)(s0 + 0) * DH + d0];
                u16x8 v1 = *(const u16x8*)&Vp[(size_t)(s0 + 1) * DH + d0];
                u16x8 v2 = *(const u16x8*)&Vp[(size_t)(s0 + 2) * DH + d0];
                u16x8 v3 = *(const u16x8*)&Vp[(size_t)(s0 + 3) * DH + d0];
                #pragma unroll
                for (int j = 0; j < 8; ++j) {
                    u16x4 wj = {v0[j], v1[j], v2[j], v3[j]};
                    vwrite(d0 + j, s0, wj);
                }
            }
        }
        __syncthreads();

        if (PRE && t + 1 < NT) {
            const u16* Kp = Kbase + (size_t)(t + 1) * KB * DH;
            const u16* Vp = Vbase + (size_t)(t + 1) * KB * DH;
            #pragma unroll
            for (int i = 0; i < KC; ++i) {
                int idx = tid + i * 128;
                kreg[i] = *(const u16x8*)&Kp[(size_t)(idx / DH8) * DH + (idx % DH8) * 8];
            }
            #pragma unroll
            for (int u = 0; u < VU; ++u) {
                int uu = tid + u * 128;
                int d0 = (uu % DH8) * 8, s0 = (uu / DH8) * 4;
                #pragma unroll
                for (int si = 0; si < 4; ++si)
                    vreg[u][si] = *(const u16x8*)&Vp[(size_t)(s0 + si) * DH + d0];
            }
        }

        f32x4 sacc[4][NQS];
        #pragma unroll
        for (int st = 0; st < 4; ++st)
            #pragma unroll
            for (int qs = 0; qs < NQS; ++qs)
                #pragma unroll
                for (int r = 0; r < 4; ++r) sacc[st][qs][r] = 0.f;
        #pragma unroll
        for (int st = 0; st < 4; ++st) {
            #pragma unroll
            for (int kk = 0; kk < NKK; ++kk) {
                short8 a = *(const short8*)&Ks[st * 16 + lo][kk * 32 + hi * 8];
                #pragma unroll
                for (int qs = 0; qs < NQS; ++qs)
                    sacc[st][qs] = __builtin_amdgcn_mfma_f32_16x16x32_bf16(
                        a, qf[qs][kk], sacc[st][qs], 0, 0, 0);
            }
        }

        float mn[NQS], ts[NQS];
        #pragma unroll
        for (int qs = 0; qs < NQS; ++qs) {
            float a0 = fmaxf(fmaxf(sacc[0][qs][0], sacc[0][qs][1]),
                             fmaxf(sacc[0][qs][2], sacc[0][qs][3]));
            float a1 = fmaxf(fmaxf(sacc[1][qs][0], sacc[1][qs][1]),
                             fmaxf(sacc[1][qs][2], sacc[1][qs][3]));
            float a2 = fmaxf(fmaxf(sacc[2][qs][0], sacc[2][qs][1]),
                             fmaxf(sacc[2][qs][2], sacc[2][qs][3]));
            float a3 = fmaxf(fmaxf(sacc[3][qs][0], sacc[3][qs][1]),
                             fmaxf(sacc[3][qs][2], sacc[3][qs][3]));
            float tm = fmaxf(fmaxf(a0, a1), fmaxf(a2, a3));
            tm = fmaxf(tm, __shfl_xor(tm, 16));
            tm = fmaxf(tm, __shfl_xor(tm, 32));
            const bool grow = __any(tm > m_i[qs] + 8.0f);
            mn[qs] = grow ? fmaxf(m_i[qs], tm) : m_i[qs];
            ts[qs] = 0.f;
            if (grow) {
                float alpha = __builtin_amdgcn_exp2f(m_i[qs] - mn[qs]);
                m_i[qs] = mn[qs];
                l_i[qs] *= alpha;
                float ar[4];
                #pragma unroll
                for (int r = 0; r < 4; ++r) ar[r] = __shfl(alpha, hi * 4 + r);
                #pragma unroll
                for (int nt = 0; nt < NNT; ++nt)
                    #pragma unroll
                    for (int r = 0; r < 4; ++r) acc[qs][nt][r] *= ar[r];
            }
        }

        #pragma unroll
        for (int st = 0; st < 4; ++st) {
            short4v pa_[NQS];
            #pragma unroll
            for (int qs = 0; qs < NQS; ++qs) {
                float p0 = __builtin_amdgcn_exp2f(sacc[st][qs][0] - mn[qs]);
                float p1 = __builtin_amdgcn_exp2f(sacc[st][qs][1] - mn[qs]);
                float p2 = __builtin_amdgcn_exp2f(sacc[st][qs][2] - mn[qs]);
                float p3 = __builtin_amdgcn_exp2f(sacc[st][qs][3] - mn[qs]);
                ts[qs] += (p0 + p1) + (p2 + p3);
                pa_[qs] = pack_bf16_trunc(p0, p1, p2, p3);
            }
            const int s0 = st * 16 + hi * 4;
            #pragma unroll
            for (int nt = 0; nt < NNT; ++nt) {
                int d = nt * 16 + lo;
                int g = ((d >> 3) ^ d) & 7;
                int scol = (s0 & 7) | ((((s0 >> 3) ^ g) & 7) << 3);
                short4v vb = *(const short4v*)&Vt[d][scol];
                #pragma unroll
                for (int qs = 0; qs < NQS; ++qs)
                    acc[qs][nt] = __builtin_amdgcn_mfma_f32_16x16x16bf16_1k(
                        pa_[qs], vb, acc[qs][nt], 0, 0, 0);
            }
        }

        #pragma unroll
        for (int qs = 0; qs < NQS; ++qs)
            l_i[qs] += ts[qs];
    }

    const int b_ = bh / NHEADS, h_ = bh % NHEADS;
    #pragma unroll
    for (int qs = 0; qs < NQS; ++qs) {
        float lr = l_i[qs];
        lr += __shfl_xor(lr, 16);
        lr += __shfl_xor(lr, 32);
        float inv = 1.0f / lr;
        float ir[4];
        #pragma unroll
        for (int r = 0; r < 4; ++r) ir[r] = __shfl(inv, hi * 4 + r);
        #pragma unroll
        for (int nt = 0; nt < NNT; ++nt)
            #pragma unroll
            for (int r = 0; r < 4; ++r) {
                int l = q0 + qs * 16 + hi * 4 + r;
                O[(((size_t)b_ * L + l) * NHEADS + h_) * DH + nt * 16 + lo] =
                    f2bf(acc[qs][nt][r] * ir[r]);
            }
    }
}

// ---------------------------------------------------------------------------

extern "C" void kernel_launch(void* const* d_in, const int* in_sizes, int n_in,
                              void* d_out, int out_size, void* d_ws, size_t ws_size,
                              hipStream_t stream)
{
    static const int CHs[4] = {64, 128, 256, 512};
    static const int HWs[4] = {128, 64, 32, 16};

    const float* f1[4] = {(const float*)d_in[0], (const float*)d_in[1],
                          (const float*)d_in[2], (const float*)d_in[3]};
    const float* f2[4] = {nullptr, (const float*)d_in[4], (const float*)d_in[6],
                          (const float*)d_in[8]};
    const float* f3[4] = {nullptr, (const float*)d_in[5], (const float*)d_in[7],
                          (const float*)d_in[9]};

    // level 0: pass-through
    size_t out0_elems = (size_t)in_sizes[0];
    hipMemcpyAsync(d_out, d_in[0], out0_elems * sizeof(float),
                   hipMemcpyDeviceToDevice, stream);

    // workspace: 8 bf16 slots of 2*4096*128 elems (16 MB) + fp32 prep region.
    const size_t SL = (size_t)2 * 4096 * 128;
    u16* wsu = (u16*)d_ws;
    u16* Qa  = wsu + 0 * SL;
    u16* Ka  = wsu + 1 * SL;
    u16* Va  = wsu + 2 * SL;
    u16* Qb  = wsu + 3 * SL;
    u16* Kb  = wsu + 4 * SL;
    u16* Vb  = wsu + 5 * SL;
    u16* Ana = wsu + 6 * SL;
    u16* Anb = wsu + 7 * SL;
    float* wp1 = (float*)(wsu + 8 * SL);
    float* wp2 = wp1 + (size_t)128 * 384;
    float* wp3 = wp2 + (size_t)256 * 768;
    float* bp1 = wp3 + (size_t)512 * 1536;
    float* bp2 = bp1 + 512;
    float* bp3 = bp2 + 512;

    // per-level weight pointers
    const float* SQW[3]; const float* OWA[3]; const float* OWB[3];
    const float* OBA[3]; const float* OBB[3]; const float* SQB[3];
    for (int l = 0; l < 3; ++l) {
        const int bi = 10 + l * 10;
        OWA[l] = (const float*)d_in[bi + 2];
        OBA[l] = (const float*)d_in[bi + 3];
        OWB[l] = (const float*)d_in[bi + 6];
        OBB[l] = (const float*)d_in[bi + 7];
        SQW[l] = (const float*)d_in[bi + 8];
        SQB[l] = (const float*)d_in[bi + 9];
    }

    // prep: fold out_proj into squeeze weights + bias (one launch)
    prep_all<<<252 + 896, 256, 0, stream>>>(
        SQW[0], OWA[0], OWB[0], OBA[0], OBB[0], SQB[0], wp1, bp1,
        SQW[1], OWA[1], OWB[1], OBA[1], OBB[1], SQB[1], wp2, bp2,
        SQW[2], OWA[2], OWB[2], OBA[2], OBB[2], SQB[2], wp3, bp3);

    const float LOG2E = 1.44269504088896340736f;

    size_t outOff = out0_elems;
    for (int lvl = 1; lvl <= 3; ++lvl) {
        const int C = CHs[lvl];
        const int Hs = HWs[lvl];
        const int L = Hs * Hs;
        const int dh = C / NHEADS;
        const int M = 2 * L;  // B*L
        const float qscale = LOG2E / sqrtf((float)dh);
        const int bi = 10 + (lvl - 1) * 10;
        const float* a12w = (const float*)d_in[bi + 0];
        const float* a12b = (const float*)d_in[bi + 1];
        const float* a13w = (const float*)d_in[bi + 4];
        const float* a13b = (const float*)d_in[bi + 5];
        float* wp = (lvl == 1) ? wp1 : (lvl == 2) ? wp2 : wp3;
        float* bp = (lvl == 1) ? bp1 : (lvl == 2) ? bp2 : bp3;

        // 1) fused qkv (both attentions) — transposing X stage
        const int gx = 3 * C / 64;
        const int perAtt = gx * (M / 64);
        gemm_qkv<<<2 * perAtt, 256, 0, stream>>>(
            f1[lvl], f2[lvl], f3[lvl], a12w, a12b, a13w, a13b,
            Qa, Ka, Va, Qb, Kb, Vb, M, C, L, dh, qscale, gx, perAtt);

        // 2) fused flash (both attentions)
        if (dh == 64)
            flash_split<64, 4, 2><<<2 * (2 * NHEADS) * (L / 64), 512, 0, stream>>>(
                Qa, Ka, Va, Ana, Qb, Kb, Vb, Anb, L, L);
        else if (dh == 128)
            flash_split<128, 4, 1><<<2 * (2 * NHEADS) * (L / 32), 512, 0, stream>>>(
                Qa, Ka, Va, Ana, Qb, Kb, Vb, Anb, L, L);
        else
            flash_mfma<256, 1, 0><<<2 * (2 * NHEADS) * (L / 32), 128, 0, stream>>>(
                Qa, Ka, Va, Ana, Qb, Kb, Vb, Anb, L, L);

        // 3) squeeze (out_proj folded into Wp) into d_out (fp32 [b, n, l])
        dim3 gsq(C / 64, M / 64);
        gemm_squeeze<<<gsq, 256, 0, stream>>>(f1[lvl], Ana, Anb, wp, bp,
                                              (float*)d_out + outOff, M, C, L);
        outOff += (size_t)2 * C * L;
    }
}

// Round 19
// 248.004 us; speedup vs baseline: 1.4077x; 1.0188x over previous
//
#include <hip/hip_runtime.h>
#include <hip/hip_bf16.h>
#include <math.h>

#define NHEADS 2

typedef unsigned short u16;
typedef unsigned int u32;
typedef __attribute__((ext_vector_type(2))) unsigned int u32x2;
typedef __attribute__((ext_vector_type(8))) unsigned short u16x8;
typedef __attribute__((ext_vector_type(4))) unsigned short u16x4;
typedef __attribute__((ext_vector_type(8))) short short8;
typedef __attribute__((ext_vector_type(4))) short short4v;
typedef __attribute__((ext_vector_type(4))) float f32x4;

__device__ __forceinline__ u16 f2bf(float x) {
    __hip_bfloat16 h = __float2bfloat16(x);
    return __builtin_bit_cast(unsigned short, h);
}

// Truncating bf16 pack for POSITIVE finite values (P = exp2(..) in (0,2^8]).
__device__ __forceinline__ short4v pack_bf16_trunc(float p0, float p1,
                                                   float p2, float p3) {
    u32 w0 = (__builtin_bit_cast(u32, p0) >> 16) |
             (__builtin_bit_cast(u32, p1) & 0xFFFF0000u);
    u32 w1 = (__builtin_bit_cast(u32, p2) >> 16) |
             (__builtin_bit_cast(u32, p3) & 0xFFFF0000u);
    u32x2 w = {w0, w1};
    return __builtin_bit_cast(short4v, w);
}

// ---------------------------------------------------------------------------
// Fused qkv GEMM, both attentions in one launch (round-13 proven).
// ---------------------------------------------------------------------------
__global__ __launch_bounds__(256) void gemm_qkv(
    const float* __restrict__ f1, const float* __restrict__ f2,
    const float* __restrict__ f3,
    const float* __restrict__ w12, const float* __restrict__ b12,
    const float* __restrict__ w13, const float* __restrict__ b13,
    u16* __restrict__ Qa, u16* __restrict__ Ka, u16* __restrict__ Va,
    u16* __restrict__ Qb, u16* __restrict__ Kb, u16* __restrict__ Vb,
    int M, int C, int L, int dh, float qscale, int gx, int perAtt)
{
    const int att = blockIdx.x / perAtt;
    const int r = blockIdx.x - att * perAtt;
    const int n0 = (r % gx) * 64;
    const int m0 = (r / gx) * 64;
    const int K = C;
    __shared__ __align__(16) u16 Xs[64][72];
    __shared__ __align__(16) u16 Ws[64][72];
    const int tid = threadIdx.x;
    const int wid = tid >> 6, lane = tid & 63;
    const int lo = lane & 15, hi = lane >> 4;
    const int wm = wid >> 1, wn = wid & 1;

    const float* __restrict__ Xf = (n0 < C) ? f1 : (att ? f3 : f2);
    const float* __restrict__ W = att ? w13 : w12;
    const float* __restrict__ bias = att ? b13 : b12;
    const int bb = m0 / L;
    const int l0 = m0 - bb * L;

    f32x4 acc[2][2];
    #pragma unroll
    for (int i = 0; i < 2; ++i)
        #pragma unroll
        for (int j = 0; j < 2; ++j)
            #pragma unroll
            for (int rr = 0; rr < 4; ++rr) acc[i][j][rr] = 0.f;

    f32x4 xregf[4];
    f32x4 wreg[4];
    const int kx = tid >> 4;
    const int lc = tid & 15;

    auto load_x = [&](int k0) {
        #pragma unroll
        for (int i = 0; i < 4; ++i)
            xregf[i] = *(const f32x4*)&Xf[((size_t)(bb * C) + k0 + kx + 16 * i) * L + l0 + lc * 4];
    };
    auto store_x = [&]() {
        #pragma unroll
        for (int i = 0; i < 4; ++i)
            #pragma unroll
            for (int j = 0; j < 4; ++j)
                Xs[lc * 4 + j][kx + 16 * i] = f2bf(xregf[i][j]);
    };
    auto load_w = [&](int k0) {
        #pragma unroll
        for (int p = 0; p < 4; ++p) {
            int c = tid + p * 256;
            int row = c >> 4, kc = c & 15;
            wreg[p] = *(const f32x4*)&W[(size_t)(n0 + row) * K + k0 + kc * 4];
        }
    };

    load_x(0);
    load_w(0);
    const int ns = K / 64;
    for (int s = 0; s < ns; ++s) {
        __syncthreads();
        store_x();
        #pragma unroll
        for (int p = 0; p < 4; ++p) {
            int c = tid + p * 256;
            int row = c >> 4, kc = c & 15;
            u16x4 cv = {f2bf(wreg[p][0]), f2bf(wreg[p][1]),
                        f2bf(wreg[p][2]), f2bf(wreg[p][3])};
            *(u16x4*)&Ws[row][kc * 4] = cv;
        }
        __syncthreads();
        if (s + 1 < ns) { load_x((s + 1) * 64); load_w((s + 1) * 64); }
        #pragma unroll
        for (int kk = 0; kk < 2; ++kk) {
            short8 wf0 = *(const short8*)&Ws[wn * 32 + lo][kk * 32 + hi * 8];
            short8 wf1 = *(const short8*)&Ws[wn * 32 + 16 + lo][kk * 32 + hi * 8];
            short8 xf0 = *(const short8*)&Xs[wm * 32 + lo][kk * 32 + hi * 8];
            short8 xf1 = *(const short8*)&Xs[wm * 32 + 16 + lo][kk * 32 + hi * 8];
            acc[0][0] = __builtin_amdgcn_mfma_f32_16x16x32_bf16(wf0, xf0, acc[0][0], 0, 0, 0);
            acc[0][1] = __builtin_amdgcn_mfma_f32_16x16x32_bf16(wf1, xf0, acc[0][1], 0, 0, 0);
            acc[1][0] = __builtin_amdgcn_mfma_f32_16x16x32_bf16(wf0, xf1, acc[1][0], 0, 0, 0);
            acc[1][1] = __builtin_amdgcn_mfma_f32_16x16x32_bf16(wf1, xf1, acc[1][1], 0, 0, 0);
        }
    }

    #pragma unroll
    for (int nt = 0; nt < 2; ++nt) {
        const int nb = n0 + wn * 32 + nt * 16 + hi * 4;
        const float b0 = bias[nb + 0], b1 = bias[nb + 1];
        const float b2 = bias[nb + 2], b3 = bias[nb + 3];
        const int which = nb / C;
        const int co = nb - which * C;
        const int h = co / dh;
        const int dd = co - h * dh;
        u16* dst = (which == 0) ? (att ? Qb : Qa)
                 : (which == 1) ? (att ? Kb : Ka) : (att ? Vb : Va);
        const float sc = (which == 0) ? qscale : 1.0f;
        #pragma unroll
        for (int mt = 0; mt < 2; ++mt) {
            int m = m0 + wm * 32 + mt * 16 + lo;
            int b_ = m / L; int l = m - b_ * L;
            u16x4 pk = {f2bf((acc[mt][nt][0] + b0) * sc),
                        f2bf((acc[mt][nt][1] + b1) * sc),
                        f2bf((acc[mt][nt][2] + b2) * sc),
                        f2bf((acc[mt][nt][3] + b3) * sc)};
            *(u16x4*)&dst[((size_t)(b_ * NHEADS + h) * L + l) * dh + dd] = pk;
        }
    }
}

// ---------------------------------------------------------------------------
// prep_all: prep_w (blocks 0..251) + prep_b (blocks 252..1147), one launch.
// ---------------------------------------------------------------------------
__global__ __launch_bounds__(256) void prep_all(
    const float* __restrict__ s1, const float* __restrict__ oa1,
    const float* __restrict__ ob1, const float* __restrict__ oba1,
    const float* __restrict__ obb1, const float* __restrict__ sqb1,
    float* __restrict__ w1, float* __restrict__ b1,
    const float* __restrict__ s2, const float* __restrict__ oa2,
    const float* __restrict__ ob2, const float* __restrict__ oba2,
    const float* __restrict__ obb2, const float* __restrict__ sqb2,
    float* __restrict__ w2, float* __restrict__ b2,
    const float* __restrict__ s3, const float* __restrict__ oa3,
    const float* __restrict__ ob3, const float* __restrict__ oba3,
    const float* __restrict__ obb3, const float* __restrict__ sqb3,
    float* __restrict__ w3, float* __restrict__ b3)
{
    const int tid = threadIdx.x;
    if (blockIdx.x < 252) {
        int bid = blockIdx.x;
        int C; const float *sqw, *owa, *owb; float* wp;
        if (bid < 12)      { C = 128; sqw = s1; owa = oa1; owb = ob1; wp = w1; }
        else if (bid < 60) { bid -= 12; C = 256; sqw = s2; owa = oa2; owb = ob2; wp = w2; }
        else               { bid -= 60; C = 512; sqw = s3; owa = oa3; owb = ob3; wp = w3; }
        const int K3 = 3 * C;
        const int gxw = K3 / 64;
        const int n0 = (bid / gxw) * 64;
        const int kc0 = (bid % gxw) * 64;

        if (kc0 < C) {
            for (int p = tid; p < 64 * 64; p += 256) {
                int i = p >> 6, j = p & 63;
                wp[(size_t)(n0 + i) * K3 + kc0 + j] = sqw[(size_t)(n0 + i) * K3 + kc0 + j];
            }
            return;
        }
        const int which = kc0 / C;
        const int kp0 = kc0 - which * C;
        const float* __restrict__ ow = (which == 1) ? owa : owb;

        __shared__ __align__(16) u16 As[64][72];
        __shared__ __align__(16) u16 Bs[64][72];
        const int wid = tid >> 6, lane = tid & 63;
        const int lo = lane & 15, hi = lane >> 4;
        const int wm = wid >> 1, wn = wid & 1;

        f32x4 acc[2][2];
        #pragma unroll
        for (int i = 0; i < 2; ++i)
            #pragma unroll
            for (int j = 0; j < 2; ++j)
                #pragma unroll
                for (int rr = 0; rr < 4; ++rr) acc[i][j][rr] = 0.f;

        for (int ct = 0; ct < C / 64; ++ct) {
            __syncthreads();
            for (int p = tid; p < 64 * 64; p += 256) {
                int i = p >> 6, j = p & 63;
                As[i][j] = f2bf(sqw[(size_t)(n0 + i) * K3 + which * C + ct * 64 + j]);
                Bs[j][i] = f2bf(ow[(size_t)(ct * 64 + i) * C + kp0 + j]);
            }
            __syncthreads();
            #pragma unroll
            for (int kk = 0; kk < 2; ++kk) {
                short8 wf0 = *(const short8*)&As[wn * 32 + lo][kk * 32 + hi * 8];
                short8 wf1 = *(const short8*)&As[wn * 32 + 16 + lo][kk * 32 + hi * 8];
                short8 xf0 = *(const short8*)&Bs[wm * 32 + lo][kk * 32 + hi * 8];
                short8 xf1 = *(const short8*)&Bs[wm * 32 + 16 + lo][kk * 32 + hi * 8];
                acc[0][0] = __builtin_amdgcn_mfma_f32_16x16x32_bf16(wf0, xf0, acc[0][0], 0, 0, 0);
                acc[0][1] = __builtin_amdgcn_mfma_f32_16x16x32_bf16(wf1, xf0, acc[0][1], 0, 0, 0);
                acc[1][0] = __builtin_amdgcn_mfma_f32_16x16x32_bf16(wf0, xf1, acc[1][0], 0, 0, 0);
                acc[1][1] = __builtin_amdgcn_mfma_f32_16x16x32_bf16(wf1, xf1, acc[1][1], 0, 0, 0);
            }
        }
        #pragma unroll
        for (int nt = 0; nt < 2; ++nt) {
            const int nb = n0 + wn * 32 + nt * 16 + hi * 4;
            #pragma unroll
            for (int mt = 0; mt < 2; ++mt) {
                const int col = kc0 + wm * 32 + mt * 16 + lo;
                #pragma unroll
                for (int rr = 0; rr < 4; ++rr)
                    wp[(size_t)(nb + rr) * K3 + col] = acc[mt][nt][rr];
            }
        }
        return;
    }

    int bid = blockIdx.x - 252;
    int C, n;
    const float *sqw, *oba, *obb, *sqb; float* bp;
    if (bid < 128)      { C = 128; n = bid;       sqw = s1; oba = oba1; obb = obb1; sqb = sqb1; bp = b1; }
    else if (bid < 384) { C = 256; n = bid - 128; sqw = s2; oba = oba2; obb = obb2; sqb = sqb2; bp = b2; }
    else                { C = 512; n = bid - 384; sqw = s3; oba = oba3; obb = obb3; sqb = sqb3; bp = b3; }

    const float* row = sqw + (size_t)n * 3 * C;
    float s = 0.f;
    for (int c = tid; c < C; c += 256)
        s += row[C + c] * oba[c] + row[2 * C + c] * obb[c];
    #pragma unroll
    for (int off = 1; off < 64; off <<= 1)
        s += __shfl_xor(s, off);
    __shared__ float ws[4];
    const int wv = tid >> 6;
    if ((tid & 63) == 0) ws[wv] = s;
    __syncthreads();
    if (tid == 0)
        bp[n] = sqb[n] + ws[0] + ws[1] + ws[2] + ws[3];
}

// ---------------------------------------------------------------------------
// Squeeze GEMM (round-13 proven).
// ---------------------------------------------------------------------------
__global__ __launch_bounds__(256) void gemm_squeeze(
    const float* __restrict__ F1, const u16* __restrict__ X1,
    const u16* __restrict__ X2,
    const float* __restrict__ W, const float* __restrict__ bias,
    float* __restrict__ out, int M, int C, int L)
{
    const int n0 = blockIdx.x * 64;
    const int m0 = blockIdx.y * 64;
    const int K = 3 * C;
    __shared__ __align__(16) u16 Xs[64][72];
    __shared__ __align__(16) u16 Ws[64][72];
    const int tid = threadIdx.x;
    const int wid = tid >> 6, lane = tid & 63;
    const int lo = lane & 15, hi = lane >> 4;
    const int wm = wid >> 1, wn = wid & 1;
    const int bb = m0 / L;
    const int l0 = m0 - bb * L;

    f32x4 acc[2][2];
    #pragma unroll
    for (int i = 0; i < 2; ++i)
        #pragma unroll
        for (int j = 0; j < 2; ++j)
            #pragma unroll
            for (int rr = 0; rr < 4; ++rr) acc[i][j][rr] = 0.f;

    f32x4 xregf[4];
    u16x8 xreg[2];
    f32x4 wreg[4];
    const int kx = tid >> 4;
    const int lc = tid & 15;

    auto load_x = [&](int k0) {
        if (k0 < C) {
            #pragma unroll
            for (int i = 0; i < 4; ++i)
                xregf[i] = *(const f32x4*)&F1[((size_t)(bb * C) + k0 + kx + 16 * i) * L + l0 + lc * 4];
        } else {
            const u16* src = (k0 < 2 * C) ? X1 : X2;
            int kl = k0 - ((k0 < 2 * C) ? C : 2 * C);
            #pragma unroll
            for (int p = 0; p < 2; ++p) {
                int c = tid + p * 256;
                int row = c >> 3, kc = c & 7;
                xreg[p] = *(const u16x8*)&src[(size_t)(m0 + row) * C + kl + kc * 8];
            }
        }
    };
    auto store_x = [&](int k0) {
        if (k0 < C) {
            #pragma unroll
            for (int i = 0; i < 4; ++i)
                #pragma unroll
                for (int j = 0; j < 4; ++j)
                    Xs[lc * 4 + j][kx + 16 * i] = f2bf(xregf[i][j]);
        } else {
            #pragma unroll
            for (int p = 0; p < 2; ++p) {
                int c = tid + p * 256;
                int row = c >> 3, kc = c & 7;
                *(u16x8*)&Xs[row][kc * 8] = xreg[p];
            }
        }
    };
    auto load_w = [&](int k0) {
        #pragma unroll
        for (int p = 0; p < 4; ++p) {
            int c = tid + p * 256;
            int row = c >> 4, kc = c & 15;
            wreg[p] = *(const f32x4*)&W[(size_t)(n0 + row) * K + k0 + kc * 4];
        }
    };

    load_x(0);
    load_w(0);
    const int ns = K / 64;
    for (int s = 0; s < ns; ++s) {
        __syncthreads();
        store_x(s * 64);
        #pragma unroll
        for (int p = 0; p < 4; ++p) {
            int c = tid + p * 256;
            int row = c >> 4, kc = c & 15;
            u16x4 cv = {f2bf(wreg[p][0]), f2bf(wreg[p][1]),
                        f2bf(wreg[p][2]), f2bf(wreg[p][3])};
            *(u16x4*)&Ws[row][kc * 4] = cv;
        }
        __syncthreads();
        if (s + 1 < ns) { load_x((s + 1) * 64); load_w((s + 1) * 64); }
        #pragma unroll
        for (int kk = 0; kk < 2; ++kk) {
            short8 wf0 = *(const short8*)&Ws[wn * 32 + lo][kk * 32 + hi * 8];
            short8 wf1 = *(const short8*)&Ws[wn * 32 + 16 + lo][kk * 32 + hi * 8];
            short8 xf0 = *(const short8*)&Xs[wm * 32 + lo][kk * 32 + hi * 8];
            short8 xf1 = *(const short8*)&Xs[wm * 32 + 16 + lo][kk * 32 + hi * 8];
            acc[0][0] = __builtin_amdgcn_mfma_f32_16x16x32_bf16(wf0, xf0, acc[0][0], 0, 0, 0);
            acc[0][1] = __builtin_amdgcn_mfma_f32_16x16x32_bf16(wf1, xf0, acc[0][1], 0, 0, 0);
            acc[1][0] = __builtin_amdgcn_mfma_f32_16x16x32_bf16(wf0, xf1, acc[1][0], 0, 0, 0);
            acc[1][1] = __builtin_amdgcn_mfma_f32_16x16x32_bf16(wf1, xf1, acc[1][1], 0, 0, 0);
        }
    }

    #pragma unroll
    for (int nt = 0; nt < 2; ++nt) {
        const int nb = n0 + wn * 32 + nt * 16 + hi * 4;
        const float b0 = bias[nb + 0], b1 = bias[nb + 1];
        const float b2 = bias[nb + 2], b3 = bias[nb + 3];
        #pragma unroll
        for (int mt = 0; mt < 2; ++mt) {
            int m = m0 + wm * 32 + mt * 16 + lo;
            int b_ = m / L; int l = m - b_ * L;
            out[((size_t)(b_ * C + nb + 0)) * L + l] = acc[mt][nt][0] + b0;
            out[((size_t)(b_ * C + nb + 1)) * L + l] = acc[mt][nt][1] + b1;
            out[((size_t)(b_ * C + nb + 2)) * L + l] = acc[mt][nt][2] + b2;
            out[((size_t)(b_ * C + nb + 3)) * L + l] = acc[mt][nt][3] + b3;
        }
    }
}

// ---------------------------------------------------------------------------
// Generalized split flash. Round-19: XCD-affinity block remap — the 8
// (att,bh) groups map to the 8 XCDs (grp = blockIdx&7), so all q-tiles
// sharing one head's K/V live on ONE XCD's L2 (kills the ~3x HBM re-fetch
// across non-coherent L2s; K-prefetch becomes L2-hit latency).
// ---------------------------------------------------------------------------
template <int DH, int NPAR, int NQS>
__global__ __launch_bounds__(128 * NPAR) void flash_split(
    const u16* __restrict__ Q1, const u16* __restrict__ K1,
    const u16* __restrict__ V1, u16* __restrict__ O1,
    const u16* __restrict__ Q2, const u16* __restrict__ K2,
    const u16* __restrict__ V2, u16* __restrict__ O2, int L, int S)
{
    constexpr int KB = 64;
    constexpr int QW = 16 * NQS;
    constexpr int QB = 2 * QW;
    constexpr int NKK = DH / 32;
    constexpr int NNT = DH / 16;
    constexpr int DG = DH / 8;
    constexpr int SLOTS = DG / 8;
    constexpr int SZ_VT = 2 * NPAR * DH * KB * 2;
    constexpr int MST = DH + 4;
    constexpr int P = NPAR - 1;

    __shared__ __align__(16) char smem[SZ_VT];
    u16 (*Vt)[NPAR][DH][KB] = (u16 (*)[NPAR][DH][KB])smem;
    float* MrgAcc = (float*)smem;
    float* MrgML  = (float*)(smem + (size_t)2 * P * QW * MST * 4);

    // XCD-affinity remap (bijective): 8 groups = 2 att x 4 bh -> blockIdx&7.
    const int grp = blockIdx.x & 7;
    const int qt  = blockIdx.x >> 3;
    const int att = grp >> 2;
    const int bh  = grp & 3;
    const u16* __restrict__ Q = att ? Q2 : Q1;
    const u16* __restrict__ K = att ? K2 : K1;
    const u16* __restrict__ V = att ? V2 : V1;
    u16* __restrict__ O = att ? O2 : O1;

    const int tid = threadIdx.x;
    const int w = tid >> 6;
    const int lane = tid & 63;
    const int lo = lane & 15, hi = lane >> 4;
    const int qg = w & 1, par = w >> 1;
    const int q0 = qt * QB + qg * QW;

    short8 qf[NQS][NKK];
    #pragma unroll
    for (int qs = 0; qs < NQS; ++qs)
        #pragma unroll
        for (int kk = 0; kk < NKK; ++kk)
            qf[qs][kk] = *(const short8*)&Q[((size_t)bh * L + q0 + qs * 16 + lo) * DH + kk * 32 + hi * 8];

    f32x4 acc[NQS][NNT];
    #pragma unroll
    for (int qs = 0; qs < NQS; ++qs)
        #pragma unroll
        for (int nt = 0; nt < NNT; ++nt)
            #pragma unroll
            for (int r = 0; r < 4; ++r) acc[qs][nt][r] = 0.f;
    float m_i[NQS], l_i[NQS];
    #pragma unroll
    for (int qs = 0; qs < NQS; ++qs) { m_i[qs] = -1e30f; l_i[qs] = 0.f; }

    const u16* Kbase = K + (size_t)bh * S * DH;
    const u16* Vbase = V + (size_t)bh * S * DH;

    short8 kf[4][NKK];
    auto load_kf = [&](int r) {
        const u16* Kt = Kbase + (size_t)(NPAR * r + par) * KB * DH;
        #pragma unroll
        for (int st = 0; st < 4; ++st)
            #pragma unroll
            for (int kk = 0; kk < NKK; ++kk)
                kf[st][kk] = *(const short8*)&Kt[(size_t)(st * 16 + lo) * DH + kk * 32 + hi * 8];
    };

    const int pt = (NPAR == 4) ? (tid >> 7) : ((tid >> 7) & (NPAR - 1));
    const int u = tid & 127;
    int dV0[SLOTS], sV0[SLOTS];
    #pragma unroll
    for (int z = 0; z < SLOTS; ++z) {
        int e = u + z * 128;
        dV0[z] = (e % DG) * 8;
        sV0[z] = (e / DG) * 4;
    }

    u16x8 vreg[SLOTS][4];

    auto loadslots = [&](int r) {
        const u16* Vp = Vbase + (size_t)(NPAR * r + pt) * KB * DH;
        #pragma unroll
        for (int z = 0; z < SLOTS; ++z)
            #pragma unroll
            for (int si = 0; si < 4; ++si)
                vreg[z][si] = *(const u16x8*)&Vp[(size_t)(sV0[z] + si) * DH + dV0[z]];
    };
    auto writeslots = [&](int buf) {
        #pragma unroll
        for (int z = 0; z < SLOTS; ++z)
            #pragma unroll
            for (int j = 0; j < 8; ++j) {
                int d = dV0[z] + j;
                int g = ((d >> 3) ^ d) & 7;
                int scol = (sV0[z] & 7) | ((((sV0[z] >> 3) ^ g) & 7) << 3);
                u16x4 wj = {vreg[z][0][j], vreg[z][1][j], vreg[z][2][j], vreg[z][3][j]};
                *(u16x4*)&Vt[buf][pt][d][scol] = wj;
            }
    };

    const int NR = S / (KB * NPAR);

    load_kf(0);
    loadslots(0);
    writeslots(0);
    __syncthreads();
    if (1 < NR) loadslots(1);

    for (int r = 0; r < NR; ++r) {
        const int cur = r & 1;

        f32x4 sacc[4][NQS];
        #pragma unroll
        for (int st = 0; st < 4; ++st)
            #pragma unroll
            for (int qs = 0; qs < NQS; ++qs)
                #pragma unroll
                for (int rr = 0; rr < 4; ++rr) sacc[st][qs][rr] = 0.f;
        #pragma unroll
        for (int st = 0; st < 4; ++st) {
            #pragma unroll
            for (int kk = 0; kk < NKK; ++kk) {
                #pragma unroll
                for (int qs = 0; qs < NQS; ++qs)
                    sacc[st][qs] = __builtin_amdgcn_mfma_f32_16x16x32_bf16(
                        kf[st][kk], qf[qs][kk], sacc[st][qs], 0, 0, 0);
            }
        }

        if (r + 1 < NR) load_kf(r + 1);

        float mn[NQS], ts[NQS];
        #pragma unroll
        for (int qs = 0; qs < NQS; ++qs) {
            float a0 = fmaxf(fmaxf(sacc[0][qs][0], sacc[0][qs][1]),
                             fmaxf(sacc[0][qs][2], sacc[0][qs][3]));
            float a1 = fmaxf(fmaxf(sacc[1][qs][0], sacc[1][qs][1]),
                             fmaxf(sacc[1][qs][2], sacc[1][qs][3]));
            float a2 = fmaxf(fmaxf(sacc[2][qs][0], sacc[2][qs][1]),
                             fmaxf(sacc[2][qs][2], sacc[2][qs][3]));
            float a3 = fmaxf(fmaxf(sacc[3][qs][0], sacc[3][qs][1]),
                             fmaxf(sacc[3][qs][2], sacc[3][qs][3]));
            float tm = fmaxf(fmaxf(a0, a1), fmaxf(a2, a3));
            tm = fmaxf(tm, __shfl_xor(tm, 16));
            tm = fmaxf(tm, __shfl_xor(tm, 32));
            const bool grow = __any(tm > m_i[qs] + 8.0f);
            mn[qs] = grow ? fmaxf(m_i[qs], tm) : m_i[qs];
            ts[qs] = 0.f;
            if (grow) {
                float alpha = __builtin_amdgcn_exp2f(m_i[qs] - mn[qs]);
                m_i[qs] = mn[qs];
                l_i[qs] *= alpha;
                float ar[4];
                #pragma unroll
                for (int rr = 0; rr < 4; ++rr) ar[rr] = __shfl(alpha, hi * 4 + rr);
                #pragma unroll
                for (int nt = 0; nt < NNT; ++nt)
                    #pragma unroll
                    for (int rr = 0; rr < 4; ++rr) acc[qs][nt][rr] *= ar[rr];
            }
        }

        if (r + 1 < NR) writeslots(cur ^ 1);

        __builtin_amdgcn_s_setprio(1);
        #pragma unroll
        for (int st = 0; st < 4; ++st) {
            short4v pa_[NQS];
            #pragma unroll
            for (int qs = 0; qs < NQS; ++qs) {
                float p0 = __builtin_amdgcn_exp2f(sacc[st][qs][0] - mn[qs]);
                float p1 = __builtin_amdgcn_exp2f(sacc[st][qs][1] - mn[qs]);
                float p2 = __builtin_amdgcn_exp2f(sacc[st][qs][2] - mn[qs]);
                float p3 = __builtin_amdgcn_exp2f(sacc[st][qs][3] - mn[qs]);
                ts[qs] += (p0 + p1) + (p2 + p3);
                pa_[qs] = pack_bf16_trunc(p0, p1, p2, p3);
            }
            const int s0 = st * 16 + hi * 4;
            #pragma unroll
            for (int nt = 0; nt < NNT; ++nt) {
                int d = nt * 16 + lo;
                int g = ((d >> 3) ^ d) & 7;
                int scol = (s0 & 7) | ((((s0 >> 3) ^ g) & 7) << 3);
                short4v vb = *(const short4v*)&Vt[cur][par][d][scol];
                #pragma unroll
                for (int qs = 0; qs < NQS; ++qs)
                    acc[qs][nt] = __builtin_amdgcn_mfma_f32_16x16x16bf16_1k(
                        pa_[qs], vb, acc[qs][nt], 0, 0, 0);
            }
        }
        __builtin_amdgcn_s_setprio(0);

        #pragma unroll
        for (int qs = 0; qs < NQS; ++qs)
            l_i[qs] += ts[qs];

        __syncthreads();
        if (r + 2 < NR) loadslots(r + 2);
    }

    #pragma unroll
    for (int qs = 0; qs < NQS; ++qs) {
        float lr = l_i[qs];
        lr += __shfl_xor(lr, 16);
        lr += __shfl_xor(lr, 32);
        l_i[qs] = lr;
    }

    const int b_ = bh / NHEADS, h_ = bh % NHEADS;
    if (par != 0) {
        const int mi = qg * P + par - 1;
        float* ma = MrgAcc + (size_t)mi * QW * MST;
        #pragma unroll
        for (int qs = 0; qs < NQS; ++qs) {
            #pragma unroll
            for (int nt = 0; nt < NNT; ++nt)
                #pragma unroll
                for (int rr = 0; rr < 4; ++rr)
                    ma[(size_t)(qs * 16 + hi * 4 + rr) * MST + nt * 16 + lo] = acc[qs][nt][rr];
            if (hi == 0) {
                MrgML[(mi * 2 + 0) * QW + qs * 16 + lo] = m_i[qs];
                MrgML[(mi * 2 + 1) * QW + qs * 16 + lo] = l_i[qs];
            }
        }
    }
    __syncthreads();
    if (par == 0) {
        #pragma unroll
        for (int qs = 0; qs < NQS; ++qs) {
            float mp[P > 0 ? P : 1], lp[P > 0 ? P : 1];
            float mt = m_i[qs];
            #pragma unroll
            for (int p = 0; p < P; ++p) {
                mp[p] = MrgML[((qg * P + p) * 2 + 0) * QW + qs * 16 + lo];
                lp[p] = MrgML[((qg * P + p) * 2 + 1) * QW + qs * 16 + lo];
                mt = fmaxf(mt, mp[p]);
            }
            float c0 = __builtin_amdgcn_exp2f(m_i[qs] - mt);
            float lt = c0 * l_i[qs];
            float cp[P > 0 ? P : 1];
            #pragma unroll
            for (int p = 0; p < P; ++p) {
                cp[p] = __builtin_amdgcn_exp2f(mp[p] - mt);
                lt += cp[p] * lp[p];
            }
            float linv = 1.0f / lt;
            c0 *= linv;
            #pragma unroll
            for (int p = 0; p < P; ++p) cp[p] *= linv;
            float c0r[4], cpr[P > 0 ? P : 1][4];
            #pragma unroll
            for (int rr = 0; rr < 4; ++rr) {
                c0r[rr] = __shfl(c0, hi * 4 + rr);
                #pragma unroll
                for (int p = 0; p < P; ++p) cpr[p][rr] = __shfl(cp[p], hi * 4 + rr);
            }
            #pragma unroll
            for (int nt = 0; nt < NNT; ++nt)
                #pragma unroll
                for (int rr = 0; rr < 4; ++rr) {
                    int q = qs * 16 + hi * 4 + rr;
                    float ov = acc[qs][nt][rr] * c0r[rr];
                    #pragma unroll
                    for (int p = 0; p < P; ++p)
                        ov += MrgAcc[((size_t)(qg * P + p) * QW + q) * MST + nt * 16 + lo] * cpr[p][rr];
                    O[(((size_t)b_ * L + q0 + q) * NHEADS + h_) * DH + nt * 16 + lo] = f2bf(ov);
                }
        }
    }
}

// ---------------------------------------------------------------------------
// Level-3 flash: 128 threads, 2 waves, in-reg P (XCD remap applied too).
// ---------------------------------------------------------------------------
template <int DH, int NQS, int PRE>
__global__ __launch_bounds__(128) void flash_mfma(
    const u16* __restrict__ Q1, const u16* __restrict__ K1,
    const u16* __restrict__ V1, u16* __restrict__ O1,
    const u16* __restrict__ Q2, const u16* __restrict__ K2,
    const u16* __restrict__ V2, u16* __restrict__ O2, int L, int S)
{
    constexpr int KB = 64;
    constexpr int QW = NQS * 16;
    constexpr int QB = 2 * QW;
    constexpr int DH8 = DH / 8;
    constexpr int KC = (KB * DH8) / 128;
    constexpr int VU = (16 * DH8) / 128;
    constexpr int NKK = DH / 32;
    constexpr int NNT = DH / 16;

    __shared__ __align__(16) u16 Ks[KB][DH + 8];
    __shared__ __align__(16) u16 Vt[DH][KB];

    // XCD-affinity remap (bijective): 8 groups = 2 att x 4 bh -> blockIdx&7.
    const int grp = blockIdx.x & 7;
    const int qt  = blockIdx.x >> 3;
    const int att = grp >> 2;
    const int bh  = grp & 3;
    const u16* __restrict__ Q = att ? Q2 : Q1;
    const u16* __restrict__ K = att ? K2 : K1;
    const u16* __restrict__ V = att ? V2 : V1;
    u16* __restrict__ O = att ? O2 : O1;

    const int tid = threadIdx.x;
    const int wv = tid >> 6;
    const int lane = tid & 63;
    const int lo = lane & 15;
    const int hi = lane >> 4;
    const int q0 = qt * QB + wv * QW;

    short8 qf[NQS][NKK];
    #pragma unroll
    for (int qs = 0; qs < NQS; ++qs)
        #pragma unroll
        for (int kk = 0; kk < NKK; ++kk)
            qf[qs][kk] = *(const short8*)&Q[((size_t)bh * L + q0 + qs * 16 + lo) * DH + kk * 32 + hi * 8];

    f32x4 acc[NQS][NNT];
    #pragma unroll
    for (int qs = 0; qs < NQS; ++qs)
        #pragma unroll
        for (int nt = 0; nt < NNT; ++nt)
            #pragma unroll
            for (int r = 0; r < 4; ++r) acc[qs][nt][r] = 0.f;
    float m_i[NQS], l_i[NQS];
    #pragma unroll
    for (int qs = 0; qs < NQS; ++qs) { m_i[qs] = -1e30f; l_i[qs] = 0.f; }

    const int NT = S / KB;
    u16x8 kreg[PRE ? KC : 1];
    u16x8 vreg[PRE ? VU : 1][4];

    const u16* Kbase = K + (size_t)bh * S * DH;
    const u16* Vbase = V + (size_t)bh * S * DH;

    auto vwrite = [&](int d, int s0, u16x4 wj) {
        int g = ((d >> 3) ^ d) & 7;
        int scol = (s0 & 7) | ((((s0 >> 3) ^ g) & 7) << 3);
        *(u16x4*)&Vt[d][scol] = wj;
    };

    if (PRE) {
        #pragma unroll
        for (int i = 0; i < KC; ++i) {
            int idx = tid + i * 128;
            kreg[i] = *(const u16x8*)&Kbase[(size_t)(idx / DH8) * DH + (idx % DH8) * 8];
        }
        #pragma unroll
        for (int u = 0; u < VU; ++u) {
            int uu = tid + u * 128;
            int d0 = (uu % DH8) * 8, s0 = (uu / DH8) * 4;
            #pragma unroll
            for (int si = 0; si < 4; ++si)
                vreg[u][si] = *(const u16x8*)&Vbase[(size_t)(s0 + si) * DH + d0];
        }
    }

    for (int t = 0; t < NT; ++t) {
        __syncthreads();
        if (PRE) {
            #pragma unroll
            for (int i = 0; i < KC; ++i) {
                int idx = tid + i * 128;
                *(u16x8*)&Ks[idx / DH8][(idx % DH8) * 8] = kreg[i];
            }
            #pragma unroll
            for (int u = 0; u < VU; ++u) {
                int uu = tid + u * 128;
                int d0 = (uu % DH8) * 8, s0 = (uu / DH8) * 4;
                #pragma unroll
                for (int j = 0; j < 8; ++j) {
                    u16x4 wj = {vreg[u][0][j], vreg[u][1][j], vreg[u][2][j], vreg[u][3][j]};
                    vwrite(d0 + j, s0, wj);
                }
            }
        } else {
            const u16* Kp = Kbase + (size_t)t * KB * DH;
            const u16* Vp = Vbase + (size_t)t * KB * DH;
            #pragma unroll
            for (int i = 0; i < KC; ++i) {
                int idx = tid + i * 128;
                *(u16x8*)&Ks[idx / DH8][(idx % DH8) * 8] =
                    *(const u16x8*)&Kp[(size_t)(idx / DH8) * DH + (idx % DH8) * 8];
            }
            #pragma unroll
            for (int u = 0; u < VU; ++u) {
                int uu = tid + u * 128;
                int d0 = (uu % DH8) * 8, s0 = (uu / DH8) * 4;
                u16x8 v0 = *(const u16x8*)&Vp[(size_t)(s0 + 0) * DH + d0];
                u16x8 v1 = *(const u16x8*)&Vp[(size_t)(s0 + 1) * DH + d0];
                u16x8 v2 = *(const u16x8*)&Vp[(size_t)(s0 + 2) * DH + d0];
                u16x8 v3 = *(const u16x8*)&Vp[(size_t)(s0 + 3) * DH + d0];
                #pragma unroll
                for (int j = 0; j < 8; ++j) {
                    u16x4 wj = {v0[j], v1[j], v2[j], v3[j]};
                    vwrite(d0 + j, s0, wj);
                }
            }
        }
        __syncthreads();

        if (PRE && t + 1 < NT) {
            const u16* Kp = Kbase + (size_t)(t + 1) * KB * DH;
            const u16* Vp = Vbase + (size_t)(t + 1) * KB * DH;
            #pragma unroll
            for (int i = 0; i < KC; ++i) {
                int idx = tid + i * 128;
                kreg[i] = *(const u16x8*)&Kp[(size_t)(idx / DH8) * DH + (idx % DH8) * 8];
            }
            #pragma unroll
            for (int u = 0; u < VU; ++u) {
                int uu = tid + u * 128;
                int d0 = (uu % DH8) * 8, s0 = (uu / DH8) * 4;
                #pragma unroll
                for (int si = 0; si < 4; ++si)
                    vreg[u][si] = *(const u16x8*)&Vp[(size_t)(s0 + si) * DH + d0];
            }
        }

        f32x4 sacc[4][NQS];
        #pragma unroll
        for (int st = 0; st < 4; ++st)
            #pragma unroll
            for (int qs = 0; qs < NQS; ++qs)
                #pragma unroll
                for (int r = 0; r < 4; ++r) sacc[st][qs][r] = 0.f;
        #pragma unroll
        for (int st = 0; st < 4; ++st) {
            #pragma unroll
            for (int kk = 0; kk < NKK; ++kk) {
                short8 a = *(const short8*)&Ks[st * 16 + lo][kk * 32 + hi * 8];
                #pragma unroll
                for (int qs = 0; qs < NQS; ++qs)
                    sacc[st][qs] = __builtin_amdgcn_mfma_f32_16x16x32_bf16(
                        a, qf[qs][kk], sacc[st][qs], 0, 0, 0);
            }
        }

        float mn[NQS], ts[NQS];
        #pragma unroll
        for (int qs = 0; qs < NQS; ++qs) {
            float a0 = fmaxf(fmaxf(sacc[0][qs][0], sacc[0][qs][1]),
                             fmaxf(sacc[0][qs][2], sacc[0][qs][3]));
            float a1 = fmaxf(fmaxf(sacc[1][qs][0], sacc[1][qs][1]),
                             fmaxf(sacc[1][qs][2], sacc[1][qs][3]));
            float a2 = fmaxf(fmaxf(sacc[2][qs][0], sacc[2][qs][1]),
                             fmaxf(sacc[2][qs][2], sacc[2][qs][3]));
            float a3 = fmaxf(fmaxf(sacc[3][qs][0], sacc[3][qs][1]),
                             fmaxf(sacc[3][qs][2], sacc[3][qs][3]));
            float tm = fmaxf(fmaxf(a0, a1), fmaxf(a2, a3));
            tm = fmaxf(tm, __shfl_xor(tm, 16));
            tm = fmaxf(tm, __shfl_xor(tm, 32));
            const bool grow = __any(tm > m_i[qs] + 8.0f);
            mn[qs] = grow ? fmaxf(m_i[qs], tm) : m_i[qs];
            ts[qs] = 0.f;
            if (grow) {
                float alpha = __builtin_amdgcn_exp2f(m_i[qs] - mn[qs]);
                m_i[qs] = mn[qs];
                l_i[qs] *= alpha;
                float ar[4];
                #pragma unroll
                for (int r = 0; r < 4; ++r) ar[r] = __shfl(alpha, hi * 4 + r);
                #pragma unroll
                for (int nt = 0; nt < NNT; ++nt)
                    #pragma unroll
                    for (int r = 0; r < 4; ++r) acc[qs][nt][r] *= ar[r];
            }
        }

        #pragma unroll
        for (int st = 0; st < 4; ++st) {
            short4v pa_[NQS];
            #pragma unroll
            for (int qs = 0; qs < NQS; ++qs) {
                float p0 = __builtin_amdgcn_exp2f(sacc[st][qs][0] - mn[qs]);
                float p1 = __builtin_amdgcn_exp2f(sacc[st][qs][1] - mn[qs]);
                float p2 = __builtin_amdgcn_exp2f(sacc[st][qs][2] - mn[qs]);
                float p3 = __builtin_amdgcn_exp2f(sacc[st][qs][3] - mn[qs]);
                ts[qs] += (p0 + p1) + (p2 + p3);
                pa_[qs] = pack_bf16_trunc(p0, p1, p2, p3);
            }
            const int s0 = st * 16 + hi * 4;
            #pragma unroll
            for (int nt = 0; nt < NNT; ++nt) {
                int d = nt * 16 + lo;
                int g = ((d >> 3) ^ d) & 7;
                int scol = (s0 & 7) | ((((s0 >> 3) ^ g) & 7) << 3);
                short4v vb = *(const short4v*)&Vt[d][scol];
                #pragma unroll
                for (int qs = 0; qs < NQS; ++qs)
                    acc[qs][nt] = __builtin_amdgcn_mfma_f32_16x16x16bf16_1k(
                        pa_[qs], vb, acc[qs][nt], 0, 0, 0);
            }
        }

        #pragma unroll
        for (int qs = 0; qs < NQS; ++qs)
            l_i[qs] += ts[qs];
    }

    const int b_ = bh / NHEADS, h_ = bh % NHEADS;
    #pragma unroll
    for (int qs = 0; qs < NQS; ++qs) {
        float lr = l_i[qs];
        lr += __shfl_xor(lr, 16);
        lr += __shfl_xor(lr, 32);
        float inv = 1.0f / lr;
        float ir[4];
        #pragma unroll
        for (int r = 0; r < 4; ++r) ir[r] = __shfl(inv, hi * 4 + r);
        #pragma unroll
        for (int nt = 0; nt < NNT; ++nt)
            #pragma unroll
            for (int r = 0; r < 4; ++r) {
                int l = q0 + qs * 16 + hi * 4 + r;
                O[(((size_t)b_ * L + l) * NHEADS + h_) * DH + nt * 16 + lo] =
                    f2bf(acc[qs][nt][r] * ir[r]);
            }
    }
}

// ---------------------------------------------------------------------------

extern "C" void kernel_launch(void* const* d_in, const int* in_sizes, int n_in,
                              void* d_out, int out_size, void* d_ws, size_t ws_size,
                              hipStream_t stream)
{
    static const int CHs[4] = {64, 128, 256, 512};
    static const int HWs[4] = {128, 64, 32, 16};

    const float* f1[4] = {(const float*)d_in[0], (const float*)d_in[1],
                          (const float*)d_in[2], (const float*)d_in[3]};
    const float* f2[4] = {nullptr, (const float*)d_in[4], (const float*)d_in[6],
                          (const float*)d_in[8]};
    const float* f3[4] = {nullptr, (const float*)d_in[5], (const float*)d_in[7],
                          (const float*)d_in[9]};

    // level 0: pass-through
    size_t out0_elems = (size_t)in_sizes[0];
    hipMemcpyAsync(d_out, d_in[0], out0_elems * sizeof(float),
                   hipMemcpyDeviceToDevice, stream);

    // workspace: 8 bf16 slots of 2*4096*128 elems (16 MB) + fp32 prep region.
    const size_t SL = (size_t)2 * 4096 * 128;
    u16* wsu = (u16*)d_ws;
    u16* Qa  = wsu + 0 * SL;
    u16* Ka  = wsu + 1 * SL;
    u16* Va  = wsu + 2 * SL;
    u16* Qb  = wsu + 3 * SL;
    u16* Kb  = wsu + 4 * SL;
    u16* Vb  = wsu + 5 * SL;
    u16* Ana = wsu + 6 * SL;
    u16* Anb = wsu + 7 * SL;
    float* wp1 = (float*)(wsu + 8 * SL);
    float* wp2 = wp1 + (size_t)128 * 384;
    float* wp3 = wp2 + (size_t)256 * 768;
    float* bp1 = wp3 + (size_t)512 * 1536;
    float* bp2 = bp1 + 512;
    float* bp3 = bp2 + 512;

    // per-level weight pointers
    const float* SQW[3]; const float* OWA[3]; const float* OWB[3];
    const float* OBA[3]; const float* OBB[3]; const float* SQB[3];
    for (int l = 0; l < 3; ++l) {
        const int bi = 10 + l * 10;
        OWA[l] = (const float*)d_in[bi + 2];
        OBA[l] = (const float*)d_in[bi + 3];
        OWB[l] = (const float*)d_in[bi + 6];
        OBB[l] = (const float*)d_in[bi + 7];
        SQW[l] = (const float*)d_in[bi + 8];
        SQB[l] = (const float*)d_in[bi + 9];
    }

    // prep: fold out_proj into squeeze weights + bias (one launch)
    prep_all<<<252 + 896, 256, 0, stream>>>(
        SQW[0], OWA[0], OWB[0], OBA[0], OBB[0], SQB[0], wp1, bp1,
        SQW[1], OWA[1], OWB[1], OBA[1], OBB[1], SQB[1], wp2, bp2,
        SQW[2], OWA[2], OWB[2], OBA[2], OBB[2], SQB[2], wp3, bp3);

    const float LOG2E = 1.44269504088896340736f;

    size_t outOff = out0_elems;
    for (int lvl = 1; lvl <= 3; ++lvl) {
        const int C = CHs[lvl];
        const int Hs = HWs[lvl];
        const int L = Hs * Hs;
        const int dh = C / NHEADS;
        const int M = 2 * L;  // B*L
        const float qscale = LOG2E / sqrtf((float)dh);
        const int bi = 10 + (lvl - 1) * 10;
        const float* a12w = (const float*)d_in[bi + 0];
        const float* a12b = (const float*)d_in[bi + 1];
        const float* a13w = (const float*)d_in[bi + 4];
        const float* a13b = (const float*)d_in[bi + 5];
        float* wp = (lvl == 1) ? wp1 : (lvl == 2) ? wp2 : wp3;
        float* bp = (lvl == 1) ? bp1 : (lvl == 2) ? bp2 : bp3;

        // 1) fused qkv (both attentions) — transposing X stage
        const int gx = 3 * C / 64;
        const int perAtt = gx * (M / 64);
        gemm_qkv<<<2 * perAtt, 256, 0, stream>>>(
            f1[lvl], f2[lvl], f3[lvl], a12w, a12b, a13w, a13b,
            Qa, Ka, Va, Qb, Kb, Vb, M, C, L, dh, qscale, gx, perAtt);

        // 2) fused flash (both attentions) — XCD-affinity block remap
        if (dh == 64)
            flash_split<64, 4, 2><<<2 * (2 * NHEADS) * (L / 64), 512, 0, stream>>>(
                Qa, Ka, Va, Ana, Qb, Kb, Vb, Anb, L, L);
        else if (dh == 128)
            flash_split<128, 4, 1><<<2 * (2 * NHEADS) * (L / 32), 512, 0, stream>>>(
                Qa, Ka, Va, Ana, Qb, Kb, Vb, Anb, L, L);
        else
            flash_mfma<256, 1, 0><<<2 * (2 * NHEADS) * (L / 32), 128, 0, stream>>>(
                Qa, Ka, Va, Ana, Qb, Kb, Vb, Anb, L, L);

        // 3) squeeze (out_proj folded into Wp) into d_out (fp32 [b, n, l])
        dim3 gsq(C / 64, M / 64);
        gemm_squeeze<<<gsq, 256, 0, stream>>>(f1[lvl], Ana, Anb, wp, bp,
                                              (float*)d_out + outOff, M, C, L);
        outOff += (size_t)2 * C * L;
    }
}